// Round 7
// baseline (530.145 us; speedup 1.0000x reference)
//
#include <hip/hip_runtime.h>
#include <hip/hip_fp16.h>
#include <math.h>

typedef unsigned int uint;
typedef _Float16 f16x8 __attribute__((ext_vector_type(8)));
typedef float f32x4 __attribute__((ext_vector_type(4)));

#define NT 256

// ---------------- ws layout (uint/f32 words) ----------------
// 0     : W_l0 frags   [16 tiles][3 ksteps][64 lanes][4 uint]  = 12288
//         (s=0 carries fused bias0 at k=16, fed by const-1 in x~ frag)
// 12288 : W_l1 frags   [16][4][64][4]                          = 16384
// 28672 : W_v1 frags   [4][64][4]   (b1 folded at k=9)         = 1024
// 29696 : W_v2 frags   [2][64][4]                              = 512
// 30208 : b1frag (legacy, unused)                              = 1024
// 31232 : b2frag  f32  [64][4]  (-1e30 pad rows)               = 256
// 31488 : bias0frag    (legacy, unused)                        = 4096
// 35584 : bias1frag f32 [16][64][4]                            = 4096

// ---------------- LDS layout (bytes), frag-linear ----------------
// B-operand granule g = (k>>3)*16 + batch, 16B = halves k&7.
#define O_XB   0       // 256    x_t features k0..7
#define O_H0   256     // 2048   h0, K=64 (shared)
#define O_H1   2304    // 2048   h1, K=64 (shared)
#define O_WP   4352    // 1280   f32 [16 batch][20] delta partials
#define O_PHID 5632    // 32768  per-wave private hid: wave w at +w*2048
#define LDS_BYTES 38400

__device__ __forceinline__ float fexp2(float x) { return __builtin_amdgcn_exp2f(x); }
__device__ __forceinline__ float frcp(float x)  { return __builtin_amdgcn_rcpf(x); }
__device__ __forceinline__ float sigm(float x)  { return frcp(1.0f + fexp2(-1.44269504f * x)); }
__device__ __forceinline__ float tanh_(float x) { return fmaf(2.0f, frcp(1.0f + fexp2(-2.88539008f * x)), -1.0f); }

__device__ __forceinline__ uint pack2(float lo, float hi) {
    return ((uint)__half_as_ushort(__float2half_rn(hi)) << 16) |
           (uint)__half_as_ushort(__float2half_rn(lo));
}
__device__ __forceinline__ unsigned short f16b(float x) {
    return __half_as_ushort(__float2half_rn(x));
}
__device__ __forceinline__ f16x8 ldfrag(const uint* p) {
    union { uint4 u; f16x8 h; } c;
    c.u = *(const uint4*)p;
    return c.h;
}
__device__ __forceinline__ float lstm_out(const f32x4 a, float& c) {
    float ii = sigm(a[0]), ff = sigm(a[1]);
    float gg = tanh_(a[2]), oo = sigm(a[3]);
    c = fmaf(ff, c, ii * gg);
    return oo * tanh_(c);
}
__device__ __forceinline__ float wp_reduce(const unsigned char* smem, int cb) {
    const float* wp = (const float*)(smem + O_WP) + cb * 20;
    float4 s0 = *(const float4*)(wp);
    float4 s1 = *(const float4*)(wp + 4);
    float4 s2 = *(const float4*)(wp + 8);
    float4 s3 = *(const float4*)(wp + 12);
    return ((s0.x + s0.y) + (s0.z + s0.w)) + ((s1.x + s1.y) + (s1.z + s1.w))
         + ((s2.x + s2.y) + (s2.z + s2.w)) + ((s3.x + s3.y) + (s3.z + s3.w));
}

// A-frag (16x16x32 f16): lane l holds A[row16 = l&15][k = (l>>4)*8 + e].
// LSTM tiles gate-interleaved: row16 -> R = (row16&3)*64 + 4*tile + (row16>>2).
__global__ __launch_bounds__(1024)
void prep_kernel(const float* __restrict__ W1,  const float* __restrict__ b1,
                 const float* __restrict__ W2,  const float* __restrict__ b2,
                 const float* __restrict__ Wih0, const float* __restrict__ Whh0,
                 const float* __restrict__ bih0, const float* __restrict__ bhh0,
                 const float* __restrict__ Wih1, const float* __restrict__ Whh1,
                 const float* __restrict__ bih1, const float* __restrict__ bhh1,
                 uint* __restrict__ ws)
{
    const int tid = blockIdx.x * 1024 + threadIdx.x;
    float* wsf = (float*)ws;

    if (tid < 12288) {                               // W_l0
        int v = tid & 3, l = (tid >> 2) & 63, ts = tid >> 8;
        int s = ts % 3, w = ts / 3;
        int R = (l & 3) * 64 + 4 * w + ((l >> 2) & 3);
        int k0 = (l >> 4) * 8 + 2 * v;
        float lo = 0.f, hi = 0.f;
        if (s == 0) {
            if (k0     < 9) lo = Wih0[R * 9 + k0];
            if (k0 + 1 < 9) hi = Wih0[R * 9 + k0 + 1];
            if (k0 == 16)   lo = bih0[R] + bhh0[R];   // bias via const-1 at k=16
        } else {
            int kh = 32 * (s - 1) + k0;
            lo = Whh0[R * 64 + kh]; hi = Whh0[R * 64 + kh + 1];
        }
        ws[tid] = pack2(lo, hi);
    } else if (tid < 28672) {                        // W_l1
        int idx = tid - 12288;
        int v = idx & 3, l = (idx >> 2) & 63, ts = idx >> 8;
        int s = ts & 3, w = ts >> 2;
        int R = (l & 3) * 64 + 4 * w + ((l >> 2) & 3);
        int kt = 32 * s + (l >> 4) * 8 + 2 * v;
        float lo, hi;
        if (kt < 64) { lo = Wih1[R * 64 + kt];      hi = Wih1[R * 64 + kt + 1]; }
        else         { lo = Whh1[R * 64 + kt - 64]; hi = Whh1[R * 64 + kt - 63]; }
        ws[tid] = pack2(lo, hi);
    } else if (tid < 29696) {                        // W_v1 (b1 folded at k=9)
        int idx = tid - 28672;
        int v = idx & 3, l = (idx >> 2) & 63, m = idx >> 8;
        int j2 = 16 * m + (l & 15);
        int k0 = (l >> 4) * 8 + 2 * v;
        float lo = (k0 < 9) ? W1[j2 * 9 + k0] : 0.f;
        float hi = 0.f;
        if (k0 + 1 < 9)       hi = W1[j2 * 9 + k0 + 1];
        else if (k0 + 1 == 9) hi = b1[j2];
        ws[tid] = pack2(lo, hi);
    } else if (tid < 30208) {                        // W_v2 (rows padded to 16)
        int idx = tid - 29696;
        int v = idx & 3, l = (idx >> 2) & 63, s = idx >> 8;
        int rr = l & 15;
        int k0 = 32 * s + (l >> 4) * 8 + 2 * v;
        float lo = (rr < 9) ? W2[rr * 64 + k0]     : 0.f;
        float hi = (rr < 9) ? W2[rr * 64 + k0 + 1] : 0.f;
        ws[tid] = pack2(lo, hi);
    } else if (tid < 31488) {                        // b2frag (-1e30 pad rows)
        int idx = tid - 31232;
        if (tid >= 31232) {
            int r = idx & 3, l = idx >> 2;
            int row = (l >> 4) * 4 + r;
            wsf[tid] = (row < 9) ? b2[row] : -1e30f;
        }
    } else if (tid >= 35584 && tid < 39680) {        // bias1frag
        int idx = tid - 35584;
        int r = idx & 3, l = (idx >> 2) & 63, w = idx >> 8;
        int R = r * 64 + 4 * w + (l >> 4);
        wsf[tid] = bih1[R] + bhh1[R];
    }
}

// 256 blocks x 1024 threads (16 waves), 16 batches/block, 1 block/CU.
// Wave w owns hidden j in [4w, 4w+4); lane (q,cb): j = 4w+q, batch cb,
// acc regs = gates {i,f,g,o}. VSN computed redundantly by every wave.
__global__ __launch_bounds__(1024)
void tft_main(const float* __restrict__ feat,
              const float* __restrict__ Wo, const float* __restrict__ bo,
              const uint* __restrict__ ws,
              float* __restrict__ out)
{
    __shared__ unsigned char smem[LDS_BYTES];
    const int tid  = threadIdx.x;
    const int lane = tid & 63;
    const int w    = tid >> 6;        // 0..15
    const int q    = lane >> 4;       // 0..3
    const int cb   = lane & 15;       // batch column
    const int b0   = blockIdx.x * 16;

    // ---- zero shared dynamic area (XB/H0/H1/WP) ----
    {
        uint4 z = {0u, 0u, 0u, 0u};
        if (tid < 352) ((uint4*)smem)[tid] = z;
    }

    // ---- weights -> registers (all waves carry everything) ----
    const f16x8 wl0_0 = ldfrag(ws + (w * 3 + 0) * 256 + lane * 4);   // Wih0(x~)+bias0@k16
    const f16x8 wl0_1 = ldfrag(ws + (w * 3 + 1) * 256 + lane * 4);   // Whh0 K0..31
    const f16x8 wl0_2 = ldfrag(ws + (w * 3 + 2) * 256 + lane * 4);   // Whh0 K32..63
    const f16x8 wl1_0 = ldfrag(ws + 12288 + (w * 4 + 0) * 256 + lane * 4); // Wih1 K0..31
    const f16x8 wl1_1 = ldfrag(ws + 12288 + (w * 4 + 1) * 256 + lane * 4); // Wih1 K32..63
    const f16x8 wl1_2 = ldfrag(ws + 12288 + (w * 4 + 2) * 256 + lane * 4); // Whh1 K0..31
    const f16x8 wl1_3 = ldfrag(ws + 12288 + (w * 4 + 3) * 256 + lane * 4); // Whh1 K32..63
    const f16x8 wv1_0 = ldfrag(ws + 28672 +           lane * 4);
    const f16x8 wv1_1 = ldfrag(ws + 28672 + 256  +    lane * 4);
    const f16x8 wv1_2 = ldfrag(ws + 28672 + 512  +    lane * 4);
    const f16x8 wv1_3 = ldfrag(ws + 28672 + 768  +    lane * 4);
    const f16x8 wv2_0 = ldfrag(ws + 29696 +           lane * 4);
    const f16x8 wv2_1 = ldfrag(ws + 29696 + 256  +    lane * 4);
    const float* wsf = (const float*)ws;
    const float4 b2f   = *(const float4*)(wsf + 31232 + lane * 4);
    const float4 bias1 = *(const float4*)(wsf + 35584 + (w * 64 + lane) * 4);
    const float woj = Wo[4 * w + q];
    const float bov = bo[0];

    float c0 = 0.f, c1 = 0.f;
    f32x4 a0 = {0.f, 0.f, 0.f, 0.f};    // L0 acc (recurrent part from phase B of t-1)
    float4 px = {0.f, 0.f, 0.f, 0.f};
    unsigned char* phid = smem + O_PHID + w * 2048;   // this wave's private hid
    __syncthreads();

    // ---- stage x(0), prefetch x(1) (wave 5 lanes) ----
    if (tid >= 320 && tid < 352) {
        int pb = (tid >> 1) & 15, ph = tid & 1;
        float4 x0 = *(const float4*)(feat + ((size_t)(b0 + pb) * NT) * 8 + 4 * ph);
        uint2 p2; p2.x = pack2(x0.x, x0.y); p2.y = pack2(x0.z, x0.w);
        *(uint2*)(smem + O_XB + pb * 16 + ph * 8) = p2;
        px = *(const float4*)(feat + ((size_t)(b0 + pb) * NT + 1) * 8 + 4 * ph);
    }
    __syncthreads();

    #pragma unroll 1
    for (int t = 0; t < NT; ++t) {
        // ================= PHASE A =================
        // L1 recurrent (h1(t-1) from shared LDS)
        f32x4 a1 = {bias1.x, bias1.y, bias1.z, bias1.w};
        {
            f16x8 h1a = *(const f16x8*)(smem + O_H1 + lane * 16);
            f16x8 h1b = *(const f16x8*)(smem + O_H1 + 1024 + lane * 16);
            a1 = __builtin_amdgcn_mfma_f32_16x16x32_f16(wl1_2, h1a, a1, 0, 0, 0);
            a1 = __builtin_amdgcn_mfma_f32_16x16x32_f16(wl1_3, h1b, a1, 0, 0, 0);
        }
        // delta(t-1) register-reduce (q=1: VSN input; q=2: x~ mult)
        float dlt = 0.f;
        if (t > 0 && (q == 1 || q == 2)) dlt = wp_reduce(smem, cb) + bov;
        if (w == 0 && q == 1 && t > 0) out[(size_t)(b0 + cb) * NT + (t - 1)] = dlt;

        // VSN1 (redundant in every wave): hid = relu(W1 [x;delta;1] )
        uint4 xw = *(const uint4*)(smem + O_XB + cb * 16);   // x[k0..7][cb]
        union { uint4 u; f16x8 h; } xb;
        xb.u = (uint4){0u, 0u, 0u, 0u};
        if (q == 0) xb.u = xw;
        else if (q == 1) xb.u.x = pack2(dlt, 1.0f);          // k8=delta, k9=1 (b1)
        f32x4 v0a = {0,0,0,0}, v1a = {0,0,0,0}, v2a = {0,0,0,0}, v3a = {0,0,0,0};
        v0a = __builtin_amdgcn_mfma_f32_16x16x32_f16(wv1_0, xb.h, v0a, 0, 0, 0);
        v1a = __builtin_amdgcn_mfma_f32_16x16x32_f16(wv1_1, xb.h, v1a, 0, 0, 0);
        v2a = __builtin_amdgcn_mfma_f32_16x16x32_f16(wv1_2, xb.h, v2a, 0, 0, 0);
        v3a = __builtin_amdgcn_mfma_f32_16x16x32_f16(wv1_3, xb.h, v3a, 0, 0, 0);
        // relu + pack -> private hid (wave-local LDS, DS pipe in-order)
        {
            uint2 u;
            const int wo = ((q >> 1) * 16 + cb) * 16 + (q & 1) * 8;
            u.x = pack2(fmaxf(v0a[0],0.f), fmaxf(v0a[1],0.f));
            u.y = pack2(fmaxf(v0a[2],0.f), fmaxf(v0a[3],0.f));
            *(uint2*)(phid + wo) = u;
            u.x = pack2(fmaxf(v1a[0],0.f), fmaxf(v1a[1],0.f));
            u.y = pack2(fmaxf(v1a[2],0.f), fmaxf(v1a[3],0.f));
            *(uint2*)(phid + 512 + wo) = u;
            u.x = pack2(fmaxf(v2a[0],0.f), fmaxf(v2a[1],0.f));
            u.y = pack2(fmaxf(v2a[2],0.f), fmaxf(v2a[3],0.f));
            *(uint2*)(phid + 1024 + wo) = u;
            u.x = pack2(fmaxf(v3a[0],0.f), fmaxf(v3a[1],0.f));
            u.y = pack2(fmaxf(v3a[2],0.f), fmaxf(v3a[3],0.f));
            *(uint2*)(phid + 1536 + wo) = u;
        }
        // VSN2 + softmax (skip-max; pad rows b2=-1e30 -> e=0)
        f16x8 hb0 = *(const f16x8*)(phid + lane * 16);
        f16x8 hb1 = *(const f16x8*)(phid + 1024 + lane * 16);
        f32x4 aA = {b2f.x, b2f.y, b2f.z, b2f.w};
        f32x4 aB = {0,0,0,0};
        aA = __builtin_amdgcn_mfma_f32_16x16x32_f16(wv2_0, hb0, aA, 0, 0, 0);
        aB = __builtin_amdgcn_mfma_f32_16x16x32_f16(wv2_1, hb1, aB, 0, 0, 0);
        {
            float e0 = fexp2(1.44269504f * (aA[0] + aB[0]));
            float e1 = fexp2(1.44269504f * (aA[1] + aB[1]));
            float e2 = fexp2(1.44269504f * (aA[2] + aB[2]));
            float e3 = fexp2(1.44269504f * (aA[3] + aB[3]));
            float sm = (e0 + e1) + (e2 + e3);
            sm += __shfl_xor(sm, 16, 64);
            sm += __shfl_xor(sm, 32, 64);
            float inv = frcp(sm);
            const __half* xh = (const __half*)&xw;
            float x0, x1, x2, x3;
            if (q == 0)      { x0 = __half2float(xh[0]); x1 = __half2float(xh[1]);
                               x2 = __half2float(xh[2]); x3 = __half2float(xh[3]); }
            else if (q == 1) { x0 = __half2float(xh[4]); x1 = __half2float(xh[5]);
                               x2 = __half2float(xh[6]); x3 = __half2float(xh[7]); }
            else if (q == 2) { x0 = dlt; x1 = x2 = x3 = 0.f; }
            else             { x0 = x1 = x2 = x3 = 0.f; }
            uint p01 = pack2(x0 * e0 * inv, x1 * e1 * inv);
            uint p23 = pack2(x2 * e2 * inv, x3 * e3 * inv);
            // redistribute C-rows -> B-frag k-layout (4 shfls)
            int srcA = (((2 * q) & 3) << 4) + cb;
            int srcB = (((2 * q + 1) & 3) << 4) + cb;
            uint hA0 = (uint)__shfl((int)p01, srcA, 64);
            uint hA1 = (uint)__shfl((int)p23, srcA, 64);
            uint hB0 = (uint)__shfl((int)p01, srcB, 64);
            uint hB1 = (uint)__shfl((int)p23, srcB, 64);
            union { uint4 u; f16x8 h; } xs;
            if (q < 2)       xs.u = (uint4){hA0, hA1, hB0, hB1};
            else if (q == 2) xs.u = (uint4){0x3C00u, 0u, 0u, 0u};  // const-1 @k16 (bias0)
            else             xs.u = (uint4){0u, 0u, 0u, 0u};
            // LSTM0 finish
            a0 = __builtin_amdgcn_mfma_f32_16x16x32_f16(wl0_0, xs.h, a0, 0, 0, 0);
            float h0v = lstm_out(a0, c0);
            *(unsigned short*)(smem + O_H0 + (w >> 1) * 256 + cb * 16 + (4 * (w & 1) + q) * 2) = f16b(h0v);
        }
        __syncthreads();   // B1

        // ================= PHASE B =================
        {
            f16x8 h0a = *(const f16x8*)(smem + O_H0 + lane * 16);
            f16x8 h0b = *(const f16x8*)(smem + O_H0 + 1024 + lane * 16);
            a1 = __builtin_amdgcn_mfma_f32_16x16x32_f16(wl1_0, h0a, a1, 0, 0, 0);
            a1 = __builtin_amdgcn_mfma_f32_16x16x32_f16(wl1_1, h0b, a1, 0, 0, 0);
            f32x4 an = {0,0,0,0};
            an = __builtin_amdgcn_mfma_f32_16x16x32_f16(wl0_1, h0a, an, 0, 0, 0);
            an = __builtin_amdgcn_mfma_f32_16x16x32_f16(wl0_2, h0b, an, 0, 0, 0);
            a0 = an;                                   // next step's L0 recurrent part
            float h1v = lstm_out(a1, c1);
            *(unsigned short*)(smem + O_H1 + (w >> 1) * 256 + cb * 16 + (4 * (w & 1) + q) * 2) = f16b(h1v);
            float p = woj * h1v;
            p += __shfl_xor(p, 16, 64);
            p += __shfl_xor(p, 32, 64);
            if (q == 0) ((float*)(smem + O_WP))[cb * 20 + w] = p;
        }
        if (tid >= 320 && tid < 352) {   // wave 5: stage x(t+1), prefetch x(t+2)
            int pb = (tid >> 1) & 15, ph = tid & 1;
            uint2 p2; p2.x = pack2(px.x, px.y); p2.y = pack2(px.z, px.w);
            *(uint2*)(smem + O_XB + pb * 16 + ph * 8) = p2;
            if (t + 2 < NT)
                px = *(const float4*)(feat + ((size_t)(b0 + pb) * NT + (t + 2)) * 8 + 4 * ph);
        }
        __syncthreads();   // B2
    }

    // ---- epilogue: delta for t = 255 ----
    if (tid < 16) {
        float s = wp_reduce(smem, tid) + bov;
        out[(size_t)(b0 + tid) * NT + (NT - 1)] = s;
    }
}

extern "C" void kernel_launch(void* const* d_in, const int* in_sizes, int n_in,
                              void* d_out, int out_size, void* d_ws, size_t ws_size,
                              hipStream_t stream) {
    const float* feat = (const float*)d_in[0];
    const float* W1   = (const float*)d_in[1];
    const float* b1   = (const float*)d_in[2];
    const float* W2   = (const float*)d_in[3];
    const float* b2   = (const float*)d_in[4];
    const float* Wih0 = (const float*)d_in[5];
    const float* Whh0 = (const float*)d_in[6];
    const float* bih0 = (const float*)d_in[7];
    const float* bhh0 = (const float*)d_in[8];
    const float* Wih1 = (const float*)d_in[9];
    const float* Whh1 = (const float*)d_in[10];
    const float* bih1 = (const float*)d_in[11];
    const float* bhh1 = (const float*)d_in[12];
    const float* Wo   = (const float*)d_in[13];
    const float* bo   = (const float*)d_in[14];
    uint* ws   = (uint*)d_ws;
    float* out = (float*)d_out;

    hipLaunchKernelGGL(prep_kernel, dim3(40), dim3(1024), 0, stream,
                       W1, b1, W2, b2, Wih0, Whh0, bih0, bhh0,
                       Wih1, Whh1, bih1, bhh1, ws);
    // 256 blocks x 1024 threads: 16 batches/block, 1 block/CU
    hipLaunchKernelGGL(tft_main, dim3(256), dim3(1024), 0, stream,
                       feat, Wo, bo, ws, out);
}

// Round 9
// 526.902 us; speedup vs baseline: 1.0062x; 1.0062x over previous
//
#include <hip/hip_runtime.h>
#include <hip/hip_fp16.h>
#include <math.h>

typedef unsigned int uint;
typedef _Float16 f16x8 __attribute__((ext_vector_type(8)));
typedef __fp16 fp16x2 __attribute__((ext_vector_type(2)));
typedef float f32x4 __attribute__((ext_vector_type(4)));

#define NT 256

// ---------------- ws layout (uint/f32 words) ----------------
// 0     : W_l0 frags [16 tiles][3 ksteps][64 lanes][4 uint] = 12288
//         gate-prescaled; s=0 carries prescaled bias0 at k=16 (const-1 input)
// 12288 : W_l1 frags [16][4][64][4] = 16384  (gate-prescaled)
// 28672 : W_v1 frags [4][64][4]  (b1 folded at k=9)          = 1024
// 29696 : W_v2 frags [2][64][4]  (x log2e)                   = 512
// 31232 : b2frag f32 [64][4]     (x log2e; -1e30 pads)       = 256
// 35584 : bias1frag f32 [16][64][4] (gate-prescaled)         = 4096

// ---------------- LDS (bytes), frag-linear ----------------
// granule g = (k>>3)*16 + batch, 16B per granule (halves k&7)
#define O_XB  0      // 256   x_t k0..7
#define O_XS  256    // 1024  x~ (k0..8; k16 = 1.0 const feeding bias0 row)
#define O_HID 1280   // 2048  VSN hidden K=64
#define O_H0  3328   // 2048  h0 K=64
#define O_H1  5376   // 2048  h1 K=64
#define O_WP  7424   // 768   f32 [16][12] delta partials (cb>=8 phantom)
#define LDS_BYTES 8192

__device__ __forceinline__ float fexp2(float x) { return __builtin_amdgcn_exp2f(x); }
__device__ __forceinline__ float frcp(float x)  { return __builtin_amdgcn_rcpf(x); }

__device__ __forceinline__ uint pkrtz(float lo, float hi) {
    fp16x2 v = __builtin_amdgcn_cvt_pkrtz(lo, hi);
    return __builtin_bit_cast(uint, v);
}
__device__ __forceinline__ uint pack2(float lo, float hi) {
    return ((uint)__half_as_ushort(__float2half_rn(hi)) << 16) |
           (uint)__half_as_ushort(__float2half_rn(lo));
}
__device__ __forceinline__ unsigned short f16b(float x) {
    return __half_as_ushort(__float2half_rn(x));
}
__device__ __forceinline__ f16x8 ldfrag(const uint* p) {
    union { uint4 u; f16x8 h; } c;
    c.u = *(const uint4*)p;
    return c.h;
}
// gate rows prescaled: i,f,o by -log2(e); g by -2*log2(e)
__device__ __forceinline__ float lstm_out2(const f32x4 a, float& c) {
    float ii = frcp(1.0f + fexp2(a[0]));
    float ff = frcp(1.0f + fexp2(a[1]));
    float gg = fmaf(2.0f, frcp(1.0f + fexp2(a[2])), -1.0f);
    float oo = frcp(1.0f + fexp2(a[3]));
    c = fmaf(ff, c, ii * gg);
    return oo * fmaf(2.0f, frcp(1.0f + fexp2(-2.88539008f * c)), -1.0f);
}
__device__ __forceinline__ float wp_reduce8(const unsigned char* smem, int cb) {
    const float* wp = (const float*)(smem + O_WP) + cb * 12;
    float4 s0 = *(const float4*)(wp);
    float4 s1 = *(const float4*)(wp + 4);
    return ((s0.x + s0.y) + (s0.z + s0.w)) + ((s1.x + s1.y) + (s1.z + s1.w));
}

// A-frag (16x16x32 f16): lane l holds A[row16=l&15][k=(l>>4)*8+e].
// LSTM tiles gate-interleaved: row16 -> R = (row16&3)*64 + 4*tile + (row16>>2).
__global__ __launch_bounds__(1024)
void prep_kernel(const float* __restrict__ W1,  const float* __restrict__ b1,
                 const float* __restrict__ W2,  const float* __restrict__ b2,
                 const float* __restrict__ Wih0, const float* __restrict__ Whh0,
                 const float* __restrict__ bih0, const float* __restrict__ bhh0,
                 const float* __restrict__ Wih1, const float* __restrict__ Whh1,
                 const float* __restrict__ bih1, const float* __restrict__ bhh1,
                 uint* __restrict__ ws)
{
    const int tid = blockIdx.x * 1024 + threadIdx.x;
    float* wsf = (float*)ws;
    const float LOG2E = 1.44269504f;

    if (tid < 12288) {                               // W_l0 (prescaled)
        int v = tid & 3, l = (tid >> 2) & 63, ts = tid >> 8;
        int s = ts % 3, w = ts / 3;
        int g = l & 3;
        float sc = (g == 2) ? -2.0f * LOG2E : -LOG2E;
        int R = g * 64 + 4 * w + ((l >> 2) & 3);
        int k0 = (l >> 4) * 8 + 2 * v;
        float lo = 0.f, hi = 0.f;
        if (s == 0) {
            if (k0     < 9) lo = Wih0[R * 9 + k0];
            if (k0 + 1 < 9) hi = Wih0[R * 9 + k0 + 1];
            if (k0 == 16)   lo = bih0[R] + bhh0[R];   // bias0 via const-1 at k16
        } else {
            int kh = 32 * (s - 1) + k0;
            lo = Whh0[R * 64 + kh]; hi = Whh0[R * 64 + kh + 1];
        }
        ws[tid] = pack2(lo * sc, hi * sc);
    } else if (tid < 28672) {                        // W_l1 (prescaled)
        int idx = tid - 12288;
        int v = idx & 3, l = (idx >> 2) & 63, ts = idx >> 8;
        int s = ts & 3, w = ts >> 2;
        int g = l & 3;
        float sc = (g == 2) ? -2.0f * LOG2E : -LOG2E;
        int R = g * 64 + 4 * w + ((l >> 2) & 3);
        int kt = 32 * s + (l >> 4) * 8 + 2 * v;
        float lo, hi;
        if (kt < 64) { lo = Wih1[R * 64 + kt];      hi = Wih1[R * 64 + kt + 1]; }
        else         { lo = Whh1[R * 64 + kt - 64]; hi = Whh1[R * 64 + kt - 63]; }
        ws[tid] = pack2(lo * sc, hi * sc);
    } else if (tid < 29696) {                        // W_v1 (b1 folded at k=9)
        int idx = tid - 28672;
        int v = idx & 3, l = (idx >> 2) & 63, m = idx >> 8;
        int j2 = 16 * m + (l & 15);
        int k0 = (l >> 4) * 8 + 2 * v;
        float lo = (k0 < 9) ? W1[j2 * 9 + k0] : 0.f;
        float hi = 0.f;
        if (k0 + 1 < 9)       hi = W1[j2 * 9 + k0 + 1];
        else if (k0 + 1 == 9) hi = b1[j2];
        ws[tid] = pack2(lo, hi);
    } else if (tid < 30208) {                        // W_v2 (x log2e)
        int idx = tid - 29696;
        int v = idx & 3, l = (idx >> 2) & 63, s = idx >> 8;
        int rr = l & 15;
        int k0 = 32 * s + (l >> 4) * 8 + 2 * v;
        float lo = (rr < 9) ? W2[rr * 64 + k0] * LOG2E     : 0.f;
        float hi = (rr < 9) ? W2[rr * 64 + k0 + 1] * LOG2E : 0.f;
        ws[tid] = pack2(lo, hi);
    } else if (tid >= 31232 && tid < 31488) {        // b2frag (x log2e, -1e30 pads)
        int idx = tid - 31232;
        int r = idx & 3, l = idx >> 2;
        int row = (l >> 4) * 4 + r;
        wsf[tid] = (row < 9) ? b2[row] * LOG2E : -1e30f;
    } else if (tid >= 35584 && tid < 39680) {        // bias1frag (prescaled)
        int idx = tid - 35584;
        int r = idx & 3, l = (idx >> 2) & 63, w = idx >> 8;
        float sc = (r == 2) ? -2.0f * LOG2E : -LOG2E;
        int R = r * 64 + 4 * w + (l >> 4);
        wsf[tid] = (bih1[R] + bhh1[R]) * sc;
    }
}

// 512 blocks x 512 threads (8 waves), 8 batches/block, 2 blocks/CU.
// Wave w owns tiles tA=2w, tB=2w+1 (hidden j in [8w, 8w+8)).
// Lane (q=lane>>4, cb=lane&15): gates {i,f,g,o} for j = 8w+q (A), 8w+4+q (B).
__global__ __launch_bounds__(512, 4)
void tft_main(const float* __restrict__ feat,
              const float* __restrict__ Wo, const float* __restrict__ bo,
              const uint* __restrict__ ws,
              float* __restrict__ out)
{
    __shared__ unsigned char smem[LDS_BYTES];
    const int tid  = threadIdx.x;
    const int lane = tid & 63;
    const int w    = tid >> 6;        // 0..7
    const int q    = lane >> 4;       // 0..3
    const int cb   = lane & 15;       // batch column (0..7 real, 8..15 phantom)
    const int b0   = blockIdx.x * 8;
    const int tA   = 2 * w, tB = 2 * w + 1;

    // ---- zero all LDS ----
    {
        uint4 z = {0u, 0u, 0u, 0u};
        ((uint4*)smem)[tid] = z;   // 512 threads x 16B = 8192B
    }

    // ---- weights -> registers ----
    const f16x8 wl0_0A = ldfrag(ws + (tA * 3 + 0) * 256 + lane * 4);
    const f16x8 wl0_1A = ldfrag(ws + (tA * 3 + 1) * 256 + lane * 4);
    const f16x8 wl0_2A = ldfrag(ws + (tA * 3 + 2) * 256 + lane * 4);
    const f16x8 wl0_0B = ldfrag(ws + (tB * 3 + 0) * 256 + lane * 4);
    const f16x8 wl0_1B = ldfrag(ws + (tB * 3 + 1) * 256 + lane * 4);
    const f16x8 wl0_2B = ldfrag(ws + (tB * 3 + 2) * 256 + lane * 4);
    const f16x8 wl1_0A = ldfrag(ws + 12288 + (tA * 4 + 0) * 256 + lane * 4);
    const f16x8 wl1_1A = ldfrag(ws + 12288 + (tA * 4 + 1) * 256 + lane * 4);
    const f16x8 wl1_2A = ldfrag(ws + 12288 + (tA * 4 + 2) * 256 + lane * 4);
    const f16x8 wl1_3A = ldfrag(ws + 12288 + (tA * 4 + 3) * 256 + lane * 4);
    const f16x8 wl1_0B = ldfrag(ws + 12288 + (tB * 4 + 0) * 256 + lane * 4);
    const f16x8 wl1_1B = ldfrag(ws + 12288 + (tB * 4 + 1) * 256 + lane * 4);
    const f16x8 wl1_2B = ldfrag(ws + 12288 + (tB * 4 + 2) * 256 + lane * 4);
    const f16x8 wl1_3B = ldfrag(ws + 12288 + (tB * 4 + 3) * 256 + lane * 4);
    f16x8 wv1 = {}, wv2_0 = {}, wv2_1 = {};
    float4 b2f = {0.f, 0.f, 0.f, 0.f};
    const float* wsf = (const float*)ws;
    if (w < 4) wv1 = ldfrag(ws + 28672 + w * 256 + lane * 4);
    if (w == 4) {
        wv2_0 = ldfrag(ws + 29696 + lane * 4);
        wv2_1 = ldfrag(ws + 29696 + 256 + lane * 4);
        b2f   = *(const float4*)(wsf + 31232 + lane * 4);
    }
    const float4 bias1A = *(const float4*)(wsf + 35584 + (tA * 64 + lane) * 4);
    const float4 bias1B = *(const float4*)(wsf + 35584 + (tB * 64 + lane) * 4);
    const float wojA = Wo[8 * w + q];
    const float wojB = Wo[8 * w + 4 + q];
    const float bov  = bo[0];

    float c0A = 0.f, c0B = 0.f, c1A = 0.f, c1B = 0.f;
    f32x4 a0A = {0.f, 0.f, 0.f, 0.f};   // L0 acc carry (recurrent from P4 of t-1)
    f32x4 a0B = {0.f, 0.f, 0.f, 0.f};
    float4 px = {0.f, 0.f, 0.f, 0.f};
    __syncthreads();

    // ---- init: XS const-1 at k16; stage x(0); prefetch x(1) ----
    if (tid < 16) *(unsigned short*)(smem + O_XS + (32 + tid) * 16) = 0x3C00;
    if (tid >= 320 && tid < 336) {
        int pb = (tid >> 1) & 7, ph = tid & 1;
        float4 x0 = *(const float4*)(feat + ((size_t)(b0 + pb) * NT) * 8 + 4 * ph);
        uint2 p2; p2.x = pkrtz(x0.x, x0.y); p2.y = pkrtz(x0.z, x0.w);
        *(uint2*)(smem + O_XB + pb * 16 + ph * 8) = p2;
        px = *(const float4*)(feat + ((size_t)(b0 + pb) * NT + 1) * 8 + 4 * ph);
    }
    __syncthreads();

    #pragma unroll 1
    for (int t = 0; t < NT; ++t) {
        // ==== P1: L1 recurrent (all waves); VSN1 (waves 0-3); delta reduce ====
        f32x4 a1A = {bias1A.x, bias1A.y, bias1A.z, bias1A.w};
        f32x4 a1B = {bias1B.x, bias1B.y, bias1B.z, bias1B.w};
        {
            f16x8 h1a = *(const f16x8*)(smem + O_H1 + lane * 16);
            f16x8 h1b = *(const f16x8*)(smem + O_H1 + 1024 + lane * 16);
            a1A = __builtin_amdgcn_mfma_f32_16x16x32_f16(wl1_2A, h1a, a1A, 0, 0, 0);
            a1B = __builtin_amdgcn_mfma_f32_16x16x32_f16(wl1_2B, h1a, a1B, 0, 0, 0);
            a1A = __builtin_amdgcn_mfma_f32_16x16x32_f16(wl1_3A, h1b, a1A, 0, 0, 0);
            a1B = __builtin_amdgcn_mfma_f32_16x16x32_f16(wl1_3B, h1b, a1B, 0, 0, 0);
        }
        float dlt = 0.f;
        if (t > 0 && (q == 1 || q == 2)) dlt = wp_reduce8(smem, cb) + bov;
        if (w == 0 && q == 1 && cb < 8 && t > 0)
            out[(size_t)(b0 + cb) * NT + (t - 1)] = dlt;
        if (w < 4) {   // VSN1: hid = relu(W1 [x; delta; 1])
            union { uint4 u; f16x8 h; } xb;
            xb.u = (uint4){0u, 0u, 0u, 0u};
            if (q == 0)      xb.u = *(const uint4*)(smem + O_XB + cb * 16);
            else if (q == 1) xb.u.x = pkrtz(dlt, 1.0f);     // k8=delta, k9=1 (b1)
            f32x4 acc = {0.f, 0.f, 0.f, 0.f};
            acc = __builtin_amdgcn_mfma_f32_16x16x32_f16(wv1, xb.h, acc, 0, 0, 0);
            uint2 hw;
            hw.x = pkrtz(fmaxf(acc[0], 0.f), fmaxf(acc[1], 0.f));
            hw.y = pkrtz(fmaxf(acc[2], 0.f), fmaxf(acc[3], 0.f));
            *(uint2*)(smem + O_HID + ((2 * w + (q >> 1)) * 16 + cb) * 16 + (q & 1) * 8) = hw;
        }
        __syncthreads();   // hid ready

        // ==== P2: VSN2 + softmax + x~ (wave 4 only; W2/b2 prescaled) ====
        if (w == 4) {
            f16x8 hb0 = *(const f16x8*)(smem + O_HID + lane * 16);
            f16x8 hb1 = *(const f16x8*)(smem + O_HID + 1024 + lane * 16);
            f32x4 aA = {b2f.x, b2f.y, b2f.z, b2f.w};
            f32x4 aB = {0.f, 0.f, 0.f, 0.f};
            aA = __builtin_amdgcn_mfma_f32_16x16x32_f16(wv2_0, hb0, aA, 0, 0, 0);
            aB = __builtin_amdgcn_mfma_f32_16x16x32_f16(wv2_1, hb1, aB, 0, 0, 0);
            float e0 = fexp2(aA[0] + aB[0]);
            float e1 = fexp2(aA[1] + aB[1]);
            float e2 = fexp2(aA[2] + aB[2]);
            float e3 = fexp2(aA[3] + aB[3]);
            float sm = (e0 + e1) + (e2 + e3);
            sm += __shfl_xor(sm, 16, 64);
            sm += __shfl_xor(sm, 32, 64);
            float inv = frcp(sm);
            uint4 xw = *(const uint4*)(smem + O_XB + cb * 16);
            const __half* xh = (const __half*)&xw;
            float x0, x1, x2, x3;
            if (q == 0)      { x0 = __half2float(xh[0]); x1 = __half2float(xh[1]);
                               x2 = __half2float(xh[2]); x3 = __half2float(xh[3]); }
            else if (q == 1) { x0 = __half2float(xh[4]); x1 = __half2float(xh[5]);
                               x2 = __half2float(xh[6]); x3 = __half2float(xh[7]); }
            else if (q == 2) { x0 = dlt; x1 = x2 = x3 = 0.f; }
            else             { x0 = x1 = x2 = x3 = 0.f; }
            uint2 xsw;
            xsw.x = pkrtz(x0 * e0 * inv, x1 * e1 * inv);
            xsw.y = pkrtz(x2 * e2 * inv, x3 * e3 * inv);
            *(uint2*)(smem + O_XS + ((q >> 1) * 16 + cb) * 16 + (q & 1) * 8) = xsw;
        }
        __syncthreads();   // x~ ready

        // ==== P3: LSTM0 finish: 2 MFMA (shared x~ frag) + gates ====
        {
            f16x8 bx = *(const f16x8*)(smem + O_XS + lane * 16);
            a0A = __builtin_amdgcn_mfma_f32_16x16x32_f16(wl0_0A, bx, a0A, 0, 0, 0);
            a0B = __builtin_amdgcn_mfma_f32_16x16x32_f16(wl0_0B, bx, a0B, 0, 0, 0);
            float hA = lstm_out2(a0A, c0A);
            float hB = lstm_out2(a0B, c0B);
            *(unsigned short*)(smem + O_H0 + w * 256 + cb * 16 + q * 2)     = f16b(hA);
            *(unsigned short*)(smem + O_H0 + w * 256 + cb * 16 + 8 + q * 2) = f16b(hB);
        }
        __syncthreads();   // h0 ready

        // ==== P4: LSTM1 finish (4 MFMA) + next-step L0 recurrent (4 MFMA)
        //          + gates + delta partial + x(t+1) stage ====
        {
            f16x8 h0a = *(const f16x8*)(smem + O_H0 + lane * 16);
            f16x8 h0b = *(const f16x8*)(smem + O_H0 + 1024 + lane * 16);
            a1A = __builtin_amdgcn_mfma_f32_16x16x32_f16(wl1_0A, h0a, a1A, 0, 0, 0);
            a1B = __builtin_amdgcn_mfma_f32_16x16x32_f16(wl1_0B, h0a, a1B, 0, 0, 0);
            a1A = __builtin_amdgcn_mfma_f32_16x16x32_f16(wl1_1A, h0b, a1A, 0, 0, 0);
            a1B = __builtin_amdgcn_mfma_f32_16x16x32_f16(wl1_1B, h0b, a1B, 0, 0, 0);
            f32x4 anA = {0.f, 0.f, 0.f, 0.f};
            f32x4 anB = {0.f, 0.f, 0.f, 0.f};
            anA = __builtin_amdgcn_mfma_f32_16x16x32_f16(wl0_1A, h0a, anA, 0, 0, 0);
            anB = __builtin_amdgcn_mfma_f32_16x16x32_f16(wl0_1B, h0a, anB, 0, 0, 0);
            anA = __builtin_amdgcn_mfma_f32_16x16x32_f16(wl0_2A, h0b, anA, 0, 0, 0);
            anB = __builtin_amdgcn_mfma_f32_16x16x32_f16(wl0_2B, h0b, anB, 0, 0, 0);
            a0A = anA; a0B = anB;
            float hA = lstm_out2(a1A, c1A);
            float hB = lstm_out2(a1B, c1B);
            *(unsigned short*)(smem + O_H1 + w * 256 + cb * 16 + q * 2)     = f16b(hA);
            *(unsigned short*)(smem + O_H1 + w * 256 + cb * 16 + 8 + q * 2) = f16b(hB);
            float p = fmaf(wojA, hA, wojB * hB);
            p += __shfl_xor(p, 16, 64);
            p += __shfl_xor(p, 32, 64);
            if (q == 0) ((float*)(smem + O_WP))[cb * 12 + w] = p;
        }
        if (tid >= 320 && tid < 336) {   // stage x(t+1), prefetch x(t+2)
            int pb = (tid >> 1) & 7, ph = tid & 1;
            uint2 p2; p2.x = pkrtz(px.x, px.y); p2.y = pkrtz(px.z, px.w);
            *(uint2*)(smem + O_XB + pb * 16 + ph * 8) = p2;
            if (t + 2 < NT)
                px = *(const float4*)(feat + ((size_t)(b0 + pb) * NT + (t + 2)) * 8 + 4 * ph);
        }
        __syncthreads();   // h1/WP/x ready for next step
    }

    // ---- epilogue: delta for t = 255 ----
    if (tid < 8) {
        float s = wp_reduce8(smem, tid) + bov;
        out[(size_t)(b0 + tid) * NT + (NT - 1)] = s;
    }
}

extern "C" void kernel_launch(void* const* d_in, const int* in_sizes, int n_in,
                              void* d_out, int out_size, void* d_ws, size_t ws_size,
                              hipStream_t stream) {
    const float* feat = (const float*)d_in[0];
    const float* W1   = (const float*)d_in[1];
    const float* b1   = (const float*)d_in[2];
    const float* W2   = (const float*)d_in[3];
    const float* b2   = (const float*)d_in[4];
    const float* Wih0 = (const float*)d_in[5];
    const float* Whh0 = (const float*)d_in[6];
    const float* bih0 = (const float*)d_in[7];
    const float* bhh0 = (const float*)d_in[8];
    const float* Wih1 = (const float*)d_in[9];
    const float* Whh1 = (const float*)d_in[10];
    const float* bih1 = (const float*)d_in[11];
    const float* bhh1 = (const float*)d_in[12];
    const float* Wo   = (const float*)d_in[13];
    const float* bo   = (const float*)d_in[14];
    uint* ws   = (uint*)d_ws;
    float* out = (float*)d_out;

    hipLaunchKernelGGL(prep_kernel, dim3(40), dim3(1024), 0, stream,
                       W1, b1, W2, b2, Wih0, Whh0, bih0, bhh0,
                       Wih1, Whh1, bih1, bhh1, ws);
    // 512 blocks x 512 threads: 8 batches/block, 2 independent gangs per CU
    hipLaunchKernelGGL(tft_main, dim3(512), dim3(512), 0, stream,
                       feat, Wo, bo, ws, out);
}

// Round 10
// 419.734 us; speedup vs baseline: 1.2631x; 1.2553x over previous
//
#include <hip/hip_runtime.h>
#include <hip/hip_fp16.h>
#include <math.h>

typedef unsigned int uint;
typedef _Float16 f16x8 __attribute__((ext_vector_type(8)));
typedef __fp16 fp16x2 __attribute__((ext_vector_type(2)));
typedef float f32x4 __attribute__((ext_vector_type(4)));

#define NT 256

// ---------------- ws layout (uint/f32 words) ----------------
// 0     : W_l0 frags [16 tiles][3 ksteps][64 lanes][4 uint] = 12288
//         gate-prescaled; s=0 carries prescaled bias0 at k=16 (const-1 input)
// 12288 : W_l1 frags [16][4][64][4] = 16384  (gate-prescaled)
// 28672 : W_v1 frags [4][64][4]  (b1 folded at k=9)          = 1024
// 29696 : W_v2 frags [2][64][4]  (x log2e)                   = 512
// 31232 : b2frag f32 [64][4]     (x log2e; -1e30 pads)       = 256
// 35584 : bias1frag f32 [16][64][4] (gate-prescaled)         = 4096

// ---------------- LDS (bytes), frag-linear ----------------
// B-operand granule g = (k>>3)*16 + batch, 16B per granule (halves k&7)
#define O_XB  0      // 256   x_t k0..7
#define O_XS  256    // 1024  x~ (k0..8; k16 = 1.0 const feeding bias0 row)
#define O_HID 1280   // 2048  VSN hidden K=64
#define O_H0  3328   // 2048  h0 K=64
#define O_H1  5376   // 2048  h1 K=64
#define O_WP  7424   // 128   f32 [2 parity][16 batch] delta accum (ds_add)
#define LDS_BYTES 7552

__device__ __forceinline__ float fexp2(float x) { return __builtin_amdgcn_exp2f(x); }
__device__ __forceinline__ float frcp(float x)  { return __builtin_amdgcn_rcpf(x); }

__device__ __forceinline__ uint pkrtz(float lo, float hi) {
    fp16x2 v = __builtin_amdgcn_cvt_pkrtz(lo, hi);
    return __builtin_bit_cast(uint, v);
}
__device__ __forceinline__ uint pack2(float lo, float hi) {
    return ((uint)__half_as_ushort(__float2half_rn(hi)) << 16) |
           (uint)__half_as_ushort(__float2half_rn(lo));
}
__device__ __forceinline__ unsigned short f16b(float x) {
    return __half_as_ushort(__float2half_rn(x));
}
__device__ __forceinline__ f16x8 ldfrag(const uint* p) {
    union { uint4 u; f16x8 h; } c;
    c.u = *(const uint4*)p;
    return c.h;
}
// gate rows prescaled: i,f,o by -log2(e); g by -2*log2(e)
__device__ __forceinline__ float lstm_out2(const f32x4 a, float& c) {
    float ii = frcp(1.0f + fexp2(a[0]));
    float ff = frcp(1.0f + fexp2(a[1]));
    float gg = fmaf(2.0f, frcp(1.0f + fexp2(a[2])), -1.0f);
    float oo = frcp(1.0f + fexp2(a[3]));
    c = fmaf(ff, c, ii * gg);
    return oo * fmaf(2.0f, frcp(1.0f + fexp2(-2.88539008f * c)), -1.0f);
}

// A-frag (16x16x32 f16): lane l holds A[row16=l&15][k=(l>>4)*8+e].
// LSTM tiles gate-interleaved: row16 -> R = (row16&3)*64 + 4*tile + (row16>>2).
__global__ __launch_bounds__(1024)
void prep_kernel(const float* __restrict__ W1,  const float* __restrict__ b1,
                 const float* __restrict__ W2,  const float* __restrict__ b2,
                 const float* __restrict__ Wih0, const float* __restrict__ Whh0,
                 const float* __restrict__ bih0, const float* __restrict__ bhh0,
                 const float* __restrict__ Wih1, const float* __restrict__ Whh1,
                 const float* __restrict__ bih1, const float* __restrict__ bhh1,
                 uint* __restrict__ ws)
{
    const int tid = blockIdx.x * 1024 + threadIdx.x;
    float* wsf = (float*)ws;
    const float LOG2E = 1.44269504f;

    if (tid < 12288) {                               // W_l0 (prescaled)
        int v = tid & 3, l = (tid >> 2) & 63, ts = tid >> 8;
        int s = ts % 3, w = ts / 3;
        int g = l & 3;
        float sc = (g == 2) ? -2.0f * LOG2E : -LOG2E;
        int R = g * 64 + 4 * w + ((l >> 2) & 3);
        int k0 = (l >> 4) * 8 + 2 * v;
        float lo = 0.f, hi = 0.f;
        if (s == 0) {
            if (k0     < 9) lo = Wih0[R * 9 + k0];
            if (k0 + 1 < 9) hi = Wih0[R * 9 + k0 + 1];
            if (k0 == 16)   lo = bih0[R] + bhh0[R];   // bias0 via const-1 at k16
        } else {
            int kh = 32 * (s - 1) + k0;
            lo = Whh0[R * 64 + kh]; hi = Whh0[R * 64 + kh + 1];
        }
        ws[tid] = pack2(lo * sc, hi * sc);
    } else if (tid < 28672) {                        // W_l1 (prescaled)
        int idx = tid - 12288;
        int v = idx & 3, l = (idx >> 2) & 63, ts = idx >> 8;
        int s = ts & 3, w = ts >> 2;
        int g = l & 3;
        float sc = (g == 2) ? -2.0f * LOG2E : -LOG2E;
        int R = g * 64 + 4 * w + ((l >> 2) & 3);
        int kt = 32 * s + (l >> 4) * 8 + 2 * v;
        float lo, hi;
        if (kt < 64) { lo = Wih1[R * 64 + kt];      hi = Wih1[R * 64 + kt + 1]; }
        else         { lo = Whh1[R * 64 + kt - 64]; hi = Whh1[R * 64 + kt - 63]; }
        ws[tid] = pack2(lo * sc, hi * sc);
    } else if (tid < 29696) {                        // W_v1 (b1 folded at k=9)
        int idx = tid - 28672;
        int v = idx & 3, l = (idx >> 2) & 63, m = idx >> 8;
        int j2 = 16 * m + (l & 15);
        int k0 = (l >> 4) * 8 + 2 * v;
        float lo = (k0 < 9) ? W1[j2 * 9 + k0] : 0.f;
        float hi = 0.f;
        if (k0 + 1 < 9)       hi = W1[j2 * 9 + k0 + 1];
        else if (k0 + 1 == 9) hi = b1[j2];
        ws[tid] = pack2(lo, hi);
    } else if (tid < 30208) {                        // W_v2 (x log2e)
        int idx = tid - 29696;
        int v = idx & 3, l = (idx >> 2) & 63, s = idx >> 8;
        int rr = l & 15;
        int k0 = 32 * s + (l >> 4) * 8 + 2 * v;
        float lo = (rr < 9) ? W2[rr * 64 + k0] * LOG2E     : 0.f;
        float hi = (rr < 9) ? W2[rr * 64 + k0 + 1] * LOG2E : 0.f;
        ws[tid] = pack2(lo, hi);
    } else if (tid >= 31232 && tid < 31488) {        // b2frag (x log2e, -1e30 pads)
        int idx = tid - 31232;
        int r = idx & 3, l = idx >> 2;
        int row = (l >> 4) * 4 + r;
        wsf[tid] = (row < 9) ? b2[row] * LOG2E : -1e30f;
    } else if (tid >= 35584 && tid < 39680) {        // bias1frag (prescaled)
        int idx = tid - 35584;
        int r = idx & 3, l = (idx >> 2) & 63, w = idx >> 8;
        float sc = (r == 2) ? -2.0f * LOG2E : -LOG2E;
        int R = r * 64 + 4 * w + (l >> 4);
        wsf[tid] = (bih1[R] + bhh1[R]) * sc;
    }
}

// 256 blocks x 1024 threads (16 waves), 16 batches/block, 1 block/CU.
// Wave w owns hidden j in [4w, 4w+4); lane (q,cb): j = 4w+q, batch cb,
// acc regs = gates {i,f,g,o} (gate-interleaved A rows).
__global__ __launch_bounds__(1024)
void tft_main(const float* __restrict__ feat,
              const float* __restrict__ Wo, const float* __restrict__ bo,
              const uint* __restrict__ ws,
              float* __restrict__ out)
{
    __shared__ unsigned char smem[LDS_BYTES];
    const int tid  = threadIdx.x;
    const int lane = tid & 63;
    const int w    = tid >> 6;        // 0..15
    const int q    = lane >> 4;       // 0..3
    const int cb   = lane & 15;       // batch column
    const int b0   = blockIdx.x * 16;
    float* wpbuf = (float*)(smem + O_WP);

    // ---- zero LDS ----
    {
        uint4 z = {0u, 0u, 0u, 0u};
        if (tid < LDS_BYTES / 16) ((uint4*)smem)[tid] = z;
    }

    // ---- weights -> registers ----
    const f16x8 wl0_0 = ldfrag(ws + (w * 3 + 0) * 256 + lane * 4);   // x~ + bias0@k16
    const f16x8 wl0_1 = ldfrag(ws + (w * 3 + 1) * 256 + lane * 4);   // Whh0 K0..31
    const f16x8 wl0_2 = ldfrag(ws + (w * 3 + 2) * 256 + lane * 4);   // Whh0 K32..63
    const f16x8 wl1_0 = ldfrag(ws + 12288 + (w * 4 + 0) * 256 + lane * 4); // Wih1 K0..31
    const f16x8 wl1_1 = ldfrag(ws + 12288 + (w * 4 + 1) * 256 + lane * 4); // Wih1 K32..63
    const f16x8 wl1_2 = ldfrag(ws + 12288 + (w * 4 + 2) * 256 + lane * 4); // Whh1 K0..31
    const f16x8 wl1_3 = ldfrag(ws + 12288 + (w * 4 + 3) * 256 + lane * 4); // Whh1 K32..63
    f16x8 wv1 = {}, wv2_0 = {}, wv2_1 = {};
    float4 b2f = {0.f, 0.f, 0.f, 0.f};
    const float* wsf = (const float*)ws;
    if (w < 4) wv1 = ldfrag(ws + 28672 + w * 256 + lane * 4);
    if (w == 4) {
        wv2_0 = ldfrag(ws + 29696 + lane * 4);
        wv2_1 = ldfrag(ws + 29696 + 256 + lane * 4);
        b2f   = *(const float4*)(wsf + 31232 + lane * 4);
    }
    const float4 bias1 = *(const float4*)(wsf + 35584 + (w * 64 + lane) * 4);
    const float woj = Wo[4 * w + q];
    const float bov = bo[0];

    float c0 = 0.f, c1 = 0.f;
    f32x4 a0 = {0.f, 0.f, 0.f, 0.f};    // L0 acc carry (recurrent from P4 of t-1)
    float4 px = {0.f, 0.f, 0.f, 0.f};   // x(t+1) prefetch (wave 5 lanes)
    __syncthreads();

    // ---- init: XS const-1 at k16; stage x(0); prefetch x(1) ----
    if (tid < 16) *(unsigned short*)(smem + O_XS + (32 + tid) * 16) = 0x3C00;
    if (tid >= 320 && tid < 352) {
        int pb = (tid >> 1) & 15, ph = tid & 1;
        float4 x0 = *(const float4*)(feat + ((size_t)(b0 + pb) * NT) * 8 + 4 * ph);
        uint2 p2; p2.x = pkrtz(x0.x, x0.y); p2.y = pkrtz(x0.z, x0.w);
        *(uint2*)(smem + O_XB + pb * 16 + ph * 8) = p2;
        px = *(const float4*)(feat + ((size_t)(b0 + pb) * NT + 1) * 8 + 4 * ph);
    }
    __syncthreads();

    #pragma unroll 1
    for (int t = 0; t < NT; ++t) {
        // ==== P1: L1 recurrent MFMAs (all); VSN1 (waves 0-3); dlt read (waves 0-4);
        //          zero next delta-accum buffer (wave 7) ====
        f32x4 a1 = {bias1.x, bias1.y, bias1.z, bias1.w};
        {
            f16x8 h1a = *(const f16x8*)(smem + O_H1 + lane * 16);
            f16x8 h1b = *(const f16x8*)(smem + O_H1 + 1024 + lane * 16);
            a1 = __builtin_amdgcn_mfma_f32_16x16x32_f16(wl1_2, h1a, a1, 0, 0, 0);
            a1 = __builtin_amdgcn_mfma_f32_16x16x32_f16(wl1_3, h1b, a1, 0, 0, 0);
        }
        float dlt = 0.f;
        if (t > 0 && w < 5) dlt = wpbuf[((t - 1) & 1) * 16 + cb] + bov;
        if (w == 0 && lane < 16 && t > 0)
            out[(size_t)(b0 + lane) * NT + (t - 1)] = dlt;
        if (w == 7 && lane < 16) wpbuf[(t & 1) * 16 + lane] = 0.f;   // this step's accum
        if (w < 4) {   // VSN1: hid = relu(W1 [x; delta; 1])
            union { uint4 u; f16x8 h; } xb;
            xb.u = (uint4){0u, 0u, 0u, 0u};
            if (q == 0)      xb.u = *(const uint4*)(smem + O_XB + cb * 16);
            else if (q == 1) xb.u.x = pkrtz(dlt, 1.0f);     // k8=delta, k9=1 (b1)
            f32x4 acc = {0.f, 0.f, 0.f, 0.f};
            acc = __builtin_amdgcn_mfma_f32_16x16x32_f16(wv1, xb.h, acc, 0, 0, 0);
            uint2 hw;
            hw.x = pkrtz(fmaxf(acc[0], 0.f), fmaxf(acc[1], 0.f));
            hw.y = pkrtz(fmaxf(acc[2], 0.f), fmaxf(acc[3], 0.f));
            *(uint2*)(smem + O_HID + ((2 * w + (q >> 1)) * 16 + cb) * 16 + (q & 1) * 8) = hw;
        }
        __syncthreads();   // hid ready

        // ==== P2: VSN2 + softmax + x~ (wave 4 only; W2/b2 prescaled by log2e) ====
        if (w == 4) {
            f16x8 hb0 = *(const f16x8*)(smem + O_HID + lane * 16);
            f16x8 hb1 = *(const f16x8*)(smem + O_HID + 1024 + lane * 16);
            f32x4 aA = {b2f.x, b2f.y, b2f.z, b2f.w};
            f32x4 aB = {0.f, 0.f, 0.f, 0.f};
            aA = __builtin_amdgcn_mfma_f32_16x16x32_f16(wv2_0, hb0, aA, 0, 0, 0);
            aB = __builtin_amdgcn_mfma_f32_16x16x32_f16(wv2_1, hb1, aB, 0, 0, 0);
            float e0 = fexp2(aA[0] + aB[0]);
            float e1 = fexp2(aA[1] + aB[1]);
            float e2 = fexp2(aA[2] + aB[2]);
            float e3 = fexp2(aA[3] + aB[3]);
            float sm = (e0 + e1) + (e2 + e3);
            sm += __shfl_xor(sm, 16, 64);
            sm += __shfl_xor(sm, 32, 64);
            float inv = frcp(sm);
            uint4 xw = *(const uint4*)(smem + O_XB + cb * 16);
            const __half* xh = (const __half*)&xw;
            float x0, x1, x2, x3;
            if (q == 0)      { x0 = __half2float(xh[0]); x1 = __half2float(xh[1]);
                               x2 = __half2float(xh[2]); x3 = __half2float(xh[3]); }
            else if (q == 1) { x0 = __half2float(xh[4]); x1 = __half2float(xh[5]);
                               x2 = __half2float(xh[6]); x3 = __half2float(xh[7]); }
            else if (q == 2) { x0 = dlt; x1 = x2 = x3 = 0.f; }
            else             { x0 = x1 = x2 = x3 = 0.f; }
            uint2 xsw;
            xsw.x = pkrtz(x0 * e0 * inv, x1 * e1 * inv);
            xsw.y = pkrtz(x2 * e2 * inv, x3 * e3 * inv);
            *(uint2*)(smem + O_XS + ((q >> 1) * 16 + cb) * 16 + (q & 1) * 8) = xsw;
        }
        __syncthreads();   // x~ ready

        // ==== P3: LSTM0 finish: 1 MFMA (x~ + fused bias0) + gates ====
        {
            f16x8 bx = *(const f16x8*)(smem + O_XS + lane * 16);
            a0 = __builtin_amdgcn_mfma_f32_16x16x32_f16(wl0_0, bx, a0, 0, 0, 0);
            float h0v = lstm_out2(a0, c0);
            *(unsigned short*)(smem + O_H0 + (w >> 1) * 256 + cb * 16 + (4 * (w & 1) + q) * 2) = f16b(h0v);
        }
        __syncthreads();   // h0 ready

        // ==== P4: LSTM1 finish (2 MFMA) + next L0 recurrent (2 MFMA, reusing
        //          h0 frags) + gates + delta ds_add + x(t+1) stage ====
        {
            f16x8 h0a = *(const f16x8*)(smem + O_H0 + lane * 16);
            f16x8 h0b = *(const f16x8*)(smem + O_H0 + 1024 + lane * 16);
            a1 = __builtin_amdgcn_mfma_f32_16x16x32_f16(wl1_0, h0a, a1, 0, 0, 0);
            a1 = __builtin_amdgcn_mfma_f32_16x16x32_f16(wl1_1, h0b, a1, 0, 0, 0);
            f32x4 an = {0.f, 0.f, 0.f, 0.f};
            an = __builtin_amdgcn_mfma_f32_16x16x32_f16(wl0_1, h0a, an, 0, 0, 0);
            an = __builtin_amdgcn_mfma_f32_16x16x32_f16(wl0_2, h0b, an, 0, 0, 0);
            a0 = an;                                   // next step's L0 recurrent part
            float h1v = lstm_out2(a1, c1);
            *(unsigned short*)(smem + O_H1 + (w >> 1) * 256 + cb * 16 + (4 * (w & 1) + q) * 2) = f16b(h1v);
            float p = woj * h1v;
            p += __shfl_xor(p, 16, 64);
            p += __shfl_xor(p, 32, 64);
            if (q == 0) atomicAdd(&wpbuf[(t & 1) * 16 + cb], p);
        }
        if (tid >= 320 && tid < 352) {   // wave 5: stage x(t+1), prefetch x(t+2)
            int pb = (tid >> 1) & 15, ph = tid & 1;
            uint2 p2; p2.x = pkrtz(px.x, px.y); p2.y = pkrtz(px.z, px.w);
            *(uint2*)(smem + O_XB + pb * 16 + ph * 8) = p2;
            if (t + 2 < NT)
                px = *(const float4*)(feat + ((size_t)(b0 + pb) * NT + (t + 2)) * 8 + 4 * ph);
        }
        __syncthreads();   // h1/delta/x ready for next step
    }

    // ---- epilogue: delta for t = 255 (accumulated in parity buffer 1) ----
    if (tid < 16)
        out[(size_t)(b0 + tid) * NT + (NT - 1)] = wpbuf[16 + tid] + bov;
}

extern "C" void kernel_launch(void* const* d_in, const int* in_sizes, int n_in,
                              void* d_out, int out_size, void* d_ws, size_t ws_size,
                              hipStream_t stream) {
    const float* feat = (const float*)d_in[0];
    const float* W1   = (const float*)d_in[1];
    const float* b1   = (const float*)d_in[2];
    const float* W2   = (const float*)d_in[3];
    const float* b2   = (const float*)d_in[4];
    const float* Wih0 = (const float*)d_in[5];
    const float* Whh0 = (const float*)d_in[6];
    const float* bih0 = (const float*)d_in[7];
    const float* bhh0 = (const float*)d_in[8];
    const float* Wih1 = (const float*)d_in[9];
    const float* Whh1 = (const float*)d_in[10];
    const float* bih1 = (const float*)d_in[11];
    const float* bhh1 = (const float*)d_in[12];
    const float* Wo   = (const float*)d_in[13];
    const float* bo   = (const float*)d_in[14];
    uint* ws   = (uint*)d_ws;
    float* out = (float*)d_out;

    hipLaunchKernelGGL(prep_kernel, dim3(40), dim3(1024), 0, stream,
                       W1, b1, W2, b2, Wih0, Whh0, bih0, bhh0,
                       Wih1, Whh1, bih1, bhh1, ws);
    // 256 blocks x 1024 threads: 16 batches/block, 1 block/CU
    hipLaunchKernelGGL(tft_main, dim3(256), dim3(1024), 0, stream,
                       feat, Wo, bo, ws, out);
}

// Round 11
// 362.181 us; speedup vs baseline: 1.4638x; 1.1589x over previous
//
#include <hip/hip_runtime.h>
#include <hip/hip_fp16.h>
#include <math.h>

typedef unsigned int uint;
typedef _Float16 f16x8 __attribute__((ext_vector_type(8)));
typedef __fp16 fp16x2 __attribute__((ext_vector_type(2)));
typedef float f32x4 __attribute__((ext_vector_type(4)));

#define NT 256

// ---------------- ws layout (uint/f32 words) ----------------
// 0     : W_l0 frags [16 tiles][3 ksteps][64 lanes][4 uint] = 12288
//         gate-prescaled; s=0 carries prescaled bias0 at k=16 (const-1 input)
// 12288 : W_l1 frags [16][4][64][4] = 16384  (gate-prescaled)
// 28672 : W_v1 frags [4][64][4]  (b1 folded at k=9)          = 1024
// 29696 : W_v2 frags [2][64][4]  (x log2e)                   = 512
// 31232 : b2frag f32 [64][4]     (x log2e; -1e30 pads)       = 256
// 35584 : bias1frag f32 [16][64][4] (gate-prescaled)         = 4096

// ---------------- LDS (bytes), frag-linear ----------------
// B-operand granule g = (k>>3)*16 + batch, 16B per granule (halves k&7)
#define O_XB  0      // 256   x_t k0..7
#define O_XS  256    // 1024  x~ (k0..8; k16 = 1.0 const feeding bias0 row)
#define O_HID 1280   // 2048  VSN hidden K=64
#define O_H0  3328   // 2048  h0 K=64
#define O_H1  5376   // 2048  h1 K=64
#define O_WP  7424   // 1280  f32 [16 batch][20] delta partials (w 0..7 used)
#define LDS_BYTES 8704

__device__ __forceinline__ float fexp2(float x) { return __builtin_amdgcn_exp2f(x); }
__device__ __forceinline__ float frcp(float x)  { return __builtin_amdgcn_rcpf(x); }

__device__ __forceinline__ uint pkrtz(float lo, float hi) {
    fp16x2 v = __builtin_amdgcn_cvt_pkrtz(lo, hi);
    return __builtin_bit_cast(uint, v);
}
__device__ __forceinline__ uint pack2(float lo, float hi) {
    return ((uint)__half_as_ushort(__float2half_rn(hi)) << 16) |
           (uint)__half_as_ushort(__float2half_rn(lo));
}
__device__ __forceinline__ unsigned short f16b(float x) {
    return __half_as_ushort(__float2half_rn(x));
}
__device__ __forceinline__ f16x8 ldfrag(const uint* p) {
    union { uint4 u; f16x8 h; } c;
    c.u = *(const uint4*)p;
    return c.h;
}
// gate rows prescaled: i,f,o by -log2(e); g by -2*log2(e)
__device__ __forceinline__ float lstm_out2(const f32x4 a, float& c) {
    float ii = frcp(1.0f + fexp2(a[0]));
    float ff = frcp(1.0f + fexp2(a[1]));
    float gg = fmaf(2.0f, frcp(1.0f + fexp2(a[2])), -1.0f);
    float oo = frcp(1.0f + fexp2(a[3]));
    c = fmaf(ff, c, ii * gg);
    return oo * fmaf(2.0f, frcp(1.0f + fexp2(-2.88539008f * c)), -1.0f);
}
// sum of 8 wave partials (waves 0..7)
__device__ __forceinline__ float wp_reduce8(const unsigned char* smem, int cb) {
    const float* wp = (const float*)(smem + O_WP) + cb * 20;
    float4 s0 = *(const float4*)(wp);
    float4 s1 = *(const float4*)(wp + 4);
    return ((s0.x + s0.y) + (s0.z + s0.w)) + ((s1.x + s1.y) + (s1.z + s1.w));
}

// A-frag (16x16x32 f16): lane l holds A[row16=l&15][k=(l>>4)*8+e].
// LSTM tiles gate-interleaved: row16 -> R = (row16&3)*64 + 4*tile + (row16>>2).
__global__ __launch_bounds__(1024)
void prep_kernel(const float* __restrict__ W1,  const float* __restrict__ b1,
                 const float* __restrict__ W2,  const float* __restrict__ b2,
                 const float* __restrict__ Wih0, const float* __restrict__ Whh0,
                 const float* __restrict__ bih0, const float* __restrict__ bhh0,
                 const float* __restrict__ Wih1, const float* __restrict__ Whh1,
                 const float* __restrict__ bih1, const float* __restrict__ bhh1,
                 uint* __restrict__ ws)
{
    const int tid = blockIdx.x * 1024 + threadIdx.x;
    float* wsf = (float*)ws;
    const float LOG2E = 1.44269504f;

    if (tid < 12288) {                               // W_l0 (prescaled)
        int v = tid & 3, l = (tid >> 2) & 63, ts = tid >> 8;
        int s = ts % 3, w = ts / 3;
        int g = l & 3;
        float sc = (g == 2) ? -2.0f * LOG2E : -LOG2E;
        int R = g * 64 + 4 * w + ((l >> 2) & 3);
        int k0 = (l >> 4) * 8 + 2 * v;
        float lo = 0.f, hi = 0.f;
        if (s == 0) {
            if (k0     < 9) lo = Wih0[R * 9 + k0];
            if (k0 + 1 < 9) hi = Wih0[R * 9 + k0 + 1];
            if (k0 == 16)   lo = bih0[R] + bhh0[R];   // bias0 via const-1 at k16
        } else {
            int kh = 32 * (s - 1) + k0;
            lo = Whh0[R * 64 + kh]; hi = Whh0[R * 64 + kh + 1];
        }
        ws[tid] = pack2(lo * sc, hi * sc);
    } else if (tid < 28672) {                        // W_l1 (prescaled)
        int idx = tid - 12288;
        int v = idx & 3, l = (idx >> 2) & 63, ts = idx >> 8;
        int s = ts & 3, w = ts >> 2;
        int g = l & 3;
        float sc = (g == 2) ? -2.0f * LOG2E : -LOG2E;
        int R = g * 64 + 4 * w + ((l >> 2) & 3);
        int kt = 32 * s + (l >> 4) * 8 + 2 * v;
        float lo, hi;
        if (kt < 64) { lo = Wih1[R * 64 + kt];      hi = Wih1[R * 64 + kt + 1]; }
        else         { lo = Whh1[R * 64 + kt - 64]; hi = Whh1[R * 64 + kt - 63]; }
        ws[tid] = pack2(lo * sc, hi * sc);
    } else if (tid < 29696) {                        // W_v1 (b1 folded at k=9)
        int idx = tid - 28672;
        int v = idx & 3, l = (idx >> 2) & 63, m = idx >> 8;
        int j2 = 16 * m + (l & 15);
        int k0 = (l >> 4) * 8 + 2 * v;
        float lo = (k0 < 9) ? W1[j2 * 9 + k0] : 0.f;
        float hi = 0.f;
        if (k0 + 1 < 9)       hi = W1[j2 * 9 + k0 + 1];
        else if (k0 + 1 == 9) hi = b1[j2];
        ws[tid] = pack2(lo, hi);
    } else if (tid < 30208) {                        // W_v2 (x log2e)
        int idx = tid - 29696;
        int v = idx & 3, l = (idx >> 2) & 63, s = idx >> 8;
        int rr = l & 15;
        int k0 = 32 * s + (l >> 4) * 8 + 2 * v;
        float lo = (rr < 9) ? W2[rr * 64 + k0] * LOG2E     : 0.f;
        float hi = (rr < 9) ? W2[rr * 64 + k0 + 1] * LOG2E : 0.f;
        ws[tid] = pack2(lo, hi);
    } else if (tid >= 31232 && tid < 31488) {        // b2frag (x log2e, -1e30 pads)
        int idx = tid - 31232;
        int r = idx & 3, l = idx >> 2;
        int row = (l >> 4) * 4 + r;
        wsf[tid] = (row < 9) ? b2[row] * LOG2E : -1e30f;
    } else if (tid >= 35584 && tid < 39680) {        // bias1frag (prescaled)
        int idx = tid - 35584;
        int r = idx & 3, l = (idx >> 2) & 63, w = idx >> 8;
        float sc = (r == 2) ? -2.0f * LOG2E : -LOG2E;
        int R = r * 64 + 4 * w + (l >> 4);
        wsf[tid] = (bih1[R] + bhh1[R]) * sc;
    }
}

// 256 blocks x 512 threads (8 waves), 16 batches/block, 1 block/CU.
// Wave w owns tiles tA=2w, tB=2w+1 (hidden j = 8w+q and 8w+4+q per lane).
// Halved DS traffic vs 16-wave: every B-frag read feeds 2 tiles' MFMAs.
__global__ __launch_bounds__(512)
void tft_main(const float* __restrict__ feat,
              const float* __restrict__ Wo, const float* __restrict__ bo,
              const uint* __restrict__ ws,
              float* __restrict__ out)
{
    __shared__ unsigned char smem[LDS_BYTES];
    const int tid  = threadIdx.x;
    const int lane = tid & 63;
    const int w    = tid >> 6;        // 0..7
    const int q    = lane >> 4;       // 0..3
    const int cb   = lane & 15;       // batch column (all 16 real)
    const int b0   = blockIdx.x * 16;
    const int tA   = 2 * w, tB = 2 * w + 1;
    float* wpbuf = (float*)(smem + O_WP);

    // ---- zero LDS (8704 B: 512*16 + 32*16) ----
    {
        uint4 z = {0u, 0u, 0u, 0u};
        ((uint4*)smem)[tid] = z;
        if (tid < LDS_BYTES / 16 - 512) ((uint4*)smem)[512 + tid] = z;
    }

    // ---- weights -> registers (2 tiles per wave) ----
    const f16x8 wl0_0A = ldfrag(ws + (tA * 3 + 0) * 256 + lane * 4);
    const f16x8 wl0_1A = ldfrag(ws + (tA * 3 + 1) * 256 + lane * 4);
    const f16x8 wl0_2A = ldfrag(ws + (tA * 3 + 2) * 256 + lane * 4);
    const f16x8 wl0_0B = ldfrag(ws + (tB * 3 + 0) * 256 + lane * 4);
    const f16x8 wl0_1B = ldfrag(ws + (tB * 3 + 1) * 256 + lane * 4);
    const f16x8 wl0_2B = ldfrag(ws + (tB * 3 + 2) * 256 + lane * 4);
    const f16x8 wl1_0A = ldfrag(ws + 12288 + (tA * 4 + 0) * 256 + lane * 4);
    const f16x8 wl1_1A = ldfrag(ws + 12288 + (tA * 4 + 1) * 256 + lane * 4);
    const f16x8 wl1_2A = ldfrag(ws + 12288 + (tA * 4 + 2) * 256 + lane * 4);
    const f16x8 wl1_3A = ldfrag(ws + 12288 + (tA * 4 + 3) * 256 + lane * 4);
    const f16x8 wl1_0B = ldfrag(ws + 12288 + (tB * 4 + 0) * 256 + lane * 4);
    const f16x8 wl1_1B = ldfrag(ws + 12288 + (tB * 4 + 1) * 256 + lane * 4);
    const f16x8 wl1_2B = ldfrag(ws + 12288 + (tB * 4 + 2) * 256 + lane * 4);
    const f16x8 wl1_3B = ldfrag(ws + 12288 + (tB * 4 + 3) * 256 + lane * 4);
    f16x8 wv1 = {}, wv2_0 = {}, wv2_1 = {};
    float4 b2f = {0.f, 0.f, 0.f, 0.f};
    const float* wsf = (const float*)ws;
    if (w < 4) wv1 = ldfrag(ws + 28672 + w * 256 + lane * 4);
    if (w == 4) {
        wv2_0 = ldfrag(ws + 29696 + lane * 4);
        wv2_1 = ldfrag(ws + 29696 + 256 + lane * 4);
        b2f   = *(const float4*)(wsf + 31232 + lane * 4);
    }
    const float4 bias1A = *(const float4*)(wsf + 35584 + (tA * 64 + lane) * 4);
    const float4 bias1B = *(const float4*)(wsf + 35584 + (tB * 64 + lane) * 4);
    const float wojA = Wo[8 * w + q];
    const float wojB = Wo[8 * w + 4 + q];
    const float bov  = bo[0];

    float c0A = 0.f, c0B = 0.f, c1A = 0.f, c1B = 0.f;
    f32x4 a0A = {0.f, 0.f, 0.f, 0.f};   // L0 acc carry (recurrent from P4 of t-1)
    f32x4 a0B = {0.f, 0.f, 0.f, 0.f};
    float4 px = {0.f, 0.f, 0.f, 0.f};
    __syncthreads();

    // ---- init: XS const-1 at k16; stage x(0); prefetch x(1) (wave 5) ----
    if (tid < 16) *(unsigned short*)(smem + O_XS + (32 + tid) * 16) = 0x3C00;
    if (tid >= 320 && tid < 352) {
        int pb = (tid >> 1) & 15, ph = tid & 1;
        float4 x0 = *(const float4*)(feat + ((size_t)(b0 + pb) * NT) * 8 + 4 * ph);
        uint2 p2; p2.x = pkrtz(x0.x, x0.y); p2.y = pkrtz(x0.z, x0.w);
        *(uint2*)(smem + O_XB + pb * 16 + ph * 8) = p2;
        px = *(const float4*)(feat + ((size_t)(b0 + pb) * NT + 1) * 8 + 4 * ph);
    }
    __syncthreads();

    #pragma unroll 1
    for (int t = 0; t < NT; ++t) {
        // ==== P1: L1 recurrent (all waves, shared h1 frags); VSN1 (waves 0-3);
        //          delta(t-1) reduce (consumer lanes only) ====
        f32x4 a1A = {bias1A.x, bias1A.y, bias1A.z, bias1A.w};
        f32x4 a1B = {bias1B.x, bias1B.y, bias1B.z, bias1B.w};
        {
            f16x8 h1a = *(const f16x8*)(smem + O_H1 + lane * 16);
            f16x8 h1b = *(const f16x8*)(smem + O_H1 + 1024 + lane * 16);
            a1A = __builtin_amdgcn_mfma_f32_16x16x32_f16(wl1_2A, h1a, a1A, 0, 0, 0);
            a1B = __builtin_amdgcn_mfma_f32_16x16x32_f16(wl1_2B, h1a, a1B, 0, 0, 0);
            a1A = __builtin_amdgcn_mfma_f32_16x16x32_f16(wl1_3A, h1b, a1A, 0, 0, 0);
            a1B = __builtin_amdgcn_mfma_f32_16x16x32_f16(wl1_3B, h1b, a1B, 0, 0, 0);
        }
        float dlt = 0.f;
        if (t > 0 && ((w < 4 && q == 1) || (w == 4 && q == 2)))
            dlt = wp_reduce8(smem, cb) + bov;
        if (w == 0 && q == 1 && t > 0)
            out[(size_t)(b0 + cb) * NT + (t - 1)] = dlt;
        if (w < 4) {   // VSN1: hid = relu(W1 [x; delta; 1])
            union { uint4 u; f16x8 h; } xb;
            xb.u = (uint4){0u, 0u, 0u, 0u};
            if (q == 0)      xb.u = *(const uint4*)(smem + O_XB + cb * 16);
            else if (q == 1) xb.u.x = pkrtz(dlt, 1.0f);     // k8=delta, k9=1 (b1)
            f32x4 acc = {0.f, 0.f, 0.f, 0.f};
            acc = __builtin_amdgcn_mfma_f32_16x16x32_f16(wv1, xb.h, acc, 0, 0, 0);
            uint2 hw;
            hw.x = pkrtz(fmaxf(acc[0], 0.f), fmaxf(acc[1], 0.f));
            hw.y = pkrtz(fmaxf(acc[2], 0.f), fmaxf(acc[3], 0.f));
            *(uint2*)(smem + O_HID + ((2 * w + (q >> 1)) * 16 + cb) * 16 + (q & 1) * 8) = hw;
        }
        __syncthreads();   // hid ready

        // ==== P2: VSN2 + softmax + x~ (wave 4 only; W2/b2 prescaled) ====
        if (w == 4) {
            f16x8 hb0 = *(const f16x8*)(smem + O_HID + lane * 16);
            f16x8 hb1 = *(const f16x8*)(smem + O_HID + 1024 + lane * 16);
            f32x4 aA = {b2f.x, b2f.y, b2f.z, b2f.w};
            f32x4 aB = {0.f, 0.f, 0.f, 0.f};
            aA = __builtin_amdgcn_mfma_f32_16x16x32_f16(wv2_0, hb0, aA, 0, 0, 0);
            aB = __builtin_amdgcn_mfma_f32_16x16x32_f16(wv2_1, hb1, aB, 0, 0, 0);
            float e0 = fexp2(aA[0] + aB[0]);
            float e1 = fexp2(aA[1] + aB[1]);
            float e2 = fexp2(aA[2] + aB[2]);
            float e3 = fexp2(aA[3] + aB[3]);
            float sm = (e0 + e1) + (e2 + e3);
            sm += __shfl_xor(sm, 16, 64);
            sm += __shfl_xor(sm, 32, 64);
            float inv = frcp(sm);
            uint4 xw = *(const uint4*)(smem + O_XB + cb * 16);
            const __half* xh = (const __half*)&xw;
            float x0, x1, x2, x3;
            if (q == 0)      { x0 = __half2float(xh[0]); x1 = __half2float(xh[1]);
                               x2 = __half2float(xh[2]); x3 = __half2float(xh[3]); }
            else if (q == 1) { x0 = __half2float(xh[4]); x1 = __half2float(xh[5]);
                               x2 = __half2float(xh[6]); x3 = __half2float(xh[7]); }
            else if (q == 2) { x0 = dlt; x1 = x2 = x3 = 0.f; }
            else             { x0 = x1 = x2 = x3 = 0.f; }
            uint2 xsw;
            xsw.x = pkrtz(x0 * e0 * inv, x1 * e1 * inv);
            xsw.y = pkrtz(x2 * e2 * inv, x3 * e3 * inv);
            *(uint2*)(smem + O_XS + ((q >> 1) * 16 + cb) * 16 + (q & 1) * 8) = xsw;
        }
        __syncthreads();   // x~ ready

        // ==== P3: LSTM0 finish: 2 MFMA (shared x~ frag) + gates ====
        {
            f16x8 bx = *(const f16x8*)(smem + O_XS + lane * 16);
            a0A = __builtin_amdgcn_mfma_f32_16x16x32_f16(wl0_0A, bx, a0A, 0, 0, 0);
            a0B = __builtin_amdgcn_mfma_f32_16x16x32_f16(wl0_0B, bx, a0B, 0, 0, 0);
            float hA = lstm_out2(a0A, c0A);
            float hB = lstm_out2(a0B, c0B);
            *(unsigned short*)(smem + O_H0 + w * 256 + cb * 16 + q * 2)     = f16b(hA);
            *(unsigned short*)(smem + O_H0 + w * 256 + cb * 16 + 8 + q * 2) = f16b(hB);
        }
        __syncthreads();   // h0 ready

        // ==== P4: LSTM1 finish (4 MFMA) + next-step L0 recurrent (4 MFMA,
        //          reusing h0 frags) + gates + delta partial + x stage ====
        {
            f16x8 h0a = *(const f16x8*)(smem + O_H0 + lane * 16);
            f16x8 h0b = *(const f16x8*)(smem + O_H0 + 1024 + lane * 16);
            a1A = __builtin_amdgcn_mfma_f32_16x16x32_f16(wl1_0A, h0a, a1A, 0, 0, 0);
            a1B = __builtin_amdgcn_mfma_f32_16x16x32_f16(wl1_0B, h0a, a1B, 0, 0, 0);
            a1A = __builtin_amdgcn_mfma_f32_16x16x32_f16(wl1_1A, h0b, a1A, 0, 0, 0);
            a1B = __builtin_amdgcn_mfma_f32_16x16x32_f16(wl1_1B, h0b, a1B, 0, 0, 0);
            f32x4 anA = {0.f, 0.f, 0.f, 0.f};
            f32x4 anB = {0.f, 0.f, 0.f, 0.f};
            anA = __builtin_amdgcn_mfma_f32_16x16x32_f16(wl0_1A, h0a, anA, 0, 0, 0);
            anB = __builtin_amdgcn_mfma_f32_16x16x32_f16(wl0_1B, h0a, anB, 0, 0, 0);
            anA = __builtin_amdgcn_mfma_f32_16x16x32_f16(wl0_2A, h0b, anA, 0, 0, 0);
            anB = __builtin_amdgcn_mfma_f32_16x16x32_f16(wl0_2B, h0b, anB, 0, 0, 0);
            a0A = anA; a0B = anB;
            float hA = lstm_out2(a1A, c1A);
            float hB = lstm_out2(a1B, c1B);
            *(unsigned short*)(smem + O_H1 + w * 256 + cb * 16 + q * 2)     = f16b(hA);
            *(unsigned short*)(smem + O_H1 + w * 256 + cb * 16 + 8 + q * 2) = f16b(hB);
            float p = fmaf(wojA, hA, wojB * hB);
            p += __shfl_xor(p, 16, 64);
            p += __shfl_xor(p, 32, 64);
            if (q == 0) wpbuf[cb * 20 + w] = p;
        }
        if (tid >= 320 && tid < 352) {   // wave 5: stage x(t+1), prefetch x(t+2)
            int pb = (tid >> 1) & 15, ph = tid & 1;
            uint2 p2; p2.x = pkrtz(px.x, px.y); p2.y = pkrtz(px.z, px.w);
            *(uint2*)(smem + O_XB + pb * 16 + ph * 8) = p2;
            if (t + 2 < NT)
                px = *(const float4*)(feat + ((size_t)(b0 + pb) * NT + (t + 2)) * 8 + 4 * ph);
        }
        __syncthreads();   // h1/WP/x ready for next step
    }

    // ---- epilogue: delta for t = 255 ----
    if (tid < 16)
        out[(size_t)(b0 + tid) * NT + (NT - 1)] = wp_reduce8(smem, tid) + bov;
}

extern "C" void kernel_launch(void* const* d_in, const int* in_sizes, int n_in,
                              void* d_out, int out_size, void* d_ws, size_t ws_size,
                              hipStream_t stream) {
    const float* feat = (const float*)d_in[0];
    const float* W1   = (const float*)d_in[1];
    const float* b1   = (const float*)d_in[2];
    const float* W2   = (const float*)d_in[3];
    const float* b2   = (const float*)d_in[4];
    const float* Wih0 = (const float*)d_in[5];
    const float* Whh0 = (const float*)d_in[6];
    const float* bih0 = (const float*)d_in[7];
    const float* bhh0 = (const float*)d_in[8];
    const float* Wih1 = (const float*)d_in[9];
    const float* Whh1 = (const float*)d_in[10];
    const float* bih1 = (const float*)d_in[11];
    const float* bhh1 = (const float*)d_in[12];
    const float* Wo   = (const float*)d_in[13];
    const float* bo   = (const float*)d_in[14];
    uint* ws   = (uint*)d_ws;
    float* out = (float*)d_out;

    hipLaunchKernelGGL(prep_kernel, dim3(40), dim3(1024), 0, stream,
                       W1, b1, W2, b2, Wih0, Whh0, bih0, bhh0,
                       Wih1, Whh1, bih1, bhh1, ws);
    // 256 blocks x 512 threads (8 waves): 16 batches/block, 1 block/CU
    hipLaunchKernelGGL(tft_main, dim3(256), dim3(512), 0, stream,
                       feat, Wo, bo, ws, out);
}

// Round 12
// 361.151 us; speedup vs baseline: 1.4679x; 1.0029x over previous
//
#include <hip/hip_runtime.h>
#include <hip/hip_fp16.h>
#include <math.h>

typedef unsigned int uint;
typedef _Float16 f16x8 __attribute__((ext_vector_type(8)));
typedef __fp16 fp16x2 __attribute__((ext_vector_type(2)));
typedef float f32x4 __attribute__((ext_vector_type(4)));

#define NT 256

// ---------------- ws layout (uint/f32 words) ----------------
// 0     : W_l0 frags [16 tiles][3 ksteps][64 lanes][4 uint] = 12288
//         gate-prescaled; s=0 carries prescaled bias0 at k=16 (const-1 input)
// 12288 : W_l1 frags [16][4][64][4] = 16384  (gate-prescaled)
// 28672 : W_v1 frags [4][64][4]  (b1 folded at k=9)          = 1024
// 29696 : W_v2 frags [2][64][4]  (x log2e)                   = 512
// 31232 : b2frag f32 [64][4]     (x log2e; -1e30 pads)       = 256
// 35584 : bias1frag f32 [16][64][4] (gate-prescaled)         = 4096

// ---------------- LDS (bytes), frag-linear ----------------
// B-operand granule g = (k>>3)*16 + batch, 16B per granule (halves k&7)
#define O_XB  0      // 256   x_t k0..7
#define O_HID 1280   // 2048  VSN hidden K=64
#define O_H0  3328   // 2048  h0 K=64
#define O_H1  5376   // 2048  h1 K=64
#define O_WP  7424   // 1280  f32 [16 batch][20] delta partials (w 0..7 used)
#define LDS_BYTES 8704

__device__ __forceinline__ float fexp2(float x) { return __builtin_amdgcn_exp2f(x); }
__device__ __forceinline__ float frcp(float x)  { return __builtin_amdgcn_rcpf(x); }

__device__ __forceinline__ uint pkrtz(float lo, float hi) {
    fp16x2 v = __builtin_amdgcn_cvt_pkrtz(lo, hi);
    return __builtin_bit_cast(uint, v);
}
__device__ __forceinline__ uint pack2(float lo, float hi) {
    return ((uint)__half_as_ushort(__float2half_rn(hi)) << 16) |
           (uint)__half_as_ushort(__float2half_rn(lo));
}
__device__ __forceinline__ unsigned short f16b(float x) {
    return __half_as_ushort(__float2half_rn(x));
}
__device__ __forceinline__ f16x8 ldfrag(const uint* p) {
    union { uint4 u; f16x8 h; } c;
    c.u = *(const uint4*)p;
    return c.h;
}
// gate rows prescaled: i,f,o by -log2(e); g by -2*log2(e)
__device__ __forceinline__ float lstm_out2(const f32x4 a, float& c) {
    float ii = frcp(1.0f + fexp2(a[0]));
    float ff = frcp(1.0f + fexp2(a[1]));
    float gg = fmaf(2.0f, frcp(1.0f + fexp2(a[2])), -1.0f);
    float oo = frcp(1.0f + fexp2(a[3]));
    c = fmaf(ff, c, ii * gg);
    return oo * fmaf(2.0f, frcp(1.0f + fexp2(-2.88539008f * c)), -1.0f);
}
// sum of 8 wave partials (waves 0..7)
__device__ __forceinline__ float wp_reduce8(const unsigned char* smem, int cb) {
    const float* wp = (const float*)(smem + O_WP) + cb * 20;
    float4 s0 = *(const float4*)(wp);
    float4 s1 = *(const float4*)(wp + 4);
    return ((s0.x + s0.y) + (s0.z + s0.w)) + ((s1.x + s1.y) + (s1.z + s1.w));
}

// A-frag (16x16x32 f16): lane l holds A[row16=l&15][k=(l>>4)*8+e].
// LSTM tiles gate-interleaved: row16 -> R = (row16&3)*64 + 4*tile + (row16>>2).
__global__ __launch_bounds__(1024)
void prep_kernel(const float* __restrict__ W1,  const float* __restrict__ b1,
                 const float* __restrict__ W2,  const float* __restrict__ b2,
                 const float* __restrict__ Wih0, const float* __restrict__ Whh0,
                 const float* __restrict__ bih0, const float* __restrict__ bhh0,
                 const float* __restrict__ Wih1, const float* __restrict__ Whh1,
                 const float* __restrict__ bih1, const float* __restrict__ bhh1,
                 uint* __restrict__ ws)
{
    const int tid = blockIdx.x * 1024 + threadIdx.x;
    float* wsf = (float*)ws;
    const float LOG2E = 1.44269504f;

    if (tid < 12288) {                               // W_l0 (prescaled)
        int v = tid & 3, l = (tid >> 2) & 63, ts = tid >> 8;
        int s = ts % 3, w = ts / 3;
        int g = l & 3;
        float sc = (g == 2) ? -2.0f * LOG2E : -LOG2E;
        int R = g * 64 + 4 * w + ((l >> 2) & 3);
        int k0 = (l >> 4) * 8 + 2 * v;
        float lo = 0.f, hi = 0.f;
        if (s == 0) {
            if (k0     < 9) lo = Wih0[R * 9 + k0];
            if (k0 + 1 < 9) hi = Wih0[R * 9 + k0 + 1];
            if (k0 == 16)   lo = bih0[R] + bhh0[R];   // bias0 via const-1 at k16
        } else {
            int kh = 32 * (s - 1) + k0;
            lo = Whh0[R * 64 + kh]; hi = Whh0[R * 64 + kh + 1];
        }
        ws[tid] = pack2(lo * sc, hi * sc);
    } else if (tid < 28672) {                        // W_l1 (prescaled)
        int idx = tid - 12288;
        int v = idx & 3, l = (idx >> 2) & 63, ts = idx >> 8;
        int s = ts & 3, w = ts >> 2;
        int g = l & 3;
        float sc = (g == 2) ? -2.0f * LOG2E : -LOG2E;
        int R = g * 64 + 4 * w + ((l >> 2) & 3);
        int kt = 32 * s + (l >> 4) * 8 + 2 * v;
        float lo, hi;
        if (kt < 64) { lo = Wih1[R * 64 + kt];      hi = Wih1[R * 64 + kt + 1]; }
        else         { lo = Whh1[R * 64 + kt - 64]; hi = Whh1[R * 64 + kt - 63]; }
        ws[tid] = pack2(lo * sc, hi * sc);
    } else if (tid < 29696) {                        // W_v1 (b1 folded at k=9)
        int idx = tid - 28672;
        int v = idx & 3, l = (idx >> 2) & 63, m = idx >> 8;
        int j2 = 16 * m + (l & 15);
        int k0 = (l >> 4) * 8 + 2 * v;
        float lo = (k0 < 9) ? W1[j2 * 9 + k0] : 0.f;
        float hi = 0.f;
        if (k0 + 1 < 9)       hi = W1[j2 * 9 + k0 + 1];
        else if (k0 + 1 == 9) hi = b1[j2];
        ws[tid] = pack2(lo, hi);
    } else if (tid < 30208) {                        // W_v2 (x log2e)
        int idx = tid - 29696;
        int v = idx & 3, l = (idx >> 2) & 63, s = idx >> 8;
        int rr = l & 15;
        int k0 = 32 * s + (l >> 4) * 8 + 2 * v;
        float lo = (rr < 9) ? W2[rr * 64 + k0] * LOG2E     : 0.f;
        float hi = (rr < 9) ? W2[rr * 64 + k0 + 1] * LOG2E : 0.f;
        ws[tid] = pack2(lo, hi);
    } else if (tid >= 31232 && tid < 31488) {        // b2frag (x log2e, -1e30 pads)
        int idx = tid - 31232;
        int r = idx & 3, l = idx >> 2;
        int row = (l >> 4) * 4 + r;
        wsf[tid] = (row < 9) ? b2[row] * LOG2E : -1e30f;
    } else if (tid >= 35584 && tid < 39680) {        // bias1frag (prescaled)
        int idx = tid - 35584;
        int r = idx & 3, l = (idx >> 2) & 63, w = idx >> 8;
        float sc = (r == 2) ? -2.0f * LOG2E : -LOG2E;
        int R = r * 64 + 4 * w + (l >> 4);
        wsf[tid] = (bih1[R] + bhh1[R]) * sc;
    }
}

// 256 blocks x 512 threads (8 waves), 16 batches/block, 1 block/CU.
// Wave w owns tiles tA=2w, tB=2w+1 (hidden j = 8w+q and 8w+4+q per lane).
// 3-phase schedule: VSN2+softmax computed redundantly by every wave; the
// x~ C-frag -> B-frag redistribution is done in-register with 4 shfls.
__global__ __launch_bounds__(512)
void tft_main(const float* __restrict__ feat,
              const float* __restrict__ Wo, const float* __restrict__ bo,
              const uint* __restrict__ ws,
              float* __restrict__ out)
{
    __shared__ unsigned char smem[LDS_BYTES];
    const int tid  = threadIdx.x;
    const int lane = tid & 63;
    const int w    = tid >> 6;        // 0..7
    const int q    = lane >> 4;       // 0..3
    const int cb   = lane & 15;       // batch column (all 16 real)
    const int b0   = blockIdx.x * 16;
    const int tA   = 2 * w, tB = 2 * w + 1;
    float* wpbuf = (float*)(smem + O_WP);

    // ---- zero LDS ----
    {
        uint4 z = {0u, 0u, 0u, 0u};
        ((uint4*)smem)[tid] = z;
        if (tid < LDS_BYTES / 16 - 512) ((uint4*)smem)[512 + tid] = z;
    }

    // ---- weights -> registers (2 tiles per wave; VSN2 in all waves) ----
    const f16x8 wl0_0A = ldfrag(ws + (tA * 3 + 0) * 256 + lane * 4);
    const f16x8 wl0_1A = ldfrag(ws + (tA * 3 + 1) * 256 + lane * 4);
    const f16x8 wl0_2A = ldfrag(ws + (tA * 3 + 2) * 256 + lane * 4);
    const f16x8 wl0_0B = ldfrag(ws + (tB * 3 + 0) * 256 + lane * 4);
    const f16x8 wl0_1B = ldfrag(ws + (tB * 3 + 1) * 256 + lane * 4);
    const f16x8 wl0_2B = ldfrag(ws + (tB * 3 + 2) * 256 + lane * 4);
    const f16x8 wl1_0A = ldfrag(ws + 12288 + (tA * 4 + 0) * 256 + lane * 4);
    const f16x8 wl1_1A = ldfrag(ws + 12288 + (tA * 4 + 1) * 256 + lane * 4);
    const f16x8 wl1_2A = ldfrag(ws + 12288 + (tA * 4 + 2) * 256 + lane * 4);
    const f16x8 wl1_3A = ldfrag(ws + 12288 + (tA * 4 + 3) * 256 + lane * 4);
    const f16x8 wl1_0B = ldfrag(ws + 12288 + (tB * 4 + 0) * 256 + lane * 4);
    const f16x8 wl1_1B = ldfrag(ws + 12288 + (tB * 4 + 1) * 256 + lane * 4);
    const f16x8 wl1_2B = ldfrag(ws + 12288 + (tB * 4 + 2) * 256 + lane * 4);
    const f16x8 wl1_3B = ldfrag(ws + 12288 + (tB * 4 + 3) * 256 + lane * 4);
    const f16x8 wv2_0 = ldfrag(ws + 29696 + lane * 4);
    const f16x8 wv2_1 = ldfrag(ws + 29696 + 256 + lane * 4);
    f16x8 wv1 = {};
    const float* wsf = (const float*)ws;
    if (w < 4) wv1 = ldfrag(ws + 28672 + w * 256 + lane * 4);
    const float4 b2f   = *(const float4*)(wsf + 31232 + lane * 4);
    const float4 bias1A = *(const float4*)(wsf + 35584 + (tA * 64 + lane) * 4);
    const float4 bias1B = *(const float4*)(wsf + 35584 + (tB * 64 + lane) * 4);
    const float wojA = Wo[8 * w + q];
    const float wojB = Wo[8 * w + 4 + q];
    const float bov  = bo[0];

    float c0A = 0.f, c0B = 0.f, c1A = 0.f, c1B = 0.f;
    f32x4 a0A = {0.f, 0.f, 0.f, 0.f};   // L0 acc carry (recurrent from C of t-1)
    f32x4 a0B = {0.f, 0.f, 0.f, 0.f};
    float4 px = {0.f, 0.f, 0.f, 0.f};
    __syncthreads();

    // ---- init: stage x(0); prefetch x(1) (wave 5 lanes) ----
    if (tid >= 320 && tid < 352) {
        int pb = (tid >> 1) & 15, ph = tid & 1;
        float4 x0 = *(const float4*)(feat + ((size_t)(b0 + pb) * NT) * 8 + 4 * ph);
        uint2 p2; p2.x = pkrtz(x0.x, x0.y); p2.y = pkrtz(x0.z, x0.w);
        *(uint2*)(smem + O_XB + pb * 16 + ph * 8) = p2;
        px = *(const float4*)(feat + ((size_t)(b0 + pb) * NT + 1) * 8 + 4 * ph);
    }
    __syncthreads();

    #pragma unroll 1
    for (int t = 0; t < NT; ++t) {
        // ==== A: L1 recurrent (shared h1 frags); delta(t-1) reduce; VSN1 ====
        f32x4 a1A = {bias1A.x, bias1A.y, bias1A.z, bias1A.w};
        f32x4 a1B = {bias1B.x, bias1B.y, bias1B.z, bias1B.w};
        {
            f16x8 h1a = *(const f16x8*)(smem + O_H1 + lane * 16);
            f16x8 h1b = *(const f16x8*)(smem + O_H1 + 1024 + lane * 16);
            a1A = __builtin_amdgcn_mfma_f32_16x16x32_f16(wl1_2A, h1a, a1A, 0, 0, 0);
            a1B = __builtin_amdgcn_mfma_f32_16x16x32_f16(wl1_2B, h1a, a1B, 0, 0, 0);
            a1A = __builtin_amdgcn_mfma_f32_16x16x32_f16(wl1_3A, h1b, a1A, 0, 0, 0);
            a1B = __builtin_amdgcn_mfma_f32_16x16x32_f16(wl1_3B, h1b, a1B, 0, 0, 0);
        }
        float dlt = 0.f;   // needed by q==1 (VSN1 input) and q==2 (softmax x8)
        if (t > 0 && (q == 1 || q == 2)) dlt = wp_reduce8(smem, cb) + bov;
        if (w == 0 && q == 1 && t > 0)
            out[(size_t)(b0 + cb) * NT + (t - 1)] = dlt;
        if (w < 4) {   // VSN1: hid = relu(W1 [x; delta; 1])
            union { uint4 u; f16x8 h; } xb;
            xb.u = (uint4){0u, 0u, 0u, 0u};
            if (q == 0)      xb.u = *(const uint4*)(smem + O_XB + cb * 16);
            else if (q == 1) xb.u.x = pkrtz(dlt, 1.0f);     // k8=delta, k9=1 (b1)
            f32x4 acc = {0.f, 0.f, 0.f, 0.f};
            acc = __builtin_amdgcn_mfma_f32_16x16x32_f16(wv1, xb.h, acc, 0, 0, 0);
            uint2 hw;
            hw.x = pkrtz(fmaxf(acc[0], 0.f), fmaxf(acc[1], 0.f));
            hw.y = pkrtz(fmaxf(acc[2], 0.f), fmaxf(acc[3], 0.f));
            *(uint2*)(smem + O_HID + ((2 * w + (q >> 1)) * 16 + cb) * 16 + (q & 1) * 8) = hw;
        }
        __syncthreads();   // hid ready

        // ==== B: VSN2 + softmax (redundant, all waves) + in-reg x~ redistribute
        //         + LSTM0 finish + h0 write ====
        {
            f16x8 hb0 = *(const f16x8*)(smem + O_HID + lane * 16);
            f16x8 hb1 = *(const f16x8*)(smem + O_HID + 1024 + lane * 16);
            f32x4 aA = {b2f.x, b2f.y, b2f.z, b2f.w};
            f32x4 aB = {0.f, 0.f, 0.f, 0.f};
            aA = __builtin_amdgcn_mfma_f32_16x16x32_f16(wv2_0, hb0, aA, 0, 0, 0);
            aB = __builtin_amdgcn_mfma_f32_16x16x32_f16(wv2_1, hb1, aB, 0, 0, 0);
            float e0 = fexp2(aA[0] + aB[0]);
            float e1 = fexp2(aA[1] + aB[1]);
            float e2 = fexp2(aA[2] + aB[2]);
            float e3 = fexp2(aA[3] + aB[3]);
            float sm = (e0 + e1) + (e2 + e3);
            sm += __shfl_xor(sm, 16, 64);
            sm += __shfl_xor(sm, 32, 64);
            float inv = frcp(sm);
            uint4 xw = *(const uint4*)(smem + O_XB + cb * 16);
            const __half* xh = (const __half*)&xw;
            float x0, x1, x2, x3;
            if (q == 0)      { x0 = __half2float(xh[0]); x1 = __half2float(xh[1]);
                               x2 = __half2float(xh[2]); x3 = __half2float(xh[3]); }
            else if (q == 1) { x0 = __half2float(xh[4]); x1 = __half2float(xh[5]);
                               x2 = __half2float(xh[6]); x3 = __half2float(xh[7]); }
            else if (q == 2) { x0 = dlt; x1 = x2 = x3 = 0.f; }
            else             { x0 = x1 = x2 = x3 = 0.f; }
            uint p01 = pkrtz(x0 * e0 * inv, x1 * e1 * inv);
            uint p23 = pkrtz(x2 * e2 * inv, x3 * e3 * inv);
            // C-rows -> B-frag k-layout (4 shfls); q=2 carries const-1 @k16 (bias0)
            int srcA = (((2 * q) & 3) << 4) + cb;
            int srcB = (((2 * q + 1) & 3) << 4) + cb;
            uint hA0 = (uint)__shfl((int)p01, srcA, 64);
            uint hA1 = (uint)__shfl((int)p23, srcA, 64);
            uint hB0 = (uint)__shfl((int)p01, srcB, 64);
            uint hB1 = (uint)__shfl((int)p23, srcB, 64);
            union { uint4 u; f16x8 h; } xs;
            if (q < 2)       xs.u = (uint4){hA0, hA1, hB0, hB1};
            else if (q == 2) xs.u = (uint4){0x3C00u, 0u, 0u, 0u};
            else             xs.u = (uint4){0u, 0u, 0u, 0u};
            a0A = __builtin_amdgcn_mfma_f32_16x16x32_f16(wl0_0A, xs.h, a0A, 0, 0, 0);
            a0B = __builtin_amdgcn_mfma_f32_16x16x32_f16(wl0_0B, xs.h, a0B, 0, 0, 0);
            float hA = lstm_out2(a0A, c0A);
            float hB = lstm_out2(a0B, c0B);
            *(unsigned short*)(smem + O_H0 + w * 256 + cb * 16 + q * 2)     = f16b(hA);
            *(unsigned short*)(smem + O_H0 + w * 256 + cb * 16 + 8 + q * 2) = f16b(hB);
        }
        __syncthreads();   // h0 ready

        // ==== C: LSTM1 finish (4 MFMA) + next-step L0 recurrent (4 MFMA,
        //         reusing h0 frags) + gates + delta partial + x stage ====
        {
            f16x8 h0a = *(const f16x8*)(smem + O_H0 + lane * 16);
            f16x8 h0b = *(const f16x8*)(smem + O_H0 + 1024 + lane * 16);
            a1A = __builtin_amdgcn_mfma_f32_16x16x32_f16(wl1_0A, h0a, a1A, 0, 0, 0);
            a1B = __builtin_amdgcn_mfma_f32_16x16x32_f16(wl1_0B, h0a, a1B, 0, 0, 0);
            a1A = __builtin_amdgcn_mfma_f32_16x16x32_f16(wl1_1A, h0b, a1A, 0, 0, 0);
            a1B = __builtin_amdgcn_mfma_f32_16x16x32_f16(wl1_1B, h0b, a1B, 0, 0, 0);
            f32x4 anA = {0.f, 0.f, 0.f, 0.f};
            f32x4 anB = {0.f, 0.f, 0.f, 0.f};
            anA = __builtin_amdgcn_mfma_f32_16x16x32_f16(wl0_1A, h0a, anA, 0, 0, 0);
            anB = __builtin_amdgcn_mfma_f32_16x16x32_f16(wl0_1B, h0a, anB, 0, 0, 0);
            anA = __builtin_amdgcn_mfma_f32_16x16x32_f16(wl0_2A, h0b, anA, 0, 0, 0);
            anB = __builtin_amdgcn_mfma_f32_16x16x32_f16(wl0_2B, h0b, anB, 0, 0, 0);
            a0A = anA; a0B = anB;
            float hA = lstm_out2(a1A, c1A);
            float hB = lstm_out2(a1B, c1B);
            *(unsigned short*)(smem + O_H1 + w * 256 + cb * 16 + q * 2)     = f16b(hA);
            *(unsigned short*)(smem + O_H1 + w * 256 + cb * 16 + 8 + q * 2) = f16b(hB);
            float p = fmaf(wojA, hA, wojB * hB);
            p += __shfl_xor(p, 16, 64);
            p += __shfl_xor(p, 32, 64);
            if (q == 0) wpbuf[cb * 20 + w] = p;
        }
        if (tid >= 320 && tid < 352) {   // wave 5: stage x(t+1), prefetch x(t+2)
            int pb = (tid >> 1) & 15, ph = tid & 1;
            uint2 p2; p2.x = pkrtz(px.x, px.y); p2.y = pkrtz(px.z, px.w);
            *(uint2*)(smem + O_XB + pb * 16 + ph * 8) = p2;
            if (t + 2 < NT)
                px = *(const float4*)(feat + ((size_t)(b0 + pb) * NT + (t + 2)) * 8 + 4 * ph);
        }
        __syncthreads();   // h1/WP/x ready for next step
    }

    // ---- epilogue: delta for t = 255 ----
    if (tid < 16)
        out[(size_t)(b0 + tid) * NT + (NT - 1)] = wp_reduce8(smem, tid) + bov;
}

extern "C" void kernel_launch(void* const* d_in, const int* in_sizes, int n_in,
                              void* d_out, int out_size, void* d_ws, size_t ws_size,
                              hipStream_t stream) {
    const float* feat = (const float*)d_in[0];
    const float* W1   = (const float*)d_in[1];
    const float* b1   = (const float*)d_in[2];
    const float* W2   = (const float*)d_in[3];
    const float* b2   = (const float*)d_in[4];
    const float* Wih0 = (const float*)d_in[5];
    const float* Whh0 = (const float*)d_in[6];
    const float* bih0 = (const float*)d_in[7];
    const float* bhh0 = (const float*)d_in[8];
    const float* Wih1 = (const float*)d_in[9];
    const float* Whh1 = (const float*)d_in[10];
    const float* bih1 = (const float*)d_in[11];
    const float* bhh1 = (const float*)d_in[12];
    const float* Wo   = (const float*)d_in[13];
    const float* bo   = (const float*)d_in[14];
    uint* ws   = (uint*)d_ws;
    float* out = (float*)d_out;

    hipLaunchKernelGGL(prep_kernel, dim3(40), dim3(1024), 0, stream,
                       W1, b1, W2, b2, Wih0, Whh0, bih0, bhh0,
                       Wih1, Whh1, bih1, bhh1, ws);
    // 256 blocks x 512 threads (8 waves): 16 batches/block, 1 block/CU
    hipLaunchKernelGGL(tft_main, dim3(256), dim3(512), 0, stream,
                       feat, Wo, bo, ws, out);
}

// Round 13
// 355.827 us; speedup vs baseline: 1.4899x; 1.0150x over previous
//
#include <hip/hip_runtime.h>
#include <hip/hip_fp16.h>
#include <math.h>

typedef unsigned int uint;
typedef _Float16 f16x8 __attribute__((ext_vector_type(8)));
typedef __fp16 fp16x2 __attribute__((ext_vector_type(2)));
typedef float f32x4 __attribute__((ext_vector_type(4)));

#define NT 256

// ---------------- ws layout (uint/f32 words) ----------------
// 0     : W_l0 frags [16 tiles][3 ksteps][64 lanes][4 uint] = 12288
//         gate-prescaled; s=0 carries prescaled bias0 at k=16 (const-1 input)
// 12288 : W_l1 frags [16][4][64][4] = 16384  (gate-prescaled)
// 28672 : W_v1 frags [4][64][4]  (b1 folded at k=9)          = 1024
// 29696 : W_v2 frags [2][64][4]  (x log2e)                   = 512
// 31232 : b2frag f32 [64][4]     (x log2e; -1e30 pads)       = 256
// 35584 : bias1frag f32 [16][64][4] (gate-prescaled)         = 4096

// ---------------- LDS (bytes), frag-linear ----------------
// B-operand granule g = (k>>3)*16 + batch, 16B per granule (halves k&7)
#define O_XB  0      // 1024  x ring: 4 slots x 256B (slot = t & 3)
#define O_HID 1280   // 2048  VSN hidden K=64
#define O_H0  3328   // 2048  h0 K=64
#define O_H1  5376   // 2048  h1 K=64
#define O_WP  7424   // 1280  f32 [16 batch][20] delta partials (w 0..7 used)
#define LDS_BYTES 8704

__device__ __forceinline__ float fexp2(float x) { return __builtin_amdgcn_exp2f(x); }
__device__ __forceinline__ float frcp(float x)  { return __builtin_amdgcn_rcpf(x); }

__device__ __forceinline__ uint pkrtz(float lo, float hi) {
    fp16x2 v = __builtin_amdgcn_cvt_pkrtz(lo, hi);
    return __builtin_bit_cast(uint, v);
}
__device__ __forceinline__ uint pack2(float lo, float hi) {
    return ((uint)__half_as_ushort(__float2half_rn(hi)) << 16) |
           (uint)__half_as_ushort(__float2half_rn(lo));
}
__device__ __forceinline__ unsigned short f16b(float x) {
    return __half_as_ushort(__float2half_rn(x));
}
__device__ __forceinline__ f16x8 ldfrag(const uint* p) {
    union { uint4 u; f16x8 h; } c;
    c.u = *(const uint4*)p;
    return c.h;
}
// gate rows prescaled: i,f,o by -log2(e); g by -2*log2(e)
__device__ __forceinline__ float lstm_out2(const f32x4 a, float& c) {
    float ii = frcp(1.0f + fexp2(a[0]));
    float ff = frcp(1.0f + fexp2(a[1]));
    float gg = fmaf(2.0f, frcp(1.0f + fexp2(a[2])), -1.0f);
    float oo = frcp(1.0f + fexp2(a[3]));
    c = fmaf(ff, c, ii * gg);
    return oo * fmaf(2.0f, frcp(1.0f + fexp2(-2.88539008f * c)), -1.0f);
}
// sum of 8 wave partials (waves 0..7)
__device__ __forceinline__ float wp_reduce8(const unsigned char* smem, int cb) {
    const float* wp = (const float*)(smem + O_WP) + cb * 20;
    float4 s0 = *(const float4*)(wp);
    float4 s1 = *(const float4*)(wp + 4);
    return ((s0.x + s0.y) + (s0.z + s0.w)) + ((s1.x + s1.y) + (s1.z + s1.w));
}

// A-frag (16x16x32 f16): lane l holds A[row16=l&15][k=(l>>4)*8+e].
// LSTM tiles gate-interleaved: row16 -> R = (row16&3)*64 + 4*tile + (row16>>2).
__global__ __launch_bounds__(1024)
void prep_kernel(const float* __restrict__ W1,  const float* __restrict__ b1,
                 const float* __restrict__ W2,  const float* __restrict__ b2,
                 const float* __restrict__ Wih0, const float* __restrict__ Whh0,
                 const float* __restrict__ bih0, const float* __restrict__ bhh0,
                 const float* __restrict__ Wih1, const float* __restrict__ Whh1,
                 const float* __restrict__ bih1, const float* __restrict__ bhh1,
                 uint* __restrict__ ws)
{
    const int tid = blockIdx.x * 1024 + threadIdx.x;
    float* wsf = (float*)ws;
    const float LOG2E = 1.44269504f;

    if (tid < 12288) {                               // W_l0 (prescaled)
        int v = tid & 3, l = (tid >> 2) & 63, ts = tid >> 8;
        int s = ts % 3, w = ts / 3;
        int g = l & 3;
        float sc = (g == 2) ? -2.0f * LOG2E : -LOG2E;
        int R = g * 64 + 4 * w + ((l >> 2) & 3);
        int k0 = (l >> 4) * 8 + 2 * v;
        float lo = 0.f, hi = 0.f;
        if (s == 0) {
            if (k0     < 9) lo = Wih0[R * 9 + k0];
            if (k0 + 1 < 9) hi = Wih0[R * 9 + k0 + 1];
            if (k0 == 16)   lo = bih0[R] + bhh0[R];   // bias0 via const-1 at k16
        } else {
            int kh = 32 * (s - 1) + k0;
            lo = Whh0[R * 64 + kh]; hi = Whh0[R * 64 + kh + 1];
        }
        ws[tid] = pack2(lo * sc, hi * sc);
    } else if (tid < 28672) {                        // W_l1 (prescaled)
        int idx = tid - 12288;
        int v = idx & 3, l = (idx >> 2) & 63, ts = idx >> 8;
        int s = ts & 3, w = ts >> 2;
        int g = l & 3;
        float sc = (g == 2) ? -2.0f * LOG2E : -LOG2E;
        int R = g * 64 + 4 * w + ((l >> 2) & 3);
        int kt = 32 * s + (l >> 4) * 8 + 2 * v;
        float lo, hi;
        if (kt < 64) { lo = Wih1[R * 64 + kt];      hi = Wih1[R * 64 + kt + 1]; }
        else         { lo = Whh1[R * 64 + kt - 64]; hi = Whh1[R * 64 + kt - 63]; }
        ws[tid] = pack2(lo * sc, hi * sc);
    } else if (tid < 29696) {                        // W_v1 (b1 folded at k=9)
        int idx = tid - 28672;
        int v = idx & 3, l = (idx >> 2) & 63, m = idx >> 8;
        int j2 = 16 * m + (l & 15);
        int k0 = (l >> 4) * 8 + 2 * v;
        float lo = (k0 < 9) ? W1[j2 * 9 + k0] : 0.f;
        float hi = 0.f;
        if (k0 + 1 < 9)       hi = W1[j2 * 9 + k0 + 1];
        else if (k0 + 1 == 9) hi = b1[j2];
        ws[tid] = pack2(lo, hi);
    } else if (tid < 30208) {                        // W_v2 (x log2e)
        int idx = tid - 29696;
        int v = idx & 3, l = (idx >> 2) & 63, s = idx >> 8;
        int rr = l & 15;
        int k0 = 32 * s + (l >> 4) * 8 + 2 * v;
        float lo = (rr < 9) ? W2[rr * 64 + k0] * LOG2E     : 0.f;
        float hi = (rr < 9) ? W2[rr * 64 + k0 + 1] * LOG2E : 0.f;
        ws[tid] = pack2(lo, hi);
    } else if (tid >= 31232 && tid < 31488) {        // b2frag (x log2e, -1e30 pads)
        int idx = tid - 31232;
        int r = idx & 3, l = idx >> 2;
        int row = (l >> 4) * 4 + r;
        wsf[tid] = (row < 9) ? b2[row] * LOG2E : -1e30f;
    } else if (tid >= 35584 && tid < 39680) {        // bias1frag (prescaled)
        int idx = tid - 35584;
        int r = idx & 3, l = (idx >> 2) & 63, w = idx >> 8;
        float sc = (r == 2) ? -2.0f * LOG2E : -LOG2E;
        int R = r * 64 + 4 * w + (l >> 4);
        wsf[tid] = (bih1[R] + bhh1[R]) * sc;
    }
}

// 256 blocks x 512 threads (8 waves), 16 batches/block, 1 block/CU.
// Wave w owns tiles tA=2w, tB=2w+1. 3-phase schedule (R11) with 4x-unrolled
// time loop: feat loads and delta stores batched to once per 4 steps so the
// pre-barrier vmcnt(0) drain is paid 1/4 as often.
__global__ __launch_bounds__(512)
void tft_main(const float* __restrict__ feat,
              const float* __restrict__ Wo, const float* __restrict__ bo,
              const uint* __restrict__ ws,
              float* __restrict__ out)
{
    __shared__ unsigned char smem[LDS_BYTES];
    const int tid  = threadIdx.x;
    const int lane = tid & 63;
    const int w    = tid >> 6;        // 0..7
    const int q    = lane >> 4;       // 0..3
    const int cb   = lane & 15;       // batch column (all 16 real)
    const int b0   = blockIdx.x * 16;
    const int tA   = 2 * w, tB = 2 * w + 1;
    float* wpbuf = (float*)(smem + O_WP);

    // ---- zero LDS ----
    {
        uint4 z = {0u, 0u, 0u, 0u};
        ((uint4*)smem)[tid] = z;
        if (tid < LDS_BYTES / 16 - 512) ((uint4*)smem)[512 + tid] = z;
    }

    // ---- weights -> registers (2 tiles per wave; VSN2 in all waves) ----
    const f16x8 wl0_0A = ldfrag(ws + (tA * 3 + 0) * 256 + lane * 4);
    const f16x8 wl0_1A = ldfrag(ws + (tA * 3 + 1) * 256 + lane * 4);
    const f16x8 wl0_2A = ldfrag(ws + (tA * 3 + 2) * 256 + lane * 4);
    const f16x8 wl0_0B = ldfrag(ws + (tB * 3 + 0) * 256 + lane * 4);
    const f16x8 wl0_1B = ldfrag(ws + (tB * 3 + 1) * 256 + lane * 4);
    const f16x8 wl0_2B = ldfrag(ws + (tB * 3 + 2) * 256 + lane * 4);
    const f16x8 wl1_0A = ldfrag(ws + 12288 + (tA * 4 + 0) * 256 + lane * 4);
    const f16x8 wl1_1A = ldfrag(ws + 12288 + (tA * 4 + 1) * 256 + lane * 4);
    const f16x8 wl1_2A = ldfrag(ws + 12288 + (tA * 4 + 2) * 256 + lane * 4);
    const f16x8 wl1_3A = ldfrag(ws + 12288 + (tA * 4 + 3) * 256 + lane * 4);
    const f16x8 wl1_0B = ldfrag(ws + 12288 + (tB * 4 + 0) * 256 + lane * 4);
    const f16x8 wl1_1B = ldfrag(ws + 12288 + (tB * 4 + 1) * 256 + lane * 4);
    const f16x8 wl1_2B = ldfrag(ws + 12288 + (tB * 4 + 2) * 256 + lane * 4);
    const f16x8 wl1_3B = ldfrag(ws + 12288 + (tB * 4 + 3) * 256 + lane * 4);
    const f16x8 wv2_0 = ldfrag(ws + 29696 + lane * 4);
    const f16x8 wv2_1 = ldfrag(ws + 29696 + 256 + lane * 4);
    f16x8 wv1 = {};
    const float* wsf = (const float*)ws;
    if (w < 4) wv1 = ldfrag(ws + 28672 + w * 256 + lane * 4);
    const float4 b2f   = *(const float4*)(wsf + 31232 + lane * 4);
    const float4 bias1A = *(const float4*)(wsf + 35584 + (tA * 64 + lane) * 4);
    const float4 bias1B = *(const float4*)(wsf + 35584 + (tB * 64 + lane) * 4);
    const float wojA = Wo[8 * w + q];
    const float wojB = Wo[8 * w + 4 + q];
    const float bov  = bo[0];

    float c0A = 0.f, c0B = 0.f, c1A = 0.f, c1B = 0.f;
    f32x4 a0A = {0.f, 0.f, 0.f, 0.f};   // L0 acc carry (recurrent from C of t-1)
    f32x4 a0B = {0.f, 0.f, 0.f, 0.f};
    float4 px   = {0.f, 0.f, 0.f, 0.f}; // staged x, 128 lanes (waves 5-6)
    float4 dout = {0.f, 0.f, 0.f, 0.f}; // 4 deltas, (w0,q1) lanes
    __syncthreads();

    // ---- init: stage x(0..3) into ring; prefetch x(4..7) ----
    if (tid >= 320 && tid < 448) {
        int L = tid - 320, pb = L >> 3, ti = (L >> 1) & 3, ph = L & 1;
        float4 x0 = *(const float4*)(feat + ((size_t)(b0 + pb) * NT + ti) * 8 + 4 * ph);
        uint2 p2; p2.x = pkrtz(x0.x, x0.y); p2.y = pkrtz(x0.z, x0.w);
        *(uint2*)(smem + O_XB + ti * 256 + pb * 16 + ph * 8) = p2;
        px = *(const float4*)(feat + ((size_t)(b0 + pb) * NT + 4 + ti) * 8 + 4 * ph);
    }
    __syncthreads();

    #pragma unroll 1
    for (int tb = 0; tb < NT; tb += 4) {
        #pragma unroll
        for (int u = 0; u < 4; ++u) {
            const int t = tb + u;
            // ==== A: L1 recurrent; delta(t-1) reduce; batched out store; VSN1 ====
            f32x4 a1A = {bias1A.x, bias1A.y, bias1A.z, bias1A.w};
            f32x4 a1B = {bias1B.x, bias1B.y, bias1B.z, bias1B.w};
            {
                f16x8 h1a = *(const f16x8*)(smem + O_H1 + lane * 16);
                f16x8 h1b = *(const f16x8*)(smem + O_H1 + 1024 + lane * 16);
                a1A = __builtin_amdgcn_mfma_f32_16x16x32_f16(wl1_2A, h1a, a1A, 0, 0, 0);
                a1B = __builtin_amdgcn_mfma_f32_16x16x32_f16(wl1_2B, h1a, a1B, 0, 0, 0);
                a1A = __builtin_amdgcn_mfma_f32_16x16x32_f16(wl1_3A, h1b, a1A, 0, 0, 0);
                a1B = __builtin_amdgcn_mfma_f32_16x16x32_f16(wl1_3B, h1b, a1B, 0, 0, 0);
            }
            float dlt = 0.f;   // delta(t-1): q==1 (VSN input), q==2 (softmax x8)
            if (t > 0 && (q == 1 || q == 2)) dlt = wp_reduce8(smem, cb) + bov;
            if (w == 0 && q == 1) {            // batched output (aligned float4)
                if (u == 1)      dout.x = dlt;
                else if (u == 2) dout.y = dlt;
                else if (u == 3) dout.z = dlt;
                else if (t > 0) {              // u == 0
                    dout.w = dlt;
                    *(float4*)(out + (size_t)(b0 + cb) * NT + (t - 4)) = dout;
                }
            }
            if (w < 4) {   // VSN1: hid = relu(W1 [x; delta; 1])
                union { uint4 u4; f16x8 h; } xb;
                xb.u4 = (uint4){0u, 0u, 0u, 0u};
                if (q == 0)      xb.u4 = *(const uint4*)(smem + O_XB + u * 256 + cb * 16);
                else if (q == 1) xb.u4.x = pkrtz(dlt, 1.0f);   // k8=delta, k9=1 (b1)
                f32x4 acc = {0.f, 0.f, 0.f, 0.f};
                acc = __builtin_amdgcn_mfma_f32_16x16x32_f16(wv1, xb.h, acc, 0, 0, 0);
                uint2 hw;
                hw.x = pkrtz(fmaxf(acc[0], 0.f), fmaxf(acc[1], 0.f));
                hw.y = pkrtz(fmaxf(acc[2], 0.f), fmaxf(acc[3], 0.f));
                *(uint2*)(smem + O_HID + ((2 * w + (q >> 1)) * 16 + cb) * 16 + (q & 1) * 8) = hw;
            }
            __syncthreads();   // hid ready

            // ==== B: VSN2 + softmax (redundant) + in-reg x~ shfl + LSTM0 ====
            {
                f16x8 hb0 = *(const f16x8*)(smem + O_HID + lane * 16);
                f16x8 hb1 = *(const f16x8*)(smem + O_HID + 1024 + lane * 16);
                f32x4 aA = {b2f.x, b2f.y, b2f.z, b2f.w};
                f32x4 aB = {0.f, 0.f, 0.f, 0.f};
                aA = __builtin_amdgcn_mfma_f32_16x16x32_f16(wv2_0, hb0, aA, 0, 0, 0);
                aB = __builtin_amdgcn_mfma_f32_16x16x32_f16(wv2_1, hb1, aB, 0, 0, 0);
                float e0 = fexp2(aA[0] + aB[0]);
                float e1 = fexp2(aA[1] + aB[1]);
                float e2 = fexp2(aA[2] + aB[2]);
                float e3 = fexp2(aA[3] + aB[3]);
                float sm = (e0 + e1) + (e2 + e3);
                sm += __shfl_xor(sm, 16, 64);
                sm += __shfl_xor(sm, 32, 64);
                float inv = frcp(sm);
                uint4 xw = *(const uint4*)(smem + O_XB + u * 256 + cb * 16);
                const __half* xh = (const __half*)&xw;
                float x0, x1, x2, x3;
                if (q == 0)      { x0 = __half2float(xh[0]); x1 = __half2float(xh[1]);
                                   x2 = __half2float(xh[2]); x3 = __half2float(xh[3]); }
                else if (q == 1) { x0 = __half2float(xh[4]); x1 = __half2float(xh[5]);
                                   x2 = __half2float(xh[6]); x3 = __half2float(xh[7]); }
                else if (q == 2) { x0 = dlt; x1 = x2 = x3 = 0.f; }
                else             { x0 = x1 = x2 = x3 = 0.f; }
                uint p01 = pkrtz(x0 * e0 * inv, x1 * e1 * inv);
                uint p23 = pkrtz(x2 * e2 * inv, x3 * e3 * inv);
                // C-rows -> B-frag k-layout (4 shfls); q=2 carries const-1 @k16
                int srcA = (((2 * q) & 3) << 4) + cb;
                int srcB = (((2 * q + 1) & 3) << 4) + cb;
                uint hA0 = (uint)__shfl((int)p01, srcA, 64);
                uint hA1 = (uint)__shfl((int)p23, srcA, 64);
                uint hB0 = (uint)__shfl((int)p01, srcB, 64);
                uint hB1 = (uint)__shfl((int)p23, srcB, 64);
                union { uint4 u4; f16x8 h; } xs;
                if (q < 2)       xs.u4 = (uint4){hA0, hA1, hB0, hB1};
                else if (q == 2) xs.u4 = (uint4){0x3C00u, 0u, 0u, 0u};
                else             xs.u4 = (uint4){0u, 0u, 0u, 0u};
                a0A = __builtin_amdgcn_mfma_f32_16x16x32_f16(wl0_0A, xs.h, a0A, 0, 0, 0);
                a0B = __builtin_amdgcn_mfma_f32_16x16x32_f16(wl0_0B, xs.h, a0B, 0, 0, 0);
                float hA = lstm_out2(a0A, c0A);
                float hB = lstm_out2(a0B, c0B);
                *(unsigned short*)(smem + O_H0 + w * 256 + cb * 16 + q * 2)     = f16b(hA);
                *(unsigned short*)(smem + O_H0 + w * 256 + cb * 16 + 8 + q * 2) = f16b(hB);
            }
            __syncthreads();   // h0 ready

            // ==== C: LSTM1 finish + next-step L0 recurrent + h1/wp write
            //         + (u==3 only) x ring staging + batched prefetch ====
            {
                f16x8 h0a = *(const f16x8*)(smem + O_H0 + lane * 16);
                f16x8 h0b = *(const f16x8*)(smem + O_H0 + 1024 + lane * 16);
                a1A = __builtin_amdgcn_mfma_f32_16x16x32_f16(wl1_0A, h0a, a1A, 0, 0, 0);
                a1B = __builtin_amdgcn_mfma_f32_16x16x32_f16(wl1_0B, h0a, a1B, 0, 0, 0);
                a1A = __builtin_amdgcn_mfma_f32_16x16x32_f16(wl1_1A, h0b, a1A, 0, 0, 0);
                a1B = __builtin_amdgcn_mfma_f32_16x16x32_f16(wl1_1B, h0b, a1B, 0, 0, 0);
                f32x4 anA = {0.f, 0.f, 0.f, 0.f};
                f32x4 anB = {0.f, 0.f, 0.f, 0.f};
                anA = __builtin_amdgcn_mfma_f32_16x16x32_f16(wl0_1A, h0a, anA, 0, 0, 0);
                anB = __builtin_amdgcn_mfma_f32_16x16x32_f16(wl0_1B, h0a, anB, 0, 0, 0);
                anA = __builtin_amdgcn_mfma_f32_16x16x32_f16(wl0_2A, h0b, anA, 0, 0, 0);
                anB = __builtin_amdgcn_mfma_f32_16x16x32_f16(wl0_2B, h0b, anB, 0, 0, 0);
                a0A = anA; a0B = anB;
                float hA = lstm_out2(a1A, c1A);
                float hB = lstm_out2(a1B, c1B);
                *(unsigned short*)(smem + O_H1 + w * 256 + cb * 16 + q * 2)     = f16b(hA);
                *(unsigned short*)(smem + O_H1 + w * 256 + cb * 16 + 8 + q * 2) = f16b(hB);
                float p = fmaf(wojA, hA, wojB * hB);
                p += __shfl_xor(p, 16, 64);
                p += __shfl_xor(p, 32, 64);
                if (q == 0) wpbuf[cb * 20 + w] = p;
            }
            if (u == 3 && tid >= 320 && tid < 448) {   // waves 5-6: ring restock
                int L = tid - 320, pb = L >> 3, ti = (L >> 1) & 3, ph = L & 1;
                uint2 p2; p2.x = pkrtz(px.x, px.y); p2.y = pkrtz(px.z, px.w);
                *(uint2*)(smem + O_XB + ti * 256 + pb * 16 + ph * 8) = p2;
                int tt = tb + 8 + ti;                  // next-next group
                if (tt < NT)
                    px = *(const float4*)(feat + ((size_t)(b0 + pb) * NT + tt) * 8 + 4 * ph);
            }
            __syncthreads();   // h1/WP/x ready for next step
        }
    }

    // ---- epilogue: finalize deltas for t = 252..255 ----
    if (w == 0 && q == 1) {
        dout.w = wp_reduce8(smem, cb) + bov;
        *(float4*)(out + (size_t)(b0 + cb) * NT + (NT - 4)) = dout;
    }
}

extern "C" void kernel_launch(void* const* d_in, const int* in_sizes, int n_in,
                              void* d_out, int out_size, void* d_ws, size_t ws_size,
                              hipStream_t stream) {
    const float* feat = (const float*)d_in[0];
    const float* W1   = (const float*)d_in[1];
    const float* b1   = (const float*)d_in[2];
    const float* W2   = (const float*)d_in[3];
    const float* b2   = (const float*)d_in[4];
    const float* Wih0 = (const float*)d_in[5];
    const float* Whh0 = (const float*)d_in[6];
    const float* bih0 = (const float*)d_in[7];
    const float* bhh0 = (const float*)d_in[8];
    const float* Wih1 = (const float*)d_in[9];
    const float* Whh1 = (const float*)d_in[10];
    const float* bih1 = (const float*)d_in[11];
    const float* bhh1 = (const float*)d_in[12];
    const float* Wo   = (const float*)d_in[13];
    const float* bo   = (const float*)d_in[14];
    uint* ws   = (uint*)d_ws;
    float* out = (float*)d_out;

    hipLaunchKernelGGL(prep_kernel, dim3(40), dim3(1024), 0, stream,
                       W1, b1, W2, b2, Wih0, Whh0, bih0, bhh0,
                       Wih1, Whh1, bih1, bhh1, ws);
    // 256 blocks x 512 threads (8 waves): 16 batches/block, 1 block/CU
    hipLaunchKernelGGL(tft_main, dim3(256), dim3(512), 0, stream,
                       feat, Wo, bo, ws, out);
}

// Round 14
// 353.196 us; speedup vs baseline: 1.5010x; 1.0074x over previous
//
#include <hip/hip_runtime.h>
#include <hip/hip_fp16.h>
#include <math.h>

typedef unsigned int uint;
typedef _Float16 f16x8 __attribute__((ext_vector_type(8)));
typedef __fp16 fp16x2 __attribute__((ext_vector_type(2)));
typedef float f32x4 __attribute__((ext_vector_type(4)));

#define NT 256

// ---------------- ws layout (uint/f32 words) ----------------
// 0     : W_l0 frags [16 tiles][3 ksteps][64 lanes][4 uint] = 12288
//         gate-prescaled; s=0 carries prescaled bias0 at k=16 (const-1 input)
// 12288 : W_l1 frags [16][4][64][4] = 16384  (gate-prescaled)
// 28672 : W_v1 frags [4][64][4]  (b1 folded at k=9)          = 1024
// 29696 : W_v2 frags [2][64][4]  (x log2e)                   = 512
// 31232 : b2frag f32 [64][4]     (x log2e; -1e30 pads)       = 256
// 35584 : bias1frag f32 [16][64][4] (gate-prescaled)         = 4096

// ---------------- LDS (bytes) ----------------
// XB : x ring, 8 slots x 256B; slot s granule cb holds x_t(k0..7) f16
// PXH: prehid ring, 2 slots x 6144B; granule g=(j>>3)*16+cb, stride 48B,
//      words (j&7) f32.  prehid = W1.[x;0;1]+b1 (pre-relu, pre-delta)
#define O_XB   0      // 2048
#define O_PXH  2048   // 12288
#define O_H0   14336  // 2048  h0 K=64 frag-linear (16B granules)
#define O_H1   16384  // 2048  h1 K=64
#define O_WP   18432  // 1280  f32 [16 batch][20] delta partials (w 0..7)
#define LDS_BYTES 19712

__device__ __forceinline__ float fexp2(float x) { return __builtin_amdgcn_exp2f(x); }
__device__ __forceinline__ float frcp(float x)  { return __builtin_amdgcn_rcpf(x); }

__device__ __forceinline__ uint pkrtz(float lo, float hi) {
    fp16x2 v = __builtin_amdgcn_cvt_pkrtz(lo, hi);
    return __builtin_bit_cast(uint, v);
}
__device__ __forceinline__ uint pack2(float lo, float hi) {
    return ((uint)__half_as_ushort(__float2half_rn(hi)) << 16) |
           (uint)__half_as_ushort(__float2half_rn(lo));
}
__device__ __forceinline__ unsigned short f16b(float x) {
    return __half_as_ushort(__float2half_rn(x));
}
__device__ __forceinline__ f16x8 ldfrag(const uint* p) {
    union { uint4 u; f16x8 h; } c;
    c.u = *(const uint4*)p;
    return c.h;
}
// gate rows prescaled: i,f,o by -log2(e); g by -2*log2(e)
__device__ __forceinline__ float lstm_out2(const f32x4 a, float& c) {
    float ii = frcp(1.0f + fexp2(a[0]));
    float ff = frcp(1.0f + fexp2(a[1]));
    float gg = fmaf(2.0f, frcp(1.0f + fexp2(a[2])), -1.0f);
    float oo = frcp(1.0f + fexp2(a[3]));
    c = fmaf(ff, c, ii * gg);
    return oo * fmaf(2.0f, frcp(1.0f + fexp2(-2.88539008f * c)), -1.0f);
}
__device__ __forceinline__ float wp_reduce8(const unsigned char* smem, int cb) {
    const float* wp = (const float*)(smem + O_WP) + cb * 20;
    float4 s0 = *(const float4*)(wp);
    float4 s1 = *(const float4*)(wp + 4);
    return ((s0.x + s0.y) + (s0.z + s0.w)) + ((s1.x + s1.y) + (s1.z + s1.w));
}

// A-frag (16x16x32 f16): lane l holds A[row16=l&15][k=(l>>4)*8+e].
// LSTM tiles gate-interleaved: row16 -> R = (row16&3)*64 + 4*tile + (row16>>2).
__global__ __launch_bounds__(1024)
void prep_kernel(const float* __restrict__ W1,  const float* __restrict__ b1,
                 const float* __restrict__ W2,  const float* __restrict__ b2,
                 const float* __restrict__ Wih0, const float* __restrict__ Whh0,
                 const float* __restrict__ bih0, const float* __restrict__ bhh0,
                 const float* __restrict__ Wih1, const float* __restrict__ Whh1,
                 const float* __restrict__ bih1, const float* __restrict__ bhh1,
                 uint* __restrict__ ws)
{
    const int tid = blockIdx.x * 1024 + threadIdx.x;
    float* wsf = (float*)ws;
    const float LOG2E = 1.44269504f;

    if (tid < 12288) {                               // W_l0 (prescaled)
        int v = tid & 3, l = (tid >> 2) & 63, ts = tid >> 8;
        int s = ts % 3, w = ts / 3;
        int g = l & 3;
        float sc = (g == 2) ? -2.0f * LOG2E : -LOG2E;
        int R = g * 64 + 4 * w + ((l >> 2) & 3);
        int k0 = (l >> 4) * 8 + 2 * v;
        float lo = 0.f, hi = 0.f;
        if (s == 0) {
            if (k0     < 9) lo = Wih0[R * 9 + k0];
            if (k0 + 1 < 9) hi = Wih0[R * 9 + k0 + 1];
            if (k0 == 16)   lo = bih0[R] + bhh0[R];   // bias0 via const-1 at k16
        } else {
            int kh = 32 * (s - 1) + k0;
            lo = Whh0[R * 64 + kh]; hi = Whh0[R * 64 + kh + 1];
        }
        ws[tid] = pack2(lo * sc, hi * sc);
    } else if (tid < 28672) {                        // W_l1 (prescaled)
        int idx = tid - 12288;
        int v = idx & 3, l = (idx >> 2) & 63, ts = idx >> 8;
        int s = ts & 3, w = ts >> 2;
        int g = l & 3;
        float sc = (g == 2) ? -2.0f * LOG2E : -LOG2E;
        int R = g * 64 + 4 * w + ((l >> 2) & 3);
        int kt = 32 * s + (l >> 4) * 8 + 2 * v;
        float lo, hi;
        if (kt < 64) { lo = Wih1[R * 64 + kt];      hi = Wih1[R * 64 + kt + 1]; }
        else         { lo = Whh1[R * 64 + kt - 64]; hi = Whh1[R * 64 + kt - 63]; }
        ws[tid] = pack2(lo * sc, hi * sc);
    } else if (tid < 29696) {                        // W_v1 (b1 folded at k=9)
        int idx = tid - 28672;
        int v = idx & 3, l = (idx >> 2) & 63, m = idx >> 8;
        int j2 = 16 * m + (l & 15);
        int k0 = (l >> 4) * 8 + 2 * v;
        float lo = (k0 < 9) ? W1[j2 * 9 + k0] : 0.f;
        float hi = 0.f;
        if (k0 + 1 < 9)       hi = W1[j2 * 9 + k0 + 1];
        else if (k0 + 1 == 9) hi = b1[j2];
        if (k0 == 8) lo = 0.f;                       // delta column handled in-reg
        ws[tid] = pack2(lo, hi);
    } else if (tid < 30208) {                        // W_v2 (x log2e)
        int idx = tid - 29696;
        int v = idx & 3, l = (idx >> 2) & 63, s = idx >> 8;
        int rr = l & 15;
        int k0 = 32 * s + (l >> 4) * 8 + 2 * v;
        float lo = (rr < 9) ? W2[rr * 64 + k0] * LOG2E     : 0.f;
        float hi = (rr < 9) ? W2[rr * 64 + k0 + 1] * LOG2E : 0.f;
        ws[tid] = pack2(lo, hi);
    } else if (tid >= 31232 && tid < 31488) {        // b2frag (x log2e, -1e30 pads)
        int idx = tid - 31232;
        int r = idx & 3, l = idx >> 2;
        int row = (l >> 4) * 4 + r;
        wsf[tid] = (row < 9) ? b2[row] * LOG2E : -1e30f;
    } else if (tid >= 35584 && tid < 39680) {        // bias1frag (prescaled)
        int idx = tid - 35584;
        int r = idx & 3, l = (idx >> 2) & 63, w = idx >> 8;
        float sc = (r == 2) ? -2.0f * LOG2E : -LOG2E;
        int R = r * 64 + 4 * w + (l >> 4);
        wsf[tid] = (bih1[R] + bhh1[R]) * sc;
    }
}

// 256 blocks x 512 threads (8 waves), 16 batches/block, 1 block/CU.
// 2-phase schedule. VSN1's x-part (prehid) is precomputed one step ahead
// (phase B, waves 0-3) -> the in-loop hid is a pure in-register rank-1
// update hid = relu(prehid + w1col8*delta). Only h0 and h1 LDS round
// trips remain on the serial chain.
__global__ __launch_bounds__(512, 2)
void tft_main(const float* __restrict__ feat,
              const float* __restrict__ W1,
              const float* __restrict__ Wo, const float* __restrict__ bo,
              const uint* __restrict__ ws,
              float* __restrict__ out)
{
    __shared__ unsigned char smem[LDS_BYTES];
    const int tid  = threadIdx.x;
    const int lane = tid & 63;
    const int w    = tid >> 6;        // 0..7
    const int q    = lane >> 4;       // 0..3
    const int cb   = lane & 15;       // batch column
    const int b0   = blockIdx.x * 16;
    const int tA   = 2 * w, tB = 2 * w + 1;
    float* wpbuf = (float*)(smem + O_WP);

    // ---- zero LDS ----
    {
        uint4 z = {0u, 0u, 0u, 0u};
        #pragma unroll
        for (int i = 0; i < 3; ++i) {
            int idx = tid + i * 512;
            if (idx < LDS_BYTES / 16) ((uint4*)smem)[idx] = z;
        }
    }

    // ---- weights -> registers ----
    const f16x8 wl0_0A = ldfrag(ws + (tA * 3 + 0) * 256 + lane * 4);
    const f16x8 wl0_1A = ldfrag(ws + (tA * 3 + 1) * 256 + lane * 4);
    const f16x8 wl0_2A = ldfrag(ws + (tA * 3 + 2) * 256 + lane * 4);
    const f16x8 wl0_0B = ldfrag(ws + (tB * 3 + 0) * 256 + lane * 4);
    const f16x8 wl0_1B = ldfrag(ws + (tB * 3 + 1) * 256 + lane * 4);
    const f16x8 wl0_2B = ldfrag(ws + (tB * 3 + 2) * 256 + lane * 4);
    const f16x8 wl1_0A = ldfrag(ws + 12288 + (tA * 4 + 0) * 256 + lane * 4);
    const f16x8 wl1_1A = ldfrag(ws + 12288 + (tA * 4 + 1) * 256 + lane * 4);
    const f16x8 wl1_2A = ldfrag(ws + 12288 + (tA * 4 + 2) * 256 + lane * 4);
    const f16x8 wl1_3A = ldfrag(ws + 12288 + (tA * 4 + 3) * 256 + lane * 4);
    const f16x8 wl1_0B = ldfrag(ws + 12288 + (tB * 4 + 0) * 256 + lane * 4);
    const f16x8 wl1_1B = ldfrag(ws + 12288 + (tB * 4 + 1) * 256 + lane * 4);
    const f16x8 wl1_2B = ldfrag(ws + 12288 + (tB * 4 + 2) * 256 + lane * 4);
    const f16x8 wl1_3B = ldfrag(ws + 12288 + (tB * 4 + 3) * 256 + lane * 4);
    const f16x8 wv2_0 = ldfrag(ws + 29696 + lane * 4);
    const f16x8 wv2_1 = ldfrag(ws + 29696 + 256 + lane * 4);
    f16x8 wv1 = {};
    const float* wsf = (const float*)ws;
    if (w < 4) wv1 = ldfrag(ws + 28672 + w * 256 + lane * 4);
    const float4 b2f   = *(const float4*)(wsf + 31232 + lane * 4);
    const float4 bias1A = *(const float4*)(wsf + 35584 + (tA * 64 + lane) * 4);
    const float4 bias1B = *(const float4*)(wsf + 35584 + (tB * 64 + lane) * 4);
    const float wojA = Wo[8 * w + q];
    const float wojB = Wo[8 * w + 4 + q];
    const float bov  = bo[0];
    // W1 delta-column (col 8) for this lane's hid indices j=q*8+e / 32+q*8+e
    float w8a[8], w8b[8];
    #pragma unroll
    for (int e = 0; e < 8; ++e) {
        w8a[e] = W1[(q * 8 + e) * 9 + 8];
        w8b[e] = W1[(32 + q * 8 + e) * 9 + 8];
    }

    float c0A = 0.f, c0B = 0.f, c1A = 0.f, c1B = 0.f;
    f32x4 a0A = {0.f, 0.f, 0.f, 0.f};   // L0 acc carry (recurrent from B of t-1)
    f32x4 a0B = {0.f, 0.f, 0.f, 0.f};
    float4 px   = {0.f, 0.f, 0.f, 0.f}; // x prefetch (tid 256..383)
    float4 dout = {0.f, 0.f, 0.f, 0.f}; // 4 deltas (w0,q1)
    __syncthreads();

    // ---- init: stage x(0..7) into 8-slot ring; px <- x(8..11) ----
    if (tid >= 256) {                       // 256 threads: slots 0..7
        int L = tid - 256, pb = L >> 4, ti = (L >> 1) & 7, ph = L & 1;
        float4 x0 = *(const float4*)(feat + ((size_t)(b0 + pb) * NT + ti) * 8 + 4 * ph);
        uint2 p2; p2.x = pkrtz(x0.x, x0.y); p2.y = pkrtz(x0.z, x0.w);
        *(uint2*)(smem + O_XB + ti * 256 + pb * 16 + ph * 8) = p2;
    }
    if (tid >= 256 && tid < 384) {          // restock lanes: px = x(8+ti)
        int L = tid - 256, pb = L >> 3, ti = (L >> 1) & 3, ph = L & 1;
        px = *(const float4*)(feat + ((size_t)(b0 + pb) * NT + 8 + ti) * 8 + 4 * ph);
    }
    __syncthreads();

    // ---- init: prehid slot 0 = W1.[x(0);0;1]+b1 (waves 0-3) ----
    if (w < 4) {
        union { uint4 u4; f16x8 h; } xb;
        xb.u4 = (uint4){0u, 0u, 0u, 0u};
        if (q == 0)      xb.u4 = *(const uint4*)(smem + O_XB + cb * 16);
        else if (q == 1) xb.u4.x = 0x3C000000u;   // k8=0, k9=1
        f32x4 acc = {0.f, 0.f, 0.f, 0.f};
        acc = __builtin_amdgcn_mfma_f32_16x16x32_f16(wv1, xb.h, acc, 0, 0, 0);
        // C row16 = 4q+r -> j = 16w+4q+r ; granule (j>>3)*16+cb stride 48
        float* dst = (float*)(smem + O_PXH + ((2 * w + (q >> 1)) * 16 + cb) * 48 + (q & 1) * 16);
        *(float4*)dst = float4{acc[0], acc[1], acc[2], acc[3]};
    }
    __syncthreads();

    #pragma unroll 1
    for (int tb = 0; tb < NT; tb += 4) {
        #pragma unroll
        for (int u = 0; u < 4; ++u) {
            const int t = tb + u;
            // ================= PHASE A =================
            // dlt (all lanes) + prehid regs + h1 recurrent + in-reg hid +
            // VSN2 + softmax + x~ shfl + LSTM0 + h0 write
            float dlt = 0.f;
            if (t > 0) dlt = wp_reduce8(smem, cb) + bov;
            if (w == 0 && q == 1) {          // batched output (aligned float4)
                if (u == 1)      dout.x = dlt;
                else if (u == 2) dout.y = dlt;
                else if (u == 3) dout.z = dlt;
                else if (t > 0) {            // u == 0
                    dout.w = dlt;
                    *(float4*)(out + (size_t)(b0 + cb) * NT + (t - 4)) = dout;
                }
            }
            f32x4 a1A = {bias1A.x, bias1A.y, bias1A.z, bias1A.w};
            f32x4 a1B = {bias1B.x, bias1B.y, bias1B.z, bias1B.w};
            {
                f16x8 h1a = *(const f16x8*)(smem + O_H1 + lane * 16);
                f16x8 h1b = *(const f16x8*)(smem + O_H1 + 1024 + lane * 16);
                a1A = __builtin_amdgcn_mfma_f32_16x16x32_f16(wl1_2A, h1a, a1A, 0, 0, 0);
                a1B = __builtin_amdgcn_mfma_f32_16x16x32_f16(wl1_2B, h1a, a1B, 0, 0, 0);
                a1A = __builtin_amdgcn_mfma_f32_16x16x32_f16(wl1_3A, h1b, a1A, 0, 0, 0);
                a1B = __builtin_amdgcn_mfma_f32_16x16x32_f16(wl1_3B, h1b, a1B, 0, 0, 0);
            }
            // in-register hid = relu(prehid + w1col8 * dlt), as VSN2 B-frags
            f16x8 hb0, hb1;
            {
                const float* PX = (const float*)(smem + O_PXH + (t & 1) * 6144);
                float4 pA0 = *(const float4*)(PX + (q * 16 + cb) * 12);
                float4 pA1 = *(const float4*)(PX + (q * 16 + cb) * 12 + 4);
                float4 pB0 = *(const float4*)(PX + ((4 + q) * 16 + cb) * 12);
                float4 pB1 = *(const float4*)(PX + ((4 + q) * 16 + cb) * 12 + 4);
                union { uint4 u4; f16x8 h; } c0, c1;
                c0.u4.x = pkrtz(fmaxf(fmaf(w8a[0], dlt, pA0.x), 0.f),
                                fmaxf(fmaf(w8a[1], dlt, pA0.y), 0.f));
                c0.u4.y = pkrtz(fmaxf(fmaf(w8a[2], dlt, pA0.z), 0.f),
                                fmaxf(fmaf(w8a[3], dlt, pA0.w), 0.f));
                c0.u4.z = pkrtz(fmaxf(fmaf(w8a[4], dlt, pA1.x), 0.f),
                                fmaxf(fmaf(w8a[5], dlt, pA1.y), 0.f));
                c0.u4.w = pkrtz(fmaxf(fmaf(w8a[6], dlt, pA1.z), 0.f),
                                fmaxf(fmaf(w8a[7], dlt, pA1.w), 0.f));
                c1.u4.x = pkrtz(fmaxf(fmaf(w8b[0], dlt, pB0.x), 0.f),
                                fmaxf(fmaf(w8b[1], dlt, pB0.y), 0.f));
                c1.u4.y = pkrtz(fmaxf(fmaf(w8b[2], dlt, pB0.z), 0.f),
                                fmaxf(fmaf(w8b[3], dlt, pB0.w), 0.f));
                c1.u4.z = pkrtz(fmaxf(fmaf(w8b[4], dlt, pB1.x), 0.f),
                                fmaxf(fmaf(w8b[5], dlt, pB1.y), 0.f));
                c1.u4.w = pkrtz(fmaxf(fmaf(w8b[6], dlt, pB1.z), 0.f),
                                fmaxf(fmaf(w8b[7], dlt, pB1.w), 0.f));
                hb0 = c0.h; hb1 = c1.h;
            }
            {
                f32x4 aA = {b2f.x, b2f.y, b2f.z, b2f.w};
                f32x4 aB = {0.f, 0.f, 0.f, 0.f};
                aA = __builtin_amdgcn_mfma_f32_16x16x32_f16(wv2_0, hb0, aA, 0, 0, 0);
                aB = __builtin_amdgcn_mfma_f32_16x16x32_f16(wv2_1, hb1, aB, 0, 0, 0);
                float e0 = fexp2(aA[0] + aB[0]);
                float e1 = fexp2(aA[1] + aB[1]);
                float e2 = fexp2(aA[2] + aB[2]);
                float e3 = fexp2(aA[3] + aB[3]);
                float sm = (e0 + e1) + (e2 + e3);
                sm += __shfl_xor(sm, 16, 64);
                sm += __shfl_xor(sm, 32, 64);
                float inv = frcp(sm);
                uint4 xw = *(const uint4*)(smem + O_XB + (t & 7) * 256 + cb * 16);
                const __half* xh = (const __half*)&xw;
                float x0, x1, x2, x3;
                if (q == 0)      { x0 = __half2float(xh[0]); x1 = __half2float(xh[1]);
                                   x2 = __half2float(xh[2]); x3 = __half2float(xh[3]); }
                else if (q == 1) { x0 = __half2float(xh[4]); x1 = __half2float(xh[5]);
                                   x2 = __half2float(xh[6]); x3 = __half2float(xh[7]); }
                else if (q == 2) { x0 = dlt; x1 = x2 = x3 = 0.f; }
                else             { x0 = x1 = x2 = x3 = 0.f; }
                uint p01 = pkrtz(x0 * e0 * inv, x1 * e1 * inv);
                uint p23 = pkrtz(x2 * e2 * inv, x3 * e3 * inv);
                int srcA = (((2 * q) & 3) << 4) + cb;
                int srcB = (((2 * q + 1) & 3) << 4) + cb;
                uint hA0 = (uint)__shfl((int)p01, srcA, 64);
                uint hA1 = (uint)__shfl((int)p23, srcA, 64);
                uint hB0 = (uint)__shfl((int)p01, srcB, 64);
                uint hB1 = (uint)__shfl((int)p23, srcB, 64);
                union { uint4 u4; f16x8 h; } xs;
                if (q < 2)       xs.u4 = (uint4){hA0, hA1, hB0, hB1};
                else if (q == 2) xs.u4 = (uint4){0x3C00u, 0u, 0u, 0u};  // const-1 @k16
                else             xs.u4 = (uint4){0u, 0u, 0u, 0u};
                a0A = __builtin_amdgcn_mfma_f32_16x16x32_f16(wl0_0A, xs.h, a0A, 0, 0, 0);
                a0B = __builtin_amdgcn_mfma_f32_16x16x32_f16(wl0_0B, xs.h, a0B, 0, 0, 0);
                float hA = lstm_out2(a0A, c0A);
                float hB = lstm_out2(a0B, c0B);
                *(unsigned short*)(smem + O_H0 + w * 256 + cb * 16 + q * 2)     = f16b(hA);
                *(unsigned short*)(smem + O_H0 + w * 256 + cb * 16 + 8 + q * 2) = f16b(hB);
            }
            __syncthreads();   // h0 ready

            // ================= PHASE B =================
            // LSTM1 finish + next L0 recurrent + h1/wp write +
            // prehid(t+1) (waves 0-3) + x restock (u==3)
            {
                f16x8 h0a = *(const f16x8*)(smem + O_H0 + lane * 16);
                f16x8 h0b = *(const f16x8*)(smem + O_H0 + 1024 + lane * 16);
                a1A = __builtin_amdgcn_mfma_f32_16x16x32_f16(wl1_0A, h0a, a1A, 0, 0, 0);
                a1B = __builtin_amdgcn_mfma_f32_16x16x32_f16(wl1_0B, h0a, a1B, 0, 0, 0);
                a1A = __builtin_amdgcn_mfma_f32_16x16x32_f16(wl1_1A, h0b, a1A, 0, 0, 0);
                a1B = __builtin_amdgcn_mfma_f32_16x16x32_f16(wl1_1B, h0b, a1B, 0, 0, 0);
                f32x4 anA = {0.f, 0.f, 0.f, 0.f};
                f32x4 anB = {0.f, 0.f, 0.f, 0.f};
                anA = __builtin_amdgcn_mfma_f32_16x16x32_f16(wl0_1A, h0a, anA, 0, 0, 0);
                anB = __builtin_amdgcn_mfma_f32_16x16x32_f16(wl0_1B, h0a, anB, 0, 0, 0);
                anA = __builtin_amdgcn_mfma_f32_16x16x32_f16(wl0_2A, h0b, anA, 0, 0, 0);
                anB = __builtin_amdgcn_mfma_f32_16x16x32_f16(wl0_2B, h0b, anB, 0, 0, 0);
                a0A = anA; a0B = anB;
                float hA = lstm_out2(a1A, c1A);
                float hB = lstm_out2(a1B, c1B);
                *(unsigned short*)(smem + O_H1 + w * 256 + cb * 16 + q * 2)     = f16b(hA);
                *(unsigned short*)(smem + O_H1 + w * 256 + cb * 16 + 8 + q * 2) = f16b(hB);
                float p = fmaf(wojA, hA, wojB * hB);
                p += __shfl_xor(p, 16, 64);
                p += __shfl_xor(p, 32, 64);
                if (q == 0) wpbuf[cb * 20 + w] = p;
            }
            if (w < 4 && t + 1 < NT) {   // prehid(t+1) into slot (t+1)&1
                union { uint4 u4; f16x8 h; } xb;
                xb.u4 = (uint4){0u, 0u, 0u, 0u};
                if (q == 0)      xb.u4 = *(const uint4*)(smem + O_XB + ((t + 1) & 7) * 256 + cb * 16);
                else if (q == 1) xb.u4.x = 0x3C000000u;   // k8=0, k9=1
                f32x4 acc = {0.f, 0.f, 0.f, 0.f};
                acc = __builtin_amdgcn_mfma_f32_16x16x32_f16(wv1, xb.h, acc, 0, 0, 0);
                float* dst = (float*)(smem + O_PXH + ((t + 1) & 1) * 6144
                                      + ((2 * w + (q >> 1)) * 16 + cb) * 48 + (q & 1) * 16);
                *(float4*)dst = float4{acc[0], acc[1], acc[2], acc[3]};
            }
            if (u == 3 && tid >= 256 && tid < 384) {   // restock slots (tb+8..11)&7
                int L = tid - 256, pb = L >> 3, ti = (L >> 1) & 3, ph = L & 1;
                uint2 p2; p2.x = pkrtz(px.x, px.y); p2.y = pkrtz(px.z, px.w);
                *(uint2*)(smem + O_XB + ((tb + 8 + ti) & 7) * 256 + pb * 16 + ph * 8) = p2;
                int tt = tb + 12 + ti;
                if (tt < NT)
                    px = *(const float4*)(feat + ((size_t)(b0 + pb) * NT + tt) * 8 + 4 * ph);
            }
            __syncthreads();   // h1/WP/prehid/x ready for next step
        }
    }

    // ---- epilogue: finalize deltas for t = 252..255 ----
    if (w == 0 && q == 1) {
        dout.w = wp_reduce8(smem, cb) + bov;
        *(float4*)(out + (size_t)(b0 + cb) * NT + (NT - 4)) = dout;
    }
}

extern "C" void kernel_launch(void* const* d_in, const int* in_sizes, int n_in,
                              void* d_out, int out_size, void* d_ws, size_t ws_size,
                              hipStream_t stream) {
    const float* feat = (const float*)d_in[0];
    const float* W1   = (const float*)d_in[1];
    const float* b1   = (const float*)d_in[2];
    const float* W2   = (const float*)d_in[3];
    const float* b2   = (const float*)d_in[4];
    const float* Wih0 = (const float*)d_in[5];
    const float* Whh0 = (const float*)d_in[6];
    const float* bih0 = (const float*)d_in[7];
    const float* bhh0 = (const float*)d_in[8];
    const float* Wih1 = (const float*)d_in[9];
    const float* Whh1 = (const float*)d_in[10];
    const float* bih1 = (const float*)d_in[11];
    const float* bhh1 = (const float*)d_in[12];
    const float* Wo   = (const float*)d_in[13];
    const float* bo   = (const float*)d_in[14];
    uint* ws   = (uint*)d_ws;
    float* out = (float*)d_out;

    hipLaunchKernelGGL(prep_kernel, dim3(40), dim3(1024), 0, stream,
                       W1, b1, W2, b2, Wih0, Whh0, bih0, bhh0,
                       Wih1, Whh1, bih1, bhh1, ws);
    // 256 blocks x 512 threads (8 waves): 16 batches/block, 1 block/CU
    hipLaunchKernelGGL(tft_main, dim3(256), dim3(512), 0, stream,
                       feat, W1, Wo, bo, ws, out);
}

// Round 15
// 328.499 us; speedup vs baseline: 1.6138x; 1.0752x over previous
//
#include <hip/hip_runtime.h>
#include <hip/hip_fp16.h>
#include <math.h>

typedef unsigned int uint;
typedef _Float16 f16x8 __attribute__((ext_vector_type(8)));
typedef __fp16 fp16x2 __attribute__((ext_vector_type(2)));
typedef float f32x4 __attribute__((ext_vector_type(4)));

#define NT 256

// ---------------- ws layout (uint/f32 words) ----------------
// 0     : W_l0 frags [16 tiles][3 ksteps][64 lanes][4 uint] = 12288
//         gate-prescaled; s=0 carries prescaled bias0 at k=16 (const-1 input)
// 12288 : W_l1 frags [16][4][64][4] = 16384  (gate-prescaled)
// 28672 : W_v1 frags [4][64][4]  (b1 folded at k=9, delta col zeroed) = 1024
// 29696 : W_v2 frags [2][64][4]  (x log2e)                   = 512
// 31232 : b2frag f32 [64][4]     (x log2e; -1e30 pads)       = 256
// 35584 : bias1frag f32 [16][64][4] (gate-prescaled)         = 4096

// ---------------- LDS (bytes) ----------------
// XB : x ring, 8 slots x 256B
// PXH: prehid ring (packed f16, B-frag layout), 2 slots x 2048B
//      byte = slot*2048 + (j>>3)*256 + cb*16 + (j&7)*2
#define O_XB   0      // 2048
#define O_PXH  2048   // 4096
#define O_H0   6144   // 2048  h0 K=64 frag-linear
#define O_H1   8192   // 2048  h1 K=64
#define O_WP   10240  // 1280  f32 [16 batch][20] delta partials (w 0..7)
#define LDS_BYTES 11520

__device__ __forceinline__ float fexp2(float x) { return __builtin_amdgcn_exp2f(x); }
__device__ __forceinline__ float frcp(float x)  { return __builtin_amdgcn_rcpf(x); }

__device__ __forceinline__ uint pkrtz(float lo, float hi) {
    fp16x2 v = __builtin_amdgcn_cvt_pkrtz(lo, hi);
    return __builtin_bit_cast(uint, v);
}
__device__ __forceinline__ uint pack2(float lo, float hi) {
    return ((uint)__half_as_ushort(__float2half_rn(hi)) << 16) |
           (uint)__half_as_ushort(__float2half_rn(lo));
}
__device__ __forceinline__ unsigned short f16b(float x) {
    return __half_as_ushort(__float2half_rn(x));
}
__device__ __forceinline__ f16x8 ldfrag(const uint* p) {
    union { uint4 u; f16x8 h; } c;
    c.u = *(const uint4*)p;
    return c.h;
}
// packed f16: relu(acc + w*d)  (one v_pk_fma_f16 + one v_pk_max_f16)
__device__ __forceinline__ uint pkfma_relu(uint acc, uint wv, uint d2) {
    uint r, z = 0u;
    asm("v_pk_fma_f16 %0, %1, %2, %3" : "=v"(r) : "v"(wv), "v"(d2), "v"(acc));
    asm("v_pk_max_f16 %0, %1, %2" : "=v"(r) : "v"(r), "v"(z));
    return r;
}
// gate rows prescaled: i,f,o by -log2(e); g by -2*log2(e)
__device__ __forceinline__ float lstm_out2(const f32x4 a, float& c) {
    float ii = frcp(1.0f + fexp2(a[0]));
    float ff = frcp(1.0f + fexp2(a[1]));
    float gg = fmaf(2.0f, frcp(1.0f + fexp2(a[2])), -1.0f);
    float oo = frcp(1.0f + fexp2(a[3]));
    c = fmaf(ff, c, ii * gg);
    return oo * fmaf(2.0f, frcp(1.0f + fexp2(-2.88539008f * c)), -1.0f);
}
__device__ __forceinline__ float wp_reduce8(const unsigned char* smem, int cb) {
    const float* wp = (const float*)(smem + O_WP) + cb * 20;
    float4 s0 = *(const float4*)(wp);
    float4 s1 = *(const float4*)(wp + 4);
    return ((s0.x + s0.y) + (s0.z + s0.w)) + ((s1.x + s1.y) + (s1.z + s1.w));
}

// A-frag (16x16x32 f16): lane l holds A[row16=l&15][k=(l>>4)*8+e].
// LSTM tiles gate-interleaved: row16 -> R = (row16&3)*64 + 4*tile + (row16>>2).
__global__ __launch_bounds__(1024)
void prep_kernel(const float* __restrict__ W1,  const float* __restrict__ b1,
                 const float* __restrict__ W2,  const float* __restrict__ b2,
                 const float* __restrict__ Wih0, const float* __restrict__ Whh0,
                 const float* __restrict__ bih0, const float* __restrict__ bhh0,
                 const float* __restrict__ Wih1, const float* __restrict__ Whh1,
                 const float* __restrict__ bih1, const float* __restrict__ bhh1,
                 uint* __restrict__ ws)
{
    const int tid = blockIdx.x * 1024 + threadIdx.x;
    float* wsf = (float*)ws;
    const float LOG2E = 1.44269504f;

    if (tid < 12288) {                               // W_l0 (prescaled)
        int v = tid & 3, l = (tid >> 2) & 63, ts = tid >> 8;
        int s = ts % 3, w = ts / 3;
        int g = l & 3;
        float sc = (g == 2) ? -2.0f * LOG2E : -LOG2E;
        int R = g * 64 + 4 * w + ((l >> 2) & 3);
        int k0 = (l >> 4) * 8 + 2 * v;
        float lo = 0.f, hi = 0.f;
        if (s == 0) {
            if (k0     < 9) lo = Wih0[R * 9 + k0];
            if (k0 + 1 < 9) hi = Wih0[R * 9 + k0 + 1];
            if (k0 == 16)   lo = bih0[R] + bhh0[R];   // bias0 via const-1 at k16
        } else {
            int kh = 32 * (s - 1) + k0;
            lo = Whh0[R * 64 + kh]; hi = Whh0[R * 64 + kh + 1];
        }
        ws[tid] = pack2(lo * sc, hi * sc);
    } else if (tid < 28672) {                        // W_l1 (prescaled)
        int idx = tid - 12288;
        int v = idx & 3, l = (idx >> 2) & 63, ts = idx >> 8;
        int s = ts & 3, w = ts >> 2;
        int g = l & 3;
        float sc = (g == 2) ? -2.0f * LOG2E : -LOG2E;
        int R = g * 64 + 4 * w + ((l >> 2) & 3);
        int kt = 32 * s + (l >> 4) * 8 + 2 * v;
        float lo, hi;
        if (kt < 64) { lo = Wih1[R * 64 + kt];      hi = Wih1[R * 64 + kt + 1]; }
        else         { lo = Whh1[R * 64 + kt - 64]; hi = Whh1[R * 64 + kt - 63]; }
        ws[tid] = pack2(lo * sc, hi * sc);
    } else if (tid < 29696) {                        // W_v1 (b1 folded at k=9)
        int idx = tid - 28672;
        int v = idx & 3, l = (idx >> 2) & 63, m = idx >> 8;
        int j2 = 16 * m + (l & 15);
        int k0 = (l >> 4) * 8 + 2 * v;
        float lo = (k0 < 9) ? W1[j2 * 9 + k0] : 0.f;
        float hi = 0.f;
        if (k0 + 1 < 9)       hi = W1[j2 * 9 + k0 + 1];
        else if (k0 + 1 == 9) hi = b1[j2];
        if (k0 == 8) lo = 0.f;                       // delta column handled in-reg
        ws[tid] = pack2(lo, hi);
    } else if (tid < 30208) {                        // W_v2 (x log2e)
        int idx = tid - 29696;
        int v = idx & 3, l = (idx >> 2) & 63, s = idx >> 8;
        int rr = l & 15;
        int k0 = 32 * s + (l >> 4) * 8 + 2 * v;
        float lo = (rr < 9) ? W2[rr * 64 + k0] * LOG2E     : 0.f;
        float hi = (rr < 9) ? W2[rr * 64 + k0 + 1] * LOG2E : 0.f;
        ws[tid] = pack2(lo, hi);
    } else if (tid >= 31232 && tid < 31488) {        // b2frag (x log2e, -1e30 pads)
        int idx = tid - 31232;
        int r = idx & 3, l = idx >> 2;
        int row = (l >> 4) * 4 + r;
        wsf[tid] = (row < 9) ? b2[row] * LOG2E : -1e30f;
    } else if (tid >= 35584 && tid < 39680) {        // bias1frag (prescaled)
        int idx = tid - 35584;
        int r = idx & 3, l = (idx >> 2) & 63, w = idx >> 8;
        float sc = (r == 2) ? -2.0f * LOG2E : -LOG2E;
        int R = r * 64 + 4 * w + (l >> 4);
        wsf[tid] = (bih1[R] + bhh1[R]) * sc;
    }
}

// 256 blocks x 512 threads (8 waves), 16 batches/block, 1 block/CU.
// 2-phase schedule. prehid precomputed one step ahead in PACKED F16
// (B-frag layout); in-loop hid = pk_fma_relu(prehid, w1col8, delta) --
// 16 packed ops, zero repack, 2 b128 reads.
__global__ __launch_bounds__(512, 2)
void tft_main(const float* __restrict__ feat,
              const float* __restrict__ W1,
              const float* __restrict__ Wo, const float* __restrict__ bo,
              const uint* __restrict__ ws,
              float* __restrict__ out)
{
    __shared__ unsigned char smem[LDS_BYTES];
    const int tid  = threadIdx.x;
    const int lane = tid & 63;
    const int w    = tid >> 6;        // 0..7
    const int q    = lane >> 4;       // 0..3
    const int cb   = lane & 15;       // batch column
    const int b0   = blockIdx.x * 16;
    const int tA   = 2 * w, tB = 2 * w + 1;
    float* wpbuf = (float*)(smem + O_WP);

    // ---- zero LDS ----
    {
        uint4 z = {0u, 0u, 0u, 0u};
        #pragma unroll
        for (int i = 0; i < 2; ++i) {
            int idx = tid + i * 512;
            if (idx < LDS_BYTES / 16) ((uint4*)smem)[idx] = z;
        }
    }

    // ---- weights -> registers ----
    const f16x8 wl0_0A = ldfrag(ws + (tA * 3 + 0) * 256 + lane * 4);
    const f16x8 wl0_1A = ldfrag(ws + (tA * 3 + 1) * 256 + lane * 4);
    const f16x8 wl0_2A = ldfrag(ws + (tA * 3 + 2) * 256 + lane * 4);
    const f16x8 wl0_0B = ldfrag(ws + (tB * 3 + 0) * 256 + lane * 4);
    const f16x8 wl0_1B = ldfrag(ws + (tB * 3 + 1) * 256 + lane * 4);
    const f16x8 wl0_2B = ldfrag(ws + (tB * 3 + 2) * 256 + lane * 4);
    const f16x8 wl1_0A = ldfrag(ws + 12288 + (tA * 4 + 0) * 256 + lane * 4);
    const f16x8 wl1_1A = ldfrag(ws + 12288 + (tA * 4 + 1) * 256 + lane * 4);
    const f16x8 wl1_2A = ldfrag(ws + 12288 + (tA * 4 + 2) * 256 + lane * 4);
    const f16x8 wl1_3A = ldfrag(ws + 12288 + (tA * 4 + 3) * 256 + lane * 4);
    const f16x8 wl1_0B = ldfrag(ws + 12288 + (tB * 4 + 0) * 256 + lane * 4);
    const f16x8 wl1_1B = ldfrag(ws + 12288 + (tB * 4 + 1) * 256 + lane * 4);
    const f16x8 wl1_2B = ldfrag(ws + 12288 + (tB * 4 + 2) * 256 + lane * 4);
    const f16x8 wl1_3B = ldfrag(ws + 12288 + (tB * 4 + 3) * 256 + lane * 4);
    const f16x8 wv2_0 = ldfrag(ws + 29696 + lane * 4);
    const f16x8 wv2_1 = ldfrag(ws + 29696 + 256 + lane * 4);
    f16x8 wv1 = {};
    const float* wsf = (const float*)ws;
    if (w < 4) wv1 = ldfrag(ws + 28672 + w * 256 + lane * 4);
    const float4 b2f   = *(const float4*)(wsf + 31232 + lane * 4);
    const float4 bias1A = *(const float4*)(wsf + 35584 + (tA * 64 + lane) * 4);
    const float4 bias1B = *(const float4*)(wsf + 35584 + (tB * 64 + lane) * 4);
    const float wojA = Wo[8 * w + q];
    const float wojB = Wo[8 * w + 4 + q];
    const float bov  = bo[0];
    // W1 delta-column (col 8) packed f16 for lane's hid indices
    uint w8aU[4], w8bU[4];
    #pragma unroll
    for (int e = 0; e < 4; ++e) {
        w8aU[e] = pack2(W1[(q * 8 + 2 * e) * 9 + 8],      W1[(q * 8 + 2 * e + 1) * 9 + 8]);
        w8bU[e] = pack2(W1[(32 + q * 8 + 2 * e) * 9 + 8], W1[(32 + q * 8 + 2 * e + 1) * 9 + 8]);
    }

    float c0A = 0.f, c0B = 0.f, c1A = 0.f, c1B = 0.f;
    f32x4 a0A = {0.f, 0.f, 0.f, 0.f};   // L0 acc carry (recurrent from B of t-1)
    f32x4 a0B = {0.f, 0.f, 0.f, 0.f};
    float4 px   = {0.f, 0.f, 0.f, 0.f}; // x prefetch (tid 256..383)
    float4 dout = {0.f, 0.f, 0.f, 0.f}; // 4 deltas (w0,q1)
    __syncthreads();

    // ---- init: stage x(0..7) into 8-slot ring; px <- x(8..11) ----
    if (tid >= 256) {                       // 256 threads: slots 0..7
        int L = tid - 256, pb = L >> 4, ti = (L >> 1) & 7, ph = L & 1;
        float4 x0 = *(const float4*)(feat + ((size_t)(b0 + pb) * NT + ti) * 8 + 4 * ph);
        uint2 p2; p2.x = pkrtz(x0.x, x0.y); p2.y = pkrtz(x0.z, x0.w);
        *(uint2*)(smem + O_XB + ti * 256 + pb * 16 + ph * 8) = p2;
    }
    if (tid >= 256 && tid < 384) {          // restock lanes: px = x(8+ti)
        int L = tid - 256, pb = L >> 3, ti = (L >> 1) & 3, ph = L & 1;
        px = *(const float4*)(feat + ((size_t)(b0 + pb) * NT + 8 + ti) * 8 + 4 * ph);
    }
    __syncthreads();

    // ---- init: prehid slot 0 = W1.[x(0);0;1]+b1, packed f16 (waves 0-3) ----
    if (w < 4) {
        union { uint4 u4; f16x8 h; } xb;
        xb.u4 = (uint4){0u, 0u, 0u, 0u};
        if (q == 0)      xb.u4 = *(const uint4*)(smem + O_XB + cb * 16);
        else if (q == 1) xb.u4.x = 0x3C000000u;   // k8=0, k9=1
        f32x4 acc = {0.f, 0.f, 0.f, 0.f};
        acc = __builtin_amdgcn_mfma_f32_16x16x32_f16(wv1, xb.h, acc, 0, 0, 0);
        uint2 ph; ph.x = pkrtz(acc[0], acc[1]); ph.y = pkrtz(acc[2], acc[3]);
        *(uint2*)(smem + O_PXH + (2 * w + (q >> 1)) * 256 + cb * 16 + (q & 1) * 8) = ph;
    }
    __syncthreads();

    #pragma unroll 1
    for (int tb = 0; tb < NT; tb += 4) {
        #pragma unroll
        for (int u = 0; u < 4; ++u) {
            const int t = tb + u;
            // ================= PHASE A =================
            float dlt = 0.f;
            if (t > 0) dlt = wp_reduce8(smem, cb) + bov;
            if (w == 0 && q == 1) {          // batched output (aligned float4)
                if (u == 1)      dout.x = dlt;
                else if (u == 2) dout.y = dlt;
                else if (u == 3) dout.z = dlt;
                else if (t > 0) {            // u == 0
                    dout.w = dlt;
                    *(float4*)(out + (size_t)(b0 + cb) * NT + (t - 4)) = dout;
                }
            }
            f32x4 a1A = {bias1A.x, bias1A.y, bias1A.z, bias1A.w};
            f32x4 a1B = {bias1B.x, bias1B.y, bias1B.z, bias1B.w};
            {
                f16x8 h1a = *(const f16x8*)(smem + O_H1 + lane * 16);
                f16x8 h1b = *(const f16x8*)(smem + O_H1 + 1024 + lane * 16);
                a1A = __builtin_amdgcn_mfma_f32_16x16x32_f16(wl1_2A, h1a, a1A, 0, 0, 0);
                a1B = __builtin_amdgcn_mfma_f32_16x16x32_f16(wl1_2B, h1a, a1B, 0, 0, 0);
                a1A = __builtin_amdgcn_mfma_f32_16x16x32_f16(wl1_3A, h1b, a1A, 0, 0, 0);
                a1B = __builtin_amdgcn_mfma_f32_16x16x32_f16(wl1_3B, h1b, a1B, 0, 0, 0);
            }
            // hid = relu(prehid + w1col8*dlt) -- packed f16, output IS B-frag
            f16x8 hb0, hb1;
            {
                const unsigned char* PX = smem + O_PXH + (t & 1) * 2048;
                uint4 pa = *(const uint4*)(PX + q * 256 + cb * 16);
                uint4 pb = *(const uint4*)(PX + (4 + q) * 256 + cb * 16);
                uint d2 = pkrtz(dlt, dlt);
                union { uint4 u4; f16x8 h; } ca, cbu;
                ca.u4.x  = pkfma_relu(pa.x, w8aU[0], d2);
                ca.u4.y  = pkfma_relu(pa.y, w8aU[1], d2);
                ca.u4.z  = pkfma_relu(pa.z, w8aU[2], d2);
                ca.u4.w  = pkfma_relu(pa.w, w8aU[3], d2);
                cbu.u4.x = pkfma_relu(pb.x, w8bU[0], d2);
                cbu.u4.y = pkfma_relu(pb.y, w8bU[1], d2);
                cbu.u4.z = pkfma_relu(pb.z, w8bU[2], d2);
                cbu.u4.w = pkfma_relu(pb.w, w8bU[3], d2);
                hb0 = ca.h; hb1 = cbu.h;
            }
            {
                f32x4 aA = {b2f.x, b2f.y, b2f.z, b2f.w};
                f32x4 aB = {0.f, 0.f, 0.f, 0.f};
                aA = __builtin_amdgcn_mfma_f32_16x16x32_f16(wv2_0, hb0, aA, 0, 0, 0);
                aB = __builtin_amdgcn_mfma_f32_16x16x32_f16(wv2_1, hb1, aB, 0, 0, 0);
                float e0 = fexp2(aA[0] + aB[0]);
                float e1 = fexp2(aA[1] + aB[1]);
                float e2 = fexp2(aA[2] + aB[2]);
                float e3 = fexp2(aA[3] + aB[3]);
                float sm = (e0 + e1) + (e2 + e3);
                sm += __shfl_xor(sm, 16, 64);
                sm += __shfl_xor(sm, 32, 64);
                float inv = frcp(sm);
                float x0, x1, x2, x3;
                if (q < 2) {
                    uint2 xw2 = *(const uint2*)(smem + O_XB + (t & 7) * 256 + cb * 16 + q * 8);
                    const __half* xh = (const __half*)&xw2;
                    x0 = __half2float(xh[0]); x1 = __half2float(xh[1]);
                    x2 = __half2float(xh[2]); x3 = __half2float(xh[3]);
                } else if (q == 2) { x0 = dlt; x1 = x2 = x3 = 0.f; }
                else               { x0 = x1 = x2 = x3 = 0.f; }
                uint p01 = pkrtz(x0 * e0 * inv, x1 * e1 * inv);
                uint p23 = pkrtz(x2 * e2 * inv, x3 * e3 * inv);
                int srcA = (((2 * q) & 3) << 4) + cb;
                int srcB = (((2 * q + 1) & 3) << 4) + cb;
                uint hA0 = (uint)__shfl((int)p01, srcA, 64);
                uint hA1 = (uint)__shfl((int)p23, srcA, 64);
                uint hB0 = (uint)__shfl((int)p01, srcB, 64);
                uint hB1 = (uint)__shfl((int)p23, srcB, 64);
                union { uint4 u4; f16x8 h; } xs;
                if (q < 2)       xs.u4 = (uint4){hA0, hA1, hB0, hB1};
                else if (q == 2) xs.u4 = (uint4){0x3C00u, 0u, 0u, 0u};  // const-1 @k16
                else             xs.u4 = (uint4){0u, 0u, 0u, 0u};
                a0A = __builtin_amdgcn_mfma_f32_16x16x32_f16(wl0_0A, xs.h, a0A, 0, 0, 0);
                a0B = __builtin_amdgcn_mfma_f32_16x16x32_f16(wl0_0B, xs.h, a0B, 0, 0, 0);
                float hA = lstm_out2(a0A, c0A);
                float hB = lstm_out2(a0B, c0B);
                *(unsigned short*)(smem + O_H0 + w * 256 + cb * 16 + q * 2)     = f16b(hA);
                *(unsigned short*)(smem + O_H0 + w * 256 + cb * 16 + 8 + q * 2) = f16b(hB);
            }
            __syncthreads();   // h0 ready

            // ================= PHASE B =================
            {
                f16x8 h0a = *(const f16x8*)(smem + O_H0 + lane * 16);
                f16x8 h0b = *(const f16x8*)(smem + O_H0 + 1024 + lane * 16);
                a1A = __builtin_amdgcn_mfma_f32_16x16x32_f16(wl1_0A, h0a, a1A, 0, 0, 0);
                a1B = __builtin_amdgcn_mfma_f32_16x16x32_f16(wl1_0B, h0a, a1B, 0, 0, 0);
                a1A = __builtin_amdgcn_mfma_f32_16x16x32_f16(wl1_1A, h0b, a1A, 0, 0, 0);
                a1B = __builtin_amdgcn_mfma_f32_16x16x32_f16(wl1_1B, h0b, a1B, 0, 0, 0);
                f32x4 anA = {0.f, 0.f, 0.f, 0.f};
                f32x4 anB = {0.f, 0.f, 0.f, 0.f};
                anA = __builtin_amdgcn_mfma_f32_16x16x32_f16(wl0_1A, h0a, anA, 0, 0, 0);
                anB = __builtin_amdgcn_mfma_f32_16x16x32_f16(wl0_1B, h0a, anB, 0, 0, 0);
                anA = __builtin_amdgcn_mfma_f32_16x16x32_f16(wl0_2A, h0b, anA, 0, 0, 0);
                anB = __builtin_amdgcn_mfma_f32_16x16x32_f16(wl0_2B, h0b, anB, 0, 0, 0);
                a0A = anA; a0B = anB;
                float hA = lstm_out2(a1A, c1A);
                float hB = lstm_out2(a1B, c1B);
                *(unsigned short*)(smem + O_H1 + w * 256 + cb * 16 + q * 2)     = f16b(hA);
                *(unsigned short*)(smem + O_H1 + w * 256 + cb * 16 + 8 + q * 2) = f16b(hB);
                float p = fmaf(wojA, hA, wojB * hB);
                p += __shfl_xor(p, 16, 64);
                p += __shfl_xor(p, 32, 64);
                if (q == 0) wpbuf[cb * 20 + w] = p;
            }
            if (w < 4 && t + 1 < NT) {   // prehid(t+1) packed f16 into slot (t+1)&1
                union { uint4 u4; f16x8 h; } xb;
                xb.u4 = (uint4){0u, 0u, 0u, 0u};
                if (q == 0)      xb.u4 = *(const uint4*)(smem + O_XB + ((t + 1) & 7) * 256 + cb * 16);
                else if (q == 1) xb.u4.x = 0x3C000000u;   // k8=0, k9=1
                f32x4 acc = {0.f, 0.f, 0.f, 0.f};
                acc = __builtin_amdgcn_mfma_f32_16x16x32_f16(wv1, xb.h, acc, 0, 0, 0);
                uint2 ph; ph.x = pkrtz(acc[0], acc[1]); ph.y = pkrtz(acc[2], acc[3]);
                *(uint2*)(smem + O_PXH + ((t + 1) & 1) * 2048
                          + (2 * w + (q >> 1)) * 256 + cb * 16 + (q & 1) * 8) = ph;
            }
            if (u == 3 && tid >= 256 && tid < 384) {   // restock slots (tb+8..11)&7
                int L = tid - 256, pb = L >> 3, ti = (L >> 1) & 3, ph = L & 1;
                uint2 p2; p2.x = pkrtz(px.x, px.y); p2.y = pkrtz(px.z, px.w);
                *(uint2*)(smem + O_XB + ((tb + 8 + ti) & 7) * 256 + pb * 16 + ph * 8) = p2;
                int tt = tb + 12 + ti;
                if (tt < NT)
                    px = *(const float4*)(feat + ((size_t)(b0 + pb) * NT + tt) * 8 + 4 * ph);
            }
            __syncthreads();   // h1/WP/prehid/x ready for next step
        }
    }

    // ---- epilogue: finalize deltas for t = 252..255 ----
    if (w == 0 && q == 1) {
        dout.w = wp_reduce8(smem, cb) + bov;
        *(float4*)(out + (size_t)(b0 + cb) * NT + (NT - 4)) = dout;
    }
}

extern "C" void kernel_launch(void* const* d_in, const int* in_sizes, int n_in,
                              void* d_out, int out_size, void* d_ws, size_t ws_size,
                              hipStream_t stream) {
    const float* feat = (const float*)d_in[0];
    const float* W1   = (const float*)d_in[1];
    const float* b1   = (const float*)d_in[2];
    const float* W2   = (const float*)d_in[3];
    const float* b2   = (const float*)d_in[4];
    const float* Wih0 = (const float*)d_in[5];
    const float* Whh0 = (const float*)d_in[6];
    const float* bih0 = (const float*)d_in[7];
    const float* bhh0 = (const float*)d_in[8];
    const float* Wih1 = (const float*)d_in[9];
    const float* Whh1 = (const float*)d_in[10];
    const float* bih1 = (const float*)d_in[11];
    const float* bhh1 = (const float*)d_in[12];
    const float* Wo   = (const float*)d_in[13];
    const float* bo   = (const float*)d_in[14];
    uint* ws   = (uint*)d_ws;
    float* out = (float*)d_out;

    hipLaunchKernelGGL(prep_kernel, dim3(40), dim3(1024), 0, stream,
                       W1, b1, W2, b2, Wih0, Whh0, bih0, bhh0,
                       Wih1, Whh1, bih1, bhh1, ws);
    // 256 blocks x 512 threads (8 waves): 16 batches/block, 1 block/CU
    hipLaunchKernelGGL(tft_main, dim3(256), dim3(512), 0, stream,
                       feat, W1, Wo, bo, ws, out);
}

// Round 17
// 284.033 us; speedup vs baseline: 1.8665x; 1.1566x over previous
//
#include <hip/hip_runtime.h>
#include <hip/hip_fp16.h>
#include <math.h>

typedef unsigned int uint;
typedef _Float16 f16x8 __attribute__((ext_vector_type(8)));
typedef _Float16 f16x4 __attribute__((ext_vector_type(4)));
typedef __fp16 fp16x2 __attribute__((ext_vector_type(2)));
typedef float f32x4 __attribute__((ext_vector_type(4)));

#define NT 256

#define MFMA16(a, b, c) __builtin_amdgcn_mfma_f32_16x16x16f16(a, b, c, 0, 0, 0)

// ---------------- ws layout (uint/f32 words) ----------------
// 0     : W_l0 frags [16 tiles][3 ksteps][64 lanes][4 uint] = 12288
//         s=0 holds the K=16 x~ A-frag (2 words/lane, rest 0);
//         s=1,2 = Whh0 K=32 frags. All gate-prescaled.
// 12288 : W_l1 frags [16][4][64][4] = 16384  (gate-prescaled)
// 28672 : W_v1 frags [4][64][4]  (b1 folded at k=9, delta col zeroed) = 1024
// 29696 : W_v2 frags [2][64][4]  (x log2e)                   = 512
// 31232 : b2frag f32 [64][4]     (x log2e; -1e30 pads)       = 256
// 31488 : bias0frag f32 [16][64][4] (gate-prescaled)         = 4096
// 35584 : bias1frag f32 [16][64][4] (gate-prescaled)         = 4096

// ---------------- LDS (bytes) ----------------
#define O_XB   0      // 2048  x ring, 8 slots x 256B
#define O_PXH  2048   // 4096  prehid ring (packed f16), 2 slots x 2048B
#define O_H0   6144   // 2048  h0 K=64 frag-linear
#define O_H1   8192   // 2048  h1 K=64
#define LDS_BYTES 10240

__device__ __forceinline__ float fexp2(float x) { return __builtin_amdgcn_exp2f(x); }
__device__ __forceinline__ float frcp(float x)  { return __builtin_amdgcn_rcpf(x); }

__device__ __forceinline__ uint pkrtz(float lo, float hi) {
    fp16x2 v = __builtin_amdgcn_cvt_pkrtz(lo, hi);
    return __builtin_bit_cast(uint, v);
}
__device__ __forceinline__ uint pack2(float lo, float hi) {
    return ((uint)__half_as_ushort(__float2half_rn(hi)) << 16) |
           (uint)__half_as_ushort(__float2half_rn(lo));
}
__device__ __forceinline__ unsigned short f16b(float x) {
    return __half_as_ushort(__float2half_rn(x));
}
__device__ __forceinline__ f16x8 ldfrag(const uint* p) {
    union { uint4 u; f16x8 h; } c;
    c.u = *(const uint4*)p;
    return c.h;
}
// packed f16: relu(acc + w*d)
__device__ __forceinline__ uint pkfma_relu(uint acc, uint wv, uint d2) {
    uint r, z = 0u;
    asm("v_pk_fma_f16 %0, %1, %2, %3" : "=v"(r) : "v"(wv), "v"(d2), "v"(acc));
    asm("v_pk_max_f16 %0, %1, %2" : "=v"(r) : "v"(r), "v"(z));
    return r;
}
// gate rows prescaled: i,f,o by -log2(e); g by -2*log2(e)
__device__ __forceinline__ float lstm_out2(const f32x4 a, float& c) {
    float ii = frcp(1.0f + fexp2(a[0]));
    float ff = frcp(1.0f + fexp2(a[1]));
    float gg = fmaf(2.0f, frcp(1.0f + fexp2(a[2])), -1.0f);
    float oo = frcp(1.0f + fexp2(a[3]));
    c = fmaf(ff, c, ii * gg);
    return oo * fmaf(2.0f, frcp(1.0f + fexp2(-2.88539008f * c)), -1.0f);
}

// A-frag K=32 (16x16x32): lane l holds A[row16=l&15][k=(l>>4)*8+e].
// A-frag K=16 (16x16x16): lane l holds A[row16=l&15][k=(l>>4)*4+e], e=0..3.
// LSTM tiles gate-interleaved: row16 -> R = (row16&3)*64 + 4*tile + (row16>>2).
__global__ __launch_bounds__(1024)
void prep_kernel(const float* __restrict__ W1,  const float* __restrict__ b1,
                 const float* __restrict__ W2,  const float* __restrict__ b2,
                 const float* __restrict__ Wih0, const float* __restrict__ Whh0,
                 const float* __restrict__ bih0, const float* __restrict__ bhh0,
                 const float* __restrict__ Wih1, const float* __restrict__ Whh1,
                 const float* __restrict__ bih1, const float* __restrict__ bhh1,
                 uint* __restrict__ ws)
{
    const int tid = blockIdx.x * 1024 + threadIdx.x;
    float* wsf = (float*)ws;
    const float LOG2E = 1.44269504f;

    if (tid < 12288) {                               // W_l0 (prescaled)
        int v = tid & 3, l = (tid >> 2) & 63, ts = tid >> 8;
        int s = ts % 3, w = ts / 3;
        int g = l & 3;
        float sc = (g == 2) ? -2.0f * LOG2E : -LOG2E;
        int R = g * 64 + 4 * w + ((l >> 2) & 3);
        float lo = 0.f, hi = 0.f;
        if (s == 0) {                                // K=16 x~ frag (v<2 used)
            if (v < 2) {
                int k0 = (l >> 4) * 4 + 2 * v;
                if (k0     < 9) lo = Wih0[R * 9 + k0];
                if (k0 + 1 < 9) hi = Wih0[R * 9 + k0 + 1];
            }
            ws[tid] = pack2(lo * sc, hi * sc);
        } else {                                     // Whh0 K=32 frags
            int k0 = (l >> 4) * 8 + 2 * v;
            int kh = 32 * (s - 1) + k0;
            lo = Whh0[R * 64 + kh]; hi = Whh0[R * 64 + kh + 1];
            ws[tid] = pack2(lo * sc, hi * sc);
        }
    } else if (tid < 28672) {                        // W_l1 (prescaled)
        int idx = tid - 12288;
        int v = idx & 3, l = (idx >> 2) & 63, ts = idx >> 8;
        int s = ts & 3, w = ts >> 2;
        int g = l & 3;
        float sc = (g == 2) ? -2.0f * LOG2E : -LOG2E;
        int R = g * 64 + 4 * w + ((l >> 2) & 3);
        int kt = 32 * s + (l >> 4) * 8 + 2 * v;
        float lo, hi;
        if (kt < 64) { lo = Wih1[R * 64 + kt];      hi = Wih1[R * 64 + kt + 1]; }
        else         { lo = Whh1[R * 64 + kt - 64]; hi = Whh1[R * 64 + kt - 63]; }
        ws[tid] = pack2(lo * sc, hi * sc);
    } else if (tid < 29696) {                        // W_v1 (b1 folded at k=9)
        int idx = tid - 28672;
        int v = idx & 3, l = (idx >> 2) & 63, m = idx >> 8;
        int j2 = 16 * m + (l & 15);
        int k0 = (l >> 4) * 8 + 2 * v;
        float lo = (k0 < 9) ? W1[j2 * 9 + k0] : 0.f;
        float hi = 0.f;
        if (k0 + 1 < 9)       hi = W1[j2 * 9 + k0 + 1];
        else if (k0 + 1 == 9) hi = b1[j2];
        if (k0 == 8) lo = 0.f;                       // delta column handled in-reg
        ws[tid] = pack2(lo, hi);
    } else if (tid < 30208) {                        // W_v2 (x log2e)
        int idx = tid - 29696;
        int v = idx & 3, l = (idx >> 2) & 63, s = idx >> 8;
        int rr = l & 15;
        int k0 = 32 * s + (l >> 4) * 8 + 2 * v;
        float lo = (rr < 9) ? W2[rr * 64 + k0] * LOG2E     : 0.f;
        float hi = (rr < 9) ? W2[rr * 64 + k0 + 1] * LOG2E : 0.f;
        ws[tid] = pack2(lo, hi);
    } else if (tid >= 31232 && tid < 31488) {        // b2frag (x log2e, -1e30 pads)
        int idx = tid - 31232;
        int r = idx & 3, l = idx >> 2;
        int row = (l >> 4) * 4 + r;
        wsf[tid] = (row < 9) ? b2[row] * LOG2E : -1e30f;
    } else if (tid >= 31488 && tid < 35584) {        // bias0frag (prescaled)
        int idx = tid - 31488;
        int r = idx & 3, l = (idx >> 2) & 63, w = idx >> 8;
        float sc = (r == 2) ? -2.0f * LOG2E : -LOG2E;
        int R = r * 64 + 4 * w + (l >> 4);
        wsf[tid] = (bih0[R] + bhh0[R]) * sc;
    } else if (tid >= 35584 && tid < 39680) {        // bias1frag (prescaled)
        int idx = tid - 35584;
        int r = idx & 3, l = (idx >> 2) & 63, w = idx >> 8;
        float sc = (r == 2) ? -2.0f * LOG2E : -LOG2E;
        int R = r * 64 + 4 * w + (l >> 4);
        wsf[tid] = (bih1[R] + bhh1[R]) * sc;
    }
}

// 256 blocks x 512 threads (8 waves), 16 batches/block, 1 block/CU.
// 2-phase schedule. Delta via dedicated MFMA row (W_dlt row0 = Wo) on the
// already-loaded h1 frags + 1 shfl broadcast. x~ feeds LSTM0 through a
// K=16 MFMA whose B-layout equals the softmax C-layout: zero shuffles.
__global__ __launch_bounds__(512, 2)
void tft_main(const float* __restrict__ feat,
              const float* __restrict__ W1,
              const float* __restrict__ Wo, const float* __restrict__ bo,
              const uint* __restrict__ ws,
              float* __restrict__ out)
{
    __shared__ unsigned char smem[LDS_BYTES];
    const int tid  = threadIdx.x;
    const int lane = tid & 63;
    const int w    = tid >> 6;        // 0..7
    const int q    = lane >> 4;       // 0..3
    const int cb   = lane & 15;       // batch column
    const int b0   = blockIdx.x * 16;
    const int tA   = 2 * w, tB = 2 * w + 1;

    // ---- zero LDS ----
    {
        uint4 z = {0u, 0u, 0u, 0u};
        ((uint4*)smem)[tid] = z;
        if (tid < LDS_BYTES / 16 - 512) ((uint4*)smem)[512 + tid] = z;
    }

    // ---- weights -> registers ----
    f16x4 wl0xA, wl0xB;               // K=16 x~ A-frags
    {
        union { uint2 u2; f16x4 h; } c;
        c.u2 = *(const uint2*)(ws + (tA * 3 + 0) * 256 + lane * 4);
        wl0xA = c.h;
        c.u2 = *(const uint2*)(ws + (tB * 3 + 0) * 256 + lane * 4);
        wl0xB = c.h;
    }
    const f16x8 wl0_1A = ldfrag(ws + (tA * 3 + 1) * 256 + lane * 4);
    const f16x8 wl0_2A = ldfrag(ws + (tA * 3 + 2) * 256 + lane * 4);
    const f16x8 wl0_1B = ldfrag(ws + (tB * 3 + 1) * 256 + lane * 4);
    const f16x8 wl0_2B = ldfrag(ws + (tB * 3 + 2) * 256 + lane * 4);
    const f16x8 wl1_0A = ldfrag(ws + 12288 + (tA * 4 + 0) * 256 + lane * 4);
    const f16x8 wl1_1A = ldfrag(ws + 12288 + (tA * 4 + 1) * 256 + lane * 4);
    const f16x8 wl1_2A = ldfrag(ws + 12288 + (tA * 4 + 2) * 256 + lane * 4);
    const f16x8 wl1_3A = ldfrag(ws + 12288 + (tA * 4 + 3) * 256 + lane * 4);
    const f16x8 wl1_0B = ldfrag(ws + 12288 + (tB * 4 + 0) * 256 + lane * 4);
    const f16x8 wl1_1B = ldfrag(ws + 12288 + (tB * 4 + 1) * 256 + lane * 4);
    const f16x8 wl1_2B = ldfrag(ws + 12288 + (tB * 4 + 2) * 256 + lane * 4);
    const f16x8 wl1_3B = ldfrag(ws + 12288 + (tB * 4 + 3) * 256 + lane * 4);
    const f16x8 wv2_0 = ldfrag(ws + 29696 + lane * 4);
    const f16x8 wv2_1 = ldfrag(ws + 29696 + 256 + lane * 4);
    f16x8 wv1 = {};
    const float* wsf = (const float*)ws;
    if (w < 4) wv1 = ldfrag(ws + 28672 + w * 256 + lane * 4);
    const float4 b2f    = *(const float4*)(wsf + 31232 + lane * 4);
    const float4 bias0A = *(const float4*)(wsf + 31488 + (tA * 64 + lane) * 4);
    const float4 bias0B = *(const float4*)(wsf + 31488 + (tB * 64 + lane) * 4);
    const float4 bias1A = *(const float4*)(wsf + 35584 + (tA * 64 + lane) * 4);
    const float4 bias1B = *(const float4*)(wsf + 35584 + (tB * 64 + lane) * 4);
    const float bov = bo[0];
    // W_dlt A-frags: row 0 = Wo (K=64 over 2 ksteps), rows 1-15 zero
    f16x8 wdlt0 = {}, wdlt1 = {};
    if ((lane & 15) == 0) {
        int kb = (lane >> 4) * 8;
        union { uint4 u4; f16x8 h; } t0, t1;
        t0.u4.x = pack2(Wo[kb],     Wo[kb + 1]);
        t0.u4.y = pack2(Wo[kb + 2], Wo[kb + 3]);
        t0.u4.z = pack2(Wo[kb + 4], Wo[kb + 5]);
        t0.u4.w = pack2(Wo[kb + 6], Wo[kb + 7]);
        t1.u4.x = pack2(Wo[32 + kb],     Wo[32 + kb + 1]);
        t1.u4.y = pack2(Wo[32 + kb + 2], Wo[32 + kb + 3]);
        t1.u4.z = pack2(Wo[32 + kb + 4], Wo[32 + kb + 5]);
        t1.u4.w = pack2(Wo[32 + kb + 6], Wo[32 + kb + 7]);
        wdlt0 = t0.h; wdlt1 = t1.h;
    }
    // W1 delta-column (col 8) packed f16 (prehid rank-1 update)
    uint w8aU[4], w8bU[4];
    #pragma unroll
    for (int e = 0; e < 4; ++e) {
        w8aU[e] = pack2(W1[(q * 8 + 2 * e) * 9 + 8],      W1[(q * 8 + 2 * e + 1) * 9 + 8]);
        w8bU[e] = pack2(W1[(32 + q * 8 + 2 * e) * 9 + 8], W1[(32 + q * 8 + 2 * e + 1) * 9 + 8]);
    }

    float c0A = 0.f, c0B = 0.f, c1A = 0.f, c1B = 0.f;
    f32x4 a0A = {bias0A.x, bias0A.y, bias0A.z, bias0A.w};   // L0 acc carry
    f32x4 a0B = {bias0B.x, bias0B.y, bias0B.z, bias0B.w};
    float4 px   = {0.f, 0.f, 0.f, 0.f}; // x prefetch (tid 256..383)
    float4 dout = {0.f, 0.f, 0.f, 0.f}; // 4 deltas (w0,q1)
    __syncthreads();

    // ---- init: stage x(0..7) into 8-slot ring; px <- x(8..11) ----
    if (tid >= 256) {
        int L = tid - 256, pb = L >> 4, ti = (L >> 1) & 7, ph = L & 1;
        float4 x0 = *(const float4*)(feat + ((size_t)(b0 + pb) * NT + ti) * 8 + 4 * ph);
        uint2 p2; p2.x = pkrtz(x0.x, x0.y); p2.y = pkrtz(x0.z, x0.w);
        *(uint2*)(smem + O_XB + ti * 256 + pb * 16 + ph * 8) = p2;
    }
    if (tid >= 256 && tid < 384) {
        int L = tid - 256, pb = L >> 3, ti = (L >> 1) & 3, ph = L & 1;
        px = *(const float4*)(feat + ((size_t)(b0 + pb) * NT + 8 + ti) * 8 + 4 * ph);
    }
    __syncthreads();

    // ---- init: prehid slot 0 (packed f16, waves 0-3) ----
    if (w < 4) {
        union { uint4 u4; f16x8 h; } xb;
        xb.u4 = (uint4){0u, 0u, 0u, 0u};
        if (q == 0)      xb.u4 = *(const uint4*)(smem + O_XB + cb * 16);
        else if (q == 1) xb.u4.x = 0x3C000000u;   // k8=0, k9=1
        f32x4 acc = {0.f, 0.f, 0.f, 0.f};
        acc = __builtin_amdgcn_mfma_f32_16x16x32_f16(wv1, xb.h, acc, 0, 0, 0);
        uint2 ph; ph.x = pkrtz(acc[0], acc[1]); ph.y = pkrtz(acc[2], acc[3]);
        *(uint2*)(smem + O_PXH + (2 * w + (q >> 1)) * 256 + cb * 16 + (q & 1) * 8) = ph;
    }
    __syncthreads();

    #pragma unroll 1
    for (int tb = 0; tb < NT; tb += 4) {
        #pragma unroll
        for (int u = 0; u < 4; ++u) {
            const int t = tb + u;
            // ================= PHASE A =================
            // h1 frag reads feed BOTH the delta MFMA and the L1 recurrent.
            f16x8 h1a = *(const f16x8*)(smem + O_H1 + lane * 16);
            f16x8 h1b = *(const f16x8*)(smem + O_H1 + 1024 + lane * 16);
            float dlt = 0.f;
            {
                f32x4 ad = {0.f, 0.f, 0.f, 0.f};
                ad = __builtin_amdgcn_mfma_f32_16x16x32_f16(wdlt0, h1a, ad, 0, 0, 0);
                ad = __builtin_amdgcn_mfma_f32_16x16x32_f16(wdlt1, h1b, ad, 0, 0, 0);
                float dr = __shfl(ad[0], cb, 64);    // C[row0][cb] broadcast
                if (t > 0) dlt = dr + bov;
            }
            if (w == 0 && q == 1) {          // batched output (aligned float4)
                if (u == 1)      dout.x = dlt;
                else if (u == 2) dout.y = dlt;
                else if (u == 3) dout.z = dlt;
                else if (t > 0) {            // u == 0
                    dout.w = dlt;
                    *(float4*)(out + (size_t)(b0 + cb) * NT + (t - 4)) = dout;
                }
            }
            f32x4 a1A = {bias1A.x, bias1A.y, bias1A.z, bias1A.w};
            f32x4 a1B = {bias1B.x, bias1B.y, bias1B.z, bias1B.w};
            a1A = __builtin_amdgcn_mfma_f32_16x16x32_f16(wl1_2A, h1a, a1A, 0, 0, 0);
            a1B = __builtin_amdgcn_mfma_f32_16x16x32_f16(wl1_2B, h1a, a1B, 0, 0, 0);
            a1A = __builtin_amdgcn_mfma_f32_16x16x32_f16(wl1_3A, h1b, a1A, 0, 0, 0);
            a1B = __builtin_amdgcn_mfma_f32_16x16x32_f16(wl1_3B, h1b, a1B, 0, 0, 0);
            // hid = relu(prehid + w1col8*dlt) -- packed f16, IS the VSN2 B-frag
            f16x8 hb0, hb1;
            {
                const unsigned char* PX = smem + O_PXH + (t & 1) * 2048;
                uint4 pa = *(const uint4*)(PX + q * 256 + cb * 16);
                uint4 pb = *(const uint4*)(PX + (4 + q) * 256 + cb * 16);
                uint d2 = pkrtz(dlt, dlt);
                union { uint4 u4; f16x8 h; } ca, cbu;
                ca.u4.x  = pkfma_relu(pa.x, w8aU[0], d2);
                ca.u4.y  = pkfma_relu(pa.y, w8aU[1], d2);
                ca.u4.z  = pkfma_relu(pa.z, w8aU[2], d2);
                ca.u4.w  = pkfma_relu(pa.w, w8aU[3], d2);
                cbu.u4.x = pkfma_relu(pb.x, w8bU[0], d2);
                cbu.u4.y = pkfma_relu(pb.y, w8bU[1], d2);
                cbu.u4.z = pkfma_relu(pb.z, w8bU[2], d2);
                cbu.u4.w = pkfma_relu(pb.w, w8bU[3], d2);
                hb0 = ca.h; hb1 = cbu.h;
            }
            {
                f32x4 aA = {b2f.x, b2f.y, b2f.z, b2f.w};
                f32x4 aB = {0.f, 0.f, 0.f, 0.f};
                aA = __builtin_amdgcn_mfma_f32_16x16x32_f16(wv2_0, hb0, aA, 0, 0, 0);
                aB = __builtin_amdgcn_mfma_f32_16x16x32_f16(wv2_1, hb1, aB, 0, 0, 0);
                float e0 = fexp2(aA[0] + aB[0]);
                float e1 = fexp2(aA[1] + aB[1]);
                float e2 = fexp2(aA[2] + aB[2]);
                float e3 = fexp2(aA[3] + aB[3]);
                float sm = (e0 + e1) + (e2 + e3);
                sm += __shfl_xor(sm, 16, 64);
                sm += __shfl_xor(sm, 32, 64);
                float inv = frcp(sm);
                float x0, x1, x2, x3;
                if (q < 2) {
                    uint2 xw2 = *(const uint2*)(smem + O_XB + (t & 7) * 256 + cb * 16 + q * 8);
                    const __half* xh = (const __half*)&xw2;
                    x0 = __half2float(xh[0]); x1 = __half2float(xh[1]);
                    x2 = __half2float(xh[2]); x3 = __half2float(xh[3]);
                } else if (q == 2) { x0 = dlt; x1 = x2 = x3 = 0.f; }
                else               { x0 = x1 = x2 = x3 = 0.f; }
                // x~ C-rows ARE the K=16 B-frag (lane q holds k=4q..4q+3)
                union { uint2 u2; f16x4 h; } xs;
                xs.u2.x = pkrtz(x0 * e0 * inv, x1 * e1 * inv);
                xs.u2.y = pkrtz(x2 * e2 * inv, x3 * e3 * inv);
                a0A = MFMA16(wl0xA, xs.h, a0A);
                a0B = MFMA16(wl0xB, xs.h, a0B);
                float hA = lstm_out2(a0A, c0A);
                float hB = lstm_out2(a0B, c0B);
                *(unsigned short*)(smem + O_H0 + w * 256 + cb * 16 + q * 2)     = f16b(hA);
                *(unsigned short*)(smem + O_H0 + w * 256 + cb * 16 + 8 + q * 2) = f16b(hB);
            }
            __syncthreads();   // h0 ready

            // ================= PHASE B =================
            {
                f16x8 h0a = *(const f16x8*)(smem + O_H0 + lane * 16);
                f16x8 h0b = *(const f16x8*)(smem + O_H0 + 1024 + lane * 16);
                a1A = __builtin_amdgcn_mfma_f32_16x16x32_f16(wl1_0A, h0a, a1A, 0, 0, 0);
                a1B = __builtin_amdgcn_mfma_f32_16x16x32_f16(wl1_0B, h0a, a1B, 0, 0, 0);
                a1A = __builtin_amdgcn_mfma_f32_16x16x32_f16(wl1_1A, h0b, a1A, 0, 0, 0);
                a1B = __builtin_amdgcn_mfma_f32_16x16x32_f16(wl1_1B, h0b, a1B, 0, 0, 0);
                f32x4 anA = {bias0A.x, bias0A.y, bias0A.z, bias0A.w};
                f32x4 anB = {bias0B.x, bias0B.y, bias0B.z, bias0B.w};
                anA = __builtin_amdgcn_mfma_f32_16x16x32_f16(wl0_1A, h0a, anA, 0, 0, 0);
                anB = __builtin_amdgcn_mfma_f32_16x16x32_f16(wl0_1B, h0a, anB, 0, 0, 0);
                anA = __builtin_amdgcn_mfma_f32_16x16x32_f16(wl0_2A, h0b, anA, 0, 0, 0);
                anB = __builtin_amdgcn_mfma_f32_16x16x32_f16(wl0_2B, h0b, anB, 0, 0, 0);
                a0A = anA; a0B = anB;
                float hA = lstm_out2(a1A, c1A);
                float hB = lstm_out2(a1B, c1B);
                *(unsigned short*)(smem + O_H1 + w * 256 + cb * 16 + q * 2)     = f16b(hA);
                *(unsigned short*)(smem + O_H1 + w * 256 + cb * 16 + 8 + q * 2) = f16b(hB);
            }
            if (w < 4 && t + 1 < NT) {   // prehid(t+1) packed f16
                union { uint4 u4; f16x8 h; } xb;
                xb.u4 = (uint4){0u, 0u, 0u, 0u};
                if (q == 0)      xb.u4 = *(const uint4*)(smem + O_XB + ((t + 1) & 7) * 256 + cb * 16);
                else if (q == 1) xb.u4.x = 0x3C000000u;   // k8=0, k9=1
                f32x4 acc = {0.f, 0.f, 0.f, 0.f};
                acc = __builtin_amdgcn_mfma_f32_16x16x32_f16(wv1, xb.h, acc, 0, 0, 0);
                uint2 ph; ph.x = pkrtz(acc[0], acc[1]); ph.y = pkrtz(acc[2], acc[3]);
                *(uint2*)(smem + O_PXH + ((t + 1) & 1) * 2048
                          + (2 * w + (q >> 1)) * 256 + cb * 16 + (q & 1) * 8) = ph;
            }
            if (u == 3 && tid >= 256 && tid < 384) {   // restock slots (tb+8..11)&7
                int L = tid - 256, pb = L >> 3, ti = (L >> 1) & 3, ph = L & 1;
                uint2 p2; p2.x = pkrtz(px.x, px.y); p2.y = pkrtz(px.z, px.w);
                *(uint2*)(smem + O_XB + ((tb + 8 + ti) & 7) * 256 + pb * 16 + ph * 8) = p2;
                int tt = tb + 12 + ti;
                if (tt < NT)
                    px = *(const float4*)(feat + ((size_t)(b0 + pb) * NT + tt) * 8 + 4 * ph);
            }
            __syncthreads();   // h1/prehid/x ready for next step
        }
    }

    // ---- epilogue: delta(255) via the same MFMA path ----
    {
        f16x8 h1a = *(const f16x8*)(smem + O_H1 + lane * 16);
        f16x8 h1b = *(const f16x8*)(smem + O_H1 + 1024 + lane * 16);
        f32x4 ad = {0.f, 0.f, 0.f, 0.f};
        ad = __builtin_amdgcn_mfma_f32_16x16x32_f16(wdlt0, h1a, ad, 0, 0, 0);
        ad = __builtin_amdgcn_mfma_f32_16x16x32_f16(wdlt1, h1b, ad, 0, 0, 0);
        float d = __shfl(ad[0], cb, 64) + bov;
        if (w == 0 && q == 1) {
            dout.w = d;
            *(float4*)(out + (size_t)(b0 + cb) * NT + (NT - 4)) = dout;
        }
    }
}

extern "C" void kernel_launch(void* const* d_in, const int* in_sizes, int n_in,
                              void* d_out, int out_size, void* d_ws, size_t ws_size,
                              hipStream_t stream) {
    const float* feat = (const float*)d_in[0];
    const float* W1   = (const float*)d_in[1];
    const float* b1   = (const float*)d_in[2];
    const float* W2   = (const float*)d_in[3];
    const float* b2   = (const float*)d_in[4];
    const float* Wih0 = (const float*)d_in[5];
    const float* Whh0 = (const float*)d_in[6];
    const float* bih0 = (const float*)d_in[7];
    const float* bhh0 = (const float*)d_in[8];
    const float* Wih1 = (const float*)d_in[9];
    const float* Whh1 = (const float*)d_in[10];
    const float* bih1 = (const float*)d_in[11];
    const float* bhh1 = (const float*)d_in[12];
    const float* Wo   = (const float*)d_in[13];
    const float* bo   = (const float*)d_in[14];
    uint* ws   = (uint*)d_ws;
    float* out = (float*)d_out;

    hipLaunchKernelGGL(prep_kernel, dim3(40), dim3(1024), 0, stream,
                       W1, b1, W2, b2, Wih0, Whh0, bih0, bhh0,
                       Wih1, Whh1, bih1, bhh1, ws);
    // 256 blocks x 512 threads (8 waves): 16 batches/block, 1 block/CU
    hipLaunchKernelGGL(tft_main, dim3(256), dim3(512), 0, stream,
                       feat, W1, Wo, bo, ws, out);
}

// Round 18
// 279.501 us; speedup vs baseline: 1.8968x; 1.0162x over previous
//
#include <hip/hip_runtime.h>
#include <hip/hip_fp16.h>
#include <math.h>

typedef unsigned int uint;
typedef _Float16 f16x8 __attribute__((ext_vector_type(8)));
typedef _Float16 f16x4 __attribute__((ext_vector_type(4)));
typedef __fp16 fp16x2 __attribute__((ext_vector_type(2)));
typedef float f32x4 __attribute__((ext_vector_type(4)));

#define NT 256

#define MFMA16(a, b, c) __builtin_amdgcn_mfma_f32_16x16x16f16(a, b, c, 0, 0, 0)

// ---------------- ws layout (uint/f32 words) ----------------
// Tile j-mapping (adjacent-j): tile t covers j = 8*(t>>1) + 2*q + (t&1),
// q = row16>>2, gate = row16&3.  Lane (q,cb) of wave w (tiles 2w,2w+1)
// owns jA = 8w+2q and jB = 8w+2q+1 -> adjacent LDS bytes, single b32 write.
// 0     : W_l0 frags [16 tiles][3 ksteps][64 lanes][4 uint] = 12288
//         s=0 = K=16 x~ A-frag (2 words/lane); s=1,2 = Whh0 K=32. prescaled.
// 12288 : W_l1 frags [16][4][64][4] = 16384  (gate-prescaled)
// 28672 : W_v1 frags [4][64][4]  (b1 folded at k=9, delta col zeroed) = 1024
// 29696 : W_v2 frags [2][64][4]  (x log2e)                   = 512
// 31232 : b2frag f32 [64][4]     (x log2e; -1e30 pads)       = 256
// 31488 : bias0frag f32 [16][64][4] (gate-prescaled)         = 4096
// 35584 : bias1frag f32 [16][64][4] (gate-prescaled)         = 4096

// ---------------- LDS (bytes) ----------------
#define O_XB   0      // 2048  x ring, 8 slots x 256B
#define O_PXH  2048   // 4096  prehid ring (packed f16), 2 slots x 2048B
#define O_H0   6144   // 2048  h0 K=64 frag-linear
#define O_H1   8192   // 2048  h1 K=64
#define LDS_BYTES 10240

__device__ __forceinline__ float fexp2(float x) { return __builtin_amdgcn_exp2f(x); }
__device__ __forceinline__ float frcp(float x)  { return __builtin_amdgcn_rcpf(x); }

__device__ __forceinline__ uint pkrtz(float lo, float hi) {
    fp16x2 v = __builtin_amdgcn_cvt_pkrtz(lo, hi);
    return __builtin_bit_cast(uint, v);
}
__device__ __forceinline__ uint pack2(float lo, float hi) {
    return ((uint)__half_as_ushort(__float2half_rn(hi)) << 16) |
           (uint)__half_as_ushort(__float2half_rn(lo));
}
__device__ __forceinline__ f16x8 ldfrag(const uint* p) {
    union { uint4 u; f16x8 h; } c;
    c.u = *(const uint4*)p;
    return c.h;
}
// packed f16: relu(acc + w*d)
__device__ __forceinline__ uint pkfma_relu(uint acc, uint wv, uint d2) {
    uint r, z = 0u;
    asm("v_pk_fma_f16 %0, %1, %2, %3" : "=v"(r) : "v"(wv), "v"(d2), "v"(acc));
    asm("v_pk_max_f16 %0, %1, %2" : "=v"(r) : "v"(r), "v"(z));
    return r;
}
// gate rows prescaled: i,f,o by -log2(e); g by -2*log2(e)
__device__ __forceinline__ float lstm_out2(const f32x4 a, float& c) {
    float ii = frcp(1.0f + fexp2(a[0]));
    float ff = frcp(1.0f + fexp2(a[1]));
    float gg = fmaf(2.0f, frcp(1.0f + fexp2(a[2])), -1.0f);
    float oo = frcp(1.0f + fexp2(a[3]));
    c = fmaf(ff, c, ii * gg);
    return oo * fmaf(2.0f, frcp(1.0f + fexp2(-2.88539008f * c)), -1.0f);
}

// A-frag K=32: lane l holds A[row16=l&15][k=(l>>4)*8+e].
// A-frag K=16: lane l holds A[row16=l&15][k=(l>>4)*4+e], e=0..3.
__global__ __launch_bounds__(1024)
void prep_kernel(const float* __restrict__ W1,  const float* __restrict__ b1,
                 const float* __restrict__ W2,  const float* __restrict__ b2,
                 const float* __restrict__ Wih0, const float* __restrict__ Whh0,
                 const float* __restrict__ bih0, const float* __restrict__ bhh0,
                 const float* __restrict__ Wih1, const float* __restrict__ Whh1,
                 const float* __restrict__ bih1, const float* __restrict__ bhh1,
                 uint* __restrict__ ws)
{
    const int tid = blockIdx.x * 1024 + threadIdx.x;
    float* wsf = (float*)ws;
    const float LOG2E = 1.44269504f;

    if (tid < 12288) {                               // W_l0 (prescaled)
        int v = tid & 3, l = (tid >> 2) & 63, ts = tid >> 8;
        int s = ts % 3, w = ts / 3;                  // w = tile index 0..15
        int g = l & 3, qr = (l >> 2) & 3;
        float sc = (g == 2) ? -2.0f * LOG2E : -LOG2E;
        int j = 8 * (w >> 1) + 2 * qr + (w & 1);     // adjacent-j mapping
        int R = g * 64 + j;
        float lo = 0.f, hi = 0.f;
        if (s == 0) {                                // K=16 x~ frag (v<2 used)
            if (v < 2) {
                int k0 = (l >> 4) * 4 + 2 * v;
                if (k0     < 9) lo = Wih0[R * 9 + k0];
                if (k0 + 1 < 9) hi = Wih0[R * 9 + k0 + 1];
            }
            ws[tid] = pack2(lo * sc, hi * sc);
        } else {                                     // Whh0 K=32 frags
            int k0 = (l >> 4) * 8 + 2 * v;
            int kh = 32 * (s - 1) + k0;
            lo = Whh0[R * 64 + kh]; hi = Whh0[R * 64 + kh + 1];
            ws[tid] = pack2(lo * sc, hi * sc);
        }
    } else if (tid < 28672) {                        // W_l1 (prescaled)
        int idx = tid - 12288;
        int v = idx & 3, l = (idx >> 2) & 63, ts = idx >> 8;
        int s = ts & 3, w = ts >> 2;
        int g = l & 3, qr = (l >> 2) & 3;
        float sc = (g == 2) ? -2.0f * LOG2E : -LOG2E;
        int j = 8 * (w >> 1) + 2 * qr + (w & 1);
        int R = g * 64 + j;
        int kt = 32 * s + (l >> 4) * 8 + 2 * v;
        float lo, hi;
        if (kt < 64) { lo = Wih1[R * 64 + kt];      hi = Wih1[R * 64 + kt + 1]; }
        else         { lo = Whh1[R * 64 + kt - 64]; hi = Whh1[R * 64 + kt - 63]; }
        ws[tid] = pack2(lo * sc, hi * sc);
    } else if (tid < 29696) {                        // W_v1 (b1 folded at k=9)
        int idx = tid - 28672;
        int v = idx & 3, l = (idx >> 2) & 63, m = idx >> 8;
        int j2 = 16 * m + (l & 15);
        int k0 = (l >> 4) * 8 + 2 * v;
        float lo = (k0 < 9) ? W1[j2 * 9 + k0] : 0.f;
        float hi = 0.f;
        if (k0 + 1 < 9)       hi = W1[j2 * 9 + k0 + 1];
        else if (k0 + 1 == 9) hi = b1[j2];
        if (k0 == 8) lo = 0.f;                       // delta column handled in-reg
        ws[tid] = pack2(lo, hi);
    } else if (tid < 30208) {                        // W_v2 (x log2e)
        int idx = tid - 29696;
        int v = idx & 3, l = (idx >> 2) & 63, s = idx >> 8;
        int rr = l & 15;
        int k0 = 32 * s + (l >> 4) * 8 + 2 * v;
        float lo = (rr < 9) ? W2[rr * 64 + k0] * LOG2E     : 0.f;
        float hi = (rr < 9) ? W2[rr * 64 + k0 + 1] * LOG2E : 0.f;
        ws[tid] = pack2(lo, hi);
    } else if (tid >= 31232 && tid < 31488) {        // b2frag (x log2e, -1e30 pads)
        int idx = tid - 31232;
        int r = idx & 3, l = idx >> 2;
        int row = (l >> 4) * 4 + r;
        wsf[tid] = (row < 9) ? b2[row] * LOG2E : -1e30f;
    } else if (tid >= 31488 && tid < 35584) {        // bias0frag (prescaled)
        int idx = tid - 31488;
        int r = idx & 3, l = (idx >> 2) & 63, w = idx >> 8;
        float sc = (r == 2) ? -2.0f * LOG2E : -LOG2E;
        int j = 8 * (w >> 1) + 2 * (l >> 4) + (w & 1);
        wsf[tid] = (bih0[j + 0] + bhh0[j + 0]) * 0.f +       // keep formula simple:
                   (bih0[r * 64 + j] + bhh0[r * 64 + j]) * sc;
    } else if (tid >= 35584 && tid < 39680) {        // bias1frag (prescaled)
        int idx = tid - 35584;
        int r = idx & 3, l = (idx >> 2) & 63, w = idx >> 8;
        float sc = (r == 2) ? -2.0f * LOG2E : -LOG2E;
        int j = 8 * (w >> 1) + 2 * (l >> 4) + (w & 1);
        wsf[tid] = (bih1[r * 64 + j] + bhh1[r * 64 + j]) * sc;
    }
}

// 256 blocks x 512 threads (8 waves), 16 batches/block, 1 block/CU.
// 2-phase schedule; adjacent-j tiles -> single b32 h-writes.
__global__ __launch_bounds__(512, 2)
void tft_main(const float* __restrict__ feat,
              const float* __restrict__ W1,
              const float* __restrict__ Wo, const float* __restrict__ bo,
              const uint* __restrict__ ws,
              float* __restrict__ out)
{
    __shared__ unsigned char smem[LDS_BYTES];
    const int tid  = threadIdx.x;
    const int lane = tid & 63;
    const int w    = tid >> 6;        // 0..7
    const int q    = lane >> 4;       // 0..3
    const int cb   = lane & 15;       // batch column
    const int b0   = blockIdx.x * 16;
    const int tA   = 2 * w, tB = 2 * w + 1;

    // ---- zero LDS ----
    {
        uint4 z = {0u, 0u, 0u, 0u};
        ((uint4*)smem)[tid] = z;
        if (tid < LDS_BYTES / 16 - 512) ((uint4*)smem)[512 + tid] = z;
    }

    // ---- weights -> registers ----
    f16x4 wl0xA, wl0xB;               // K=16 x~ A-frags
    {
        union { uint2 u2; f16x4 h; } c;
        c.u2 = *(const uint2*)(ws + (tA * 3 + 0) * 256 + lane * 4);
        wl0xA = c.h;
        c.u2 = *(const uint2*)(ws + (tB * 3 + 0) * 256 + lane * 4);
        wl0xB = c.h;
    }
    const f16x8 wl0_1A = ldfrag(ws + (tA * 3 + 1) * 256 + lane * 4);
    const f16x8 wl0_2A = ldfrag(ws + (tA * 3 + 2) * 256 + lane * 4);
    const f16x8 wl0_1B = ldfrag(ws + (tB * 3 + 1) * 256 + lane * 4);
    const f16x8 wl0_2B = ldfrag(ws + (tB * 3 + 2) * 256 + lane * 4);
    const f16x8 wl1_0A = ldfrag(ws + 12288 + (tA * 4 + 0) * 256 + lane * 4);
    const f16x8 wl1_1A = ldfrag(ws + 12288 + (tA * 4 + 1) * 256 + lane * 4);
    const f16x8 wl1_2A = ldfrag(ws + 12288 + (tA * 4 + 2) * 256 + lane * 4);
    const f16x8 wl1_3A = ldfrag(ws + 12288 + (tA * 4 + 3) * 256 + lane * 4);
    const f16x8 wl1_0B = ldfrag(ws + 12288 + (tB * 4 + 0) * 256 + lane * 4);
    const f16x8 wl1_1B = ldfrag(ws + 12288 + (tB * 4 + 1) * 256 + lane * 4);
    const f16x8 wl1_2B = ldfrag(ws + 12288 + (tB * 4 + 2) * 256 + lane * 4);
    const f16x8 wl1_3B = ldfrag(ws + 12288 + (tB * 4 + 3) * 256 + lane * 4);
    const f16x8 wv2_0 = ldfrag(ws + 29696 + lane * 4);
    const f16x8 wv2_1 = ldfrag(ws + 29696 + 256 + lane * 4);
    f16x8 wv1 = {};
    const float* wsf = (const float*)ws;
    if (w < 4) wv1 = ldfrag(ws + 28672 + w * 256 + lane * 4);
    const float4 b2f    = *(const float4*)(wsf + 31232 + lane * 4);
    const float4 bias0A = *(const float4*)(wsf + 31488 + (tA * 64 + lane) * 4);
    const float4 bias0B = *(const float4*)(wsf + 31488 + (tB * 64 + lane) * 4);
    const float4 bias1A = *(const float4*)(wsf + 35584 + (tA * 64 + lane) * 4);
    const float4 bias1B = *(const float4*)(wsf + 35584 + (tB * 64 + lane) * 4);
    const float bov = bo[0];
    // W_dlt A-frags: row 0 = Wo (K=64 over 2 ksteps), rows 1-15 zero
    f16x8 wdlt0 = {}, wdlt1 = {};
    if ((lane & 15) == 0) {
        int kb = (lane >> 4) * 8;
        union { uint4 u4; f16x8 h; } t0, t1;
        t0.u4.x = pack2(Wo[kb],     Wo[kb + 1]);
        t0.u4.y = pack2(Wo[kb + 2], Wo[kb + 3]);
        t0.u4.z = pack2(Wo[kb + 4], Wo[kb + 5]);
        t0.u4.w = pack2(Wo[kb + 6], Wo[kb + 7]);
        t1.u4.x = pack2(Wo[32 + kb],     Wo[32 + kb + 1]);
        t1.u4.y = pack2(Wo[32 + kb + 2], Wo[32 + kb + 3]);
        t1.u4.z = pack2(Wo[32 + kb + 4], Wo[32 + kb + 5]);
        t1.u4.w = pack2(Wo[32 + kb + 6], Wo[32 + kb + 7]);
        wdlt0 = t0.h; wdlt1 = t1.h;
    }
    // W1 delta-column (col 8) packed f16 (prehid rank-1 update)
    uint w8aU[4], w8bU[4];
    #pragma unroll
    for (int e = 0; e < 4; ++e) {
        w8aU[e] = pack2(W1[(q * 8 + 2 * e) * 9 + 8],      W1[(q * 8 + 2 * e + 1) * 9 + 8]);
        w8bU[e] = pack2(W1[(32 + q * 8 + 2 * e) * 9 + 8], W1[(32 + q * 8 + 2 * e + 1) * 9 + 8]);
    }

    float c0A = 0.f, c0B = 0.f, c1A = 0.f, c1B = 0.f;
    f32x4 a0A = {bias0A.x, bias0A.y, bias0A.z, bias0A.w};   // L0 acc carry
    f32x4 a0B = {bias0B.x, bias0B.y, bias0B.z, bias0B.w};
    float4 px   = {0.f, 0.f, 0.f, 0.f}; // x prefetch (tid 256..383)
    float4 dout = {0.f, 0.f, 0.f, 0.f}; // 4 deltas (w0,q1)
    __syncthreads();

    // ---- init: stage x(0..7) into 8-slot ring; px <- x(8..11) ----
    if (tid >= 256) {
        int L = tid - 256, pb = L >> 4, ti = (L >> 1) & 7, ph = L & 1;
        float4 x0 = *(const float4*)(feat + ((size_t)(b0 + pb) * NT + ti) * 8 + 4 * ph);
        uint2 p2; p2.x = pkrtz(x0.x, x0.y); p2.y = pkrtz(x0.z, x0.w);
        *(uint2*)(smem + O_XB + ti * 256 + pb * 16 + ph * 8) = p2;
    }
    if (tid >= 256 && tid < 384) {
        int L = tid - 256, pb = L >> 3, ti = (L >> 1) & 3, ph = L & 1;
        px = *(const float4*)(feat + ((size_t)(b0 + pb) * NT + 8 + ti) * 8 + 4 * ph);
    }
    __syncthreads();

    // ---- init: prehid slot 0 (packed f16, waves 0-3) ----
    if (w < 4) {
        union { uint4 u4; f16x8 h; } xb;
        xb.u4 = (uint4){0u, 0u, 0u, 0u};
        if (q == 0)      xb.u4 = *(const uint4*)(smem + O_XB + cb * 16);
        else if (q == 1) xb.u4.x = 0x3C000000u;   // k8=0, k9=1
        f32x4 acc = {0.f, 0.f, 0.f, 0.f};
        acc = __builtin_amdgcn_mfma_f32_16x16x32_f16(wv1, xb.h, acc, 0, 0, 0);
        uint2 ph; ph.x = pkrtz(acc[0], acc[1]); ph.y = pkrtz(acc[2], acc[3]);
        *(uint2*)(smem + O_PXH + (2 * w + (q >> 1)) * 256 + cb * 16 + (q & 1) * 8) = ph;
    }
    __syncthreads();

    #pragma unroll 1
    for (int tb = 0; tb < NT; tb += 4) {
        #pragma unroll
        for (int u = 0; u < 4; ++u) {
            const int t = tb + u;
            // ================= PHASE A =================
            f16x8 h1a = *(const f16x8*)(smem + O_H1 + lane * 16);
            f16x8 h1b = *(const f16x8*)(smem + O_H1 + 1024 + lane * 16);
            float dlt = 0.f;
            {
                f32x4 ad = {0.f, 0.f, 0.f, 0.f};
                ad = __builtin_amdgcn_mfma_f32_16x16x32_f16(wdlt0, h1a, ad, 0, 0, 0);
                ad = __builtin_amdgcn_mfma_f32_16x16x32_f16(wdlt1, h1b, ad, 0, 0, 0);
                float dr = __shfl(ad[0], cb, 64);    // C[row0][cb] broadcast
                if (t > 0) dlt = dr + bov;
            }
            if (w == 0 && q == 1) {          // batched output (aligned float4)
                if (u == 1)      dout.x = dlt;
                else if (u == 2) dout.y = dlt;
                else if (u == 3) dout.z = dlt;
                else if (t > 0) {            // u == 0
                    dout.w = dlt;
                    *(float4*)(out + (size_t)(b0 + cb) * NT + (t - 4)) = dout;
                }
            }
            f32x4 a1A = {bias1A.x, bias1A.y, bias1A.z, bias1A.w};
            f32x4 a1B = {bias1B.x, bias1B.y, bias1B.z, bias1B.w};
            a1A = __builtin_amdgcn_mfma_f32_16x16x32_f16(wl1_2A, h1a, a1A, 0, 0, 0);
            a1B = __builtin_amdgcn_mfma_f32_16x16x32_f16(wl1_2B, h1a, a1B, 0, 0, 0);
            a1A = __builtin_amdgcn_mfma_f32_16x16x32_f16(wl1_3A, h1b, a1A, 0, 0, 0);
            a1B = __builtin_amdgcn_mfma_f32_16x16x32_f16(wl1_3B, h1b, a1B, 0, 0, 0);
            // hid = relu(prehid + w1col8*dlt) -- packed f16, IS the VSN2 B-frag
            f16x8 hb0, hb1;
            {
                const unsigned char* PX = smem + O_PXH + (t & 1) * 2048;
                uint4 pa = *(const uint4*)(PX + q * 256 + cb * 16);
                uint4 pb = *(const uint4*)(PX + (4 + q) * 256 + cb * 16);
                uint d2 = pkrtz(dlt, dlt);
                union { uint4 u4; f16x8 h; } ca, cbu;
                ca.u4.x  = pkfma_relu(pa.x, w8aU[0], d2);
                ca.u4.y  = pkfma_relu(pa.y, w8aU[1], d2);
                ca.u4.z  = pkfma_relu(pa.z, w8aU[2], d2);
                ca.u4.w  = pkfma_relu(pa.w, w8aU[3], d2);
                cbu.u4.x = pkfma_relu(pb.x, w8bU[0], d2);
                cbu.u4.y = pkfma_relu(pb.y, w8bU[1], d2);
                cbu.u4.z = pkfma_relu(pb.z, w8bU[2], d2);
                cbu.u4.w = pkfma_relu(pb.w, w8bU[3], d2);
                hb0 = ca.h; hb1 = cbu.h;
            }
            {
                f32x4 aA = {b2f.x, b2f.y, b2f.z, b2f.w};
                f32x4 aB = {0.f, 0.f, 0.f, 0.f};
                aA = __builtin_amdgcn_mfma_f32_16x16x32_f16(wv2_0, hb0, aA, 0, 0, 0);
                aB = __builtin_amdgcn_mfma_f32_16x16x32_f16(wv2_1, hb1, aB, 0, 0, 0);
                float e0 = fexp2(aA[0] + aB[0]);
                float e1 = fexp2(aA[1] + aB[1]);
                float e2 = fexp2(aA[2] + aB[2]);
                float e3 = fexp2(aA[3] + aB[3]);
                float sm = (e0 + e1) + (e2 + e3);
                sm += __shfl_xor(sm, 16, 64);
                sm += __shfl_xor(sm, 32, 64);
                float inv = frcp(sm);
                float x0, x1, x2, x3;
                if (q < 2) {
                    uint2 xw2 = *(const uint2*)(smem + O_XB + (t & 7) * 256 + cb * 16 + q * 8);
                    const __half* xh = (const __half*)&xw2;
                    x0 = __half2float(xh[0]); x1 = __half2float(xh[1]);
                    x2 = __half2float(xh[2]); x3 = __half2float(xh[3]);
                } else if (q == 2) { x0 = dlt; x1 = x2 = x3 = 0.f; }
                else               { x0 = x1 = x2 = x3 = 0.f; }
                // x~ C-rows ARE the K=16 B-frag (lane q holds k=4q..4q+3)
                union { uint2 u2; f16x4 h; } xs;
                xs.u2.x = pkrtz(x0 * e0 * inv, x1 * e1 * inv);
                xs.u2.y = pkrtz(x2 * e2 * inv, x3 * e3 * inv);
                a0A = MFMA16(wl0xA, xs.h, a0A);
                a0B = MFMA16(wl0xB, xs.h, a0B);
                float hA = lstm_out2(a0A, c0A);
                float hB = lstm_out2(a0B, c0B);
                // jA = 8w+2q, jB = 8w+2q+1 -> adjacent: single b32 write
                *(uint*)(smem + O_H0 + w * 256 + cb * 16 + q * 4) = pkrtz(hA, hB);
            }
            __syncthreads();   // h0 ready

            // ================= PHASE B =================
            {
                f16x8 h0a = *(const f16x8*)(smem + O_H0 + lane * 16);
                f16x8 h0b = *(const f16x8*)(smem + O_H0 + 1024 + lane * 16);
                a1A = __builtin_amdgcn_mfma_f32_16x16x32_f16(wl1_0A, h0a, a1A, 0, 0, 0);
                a1B = __builtin_amdgcn_mfma_f32_16x16x32_f16(wl1_0B, h0a, a1B, 0, 0, 0);
                a1A = __builtin_amdgcn_mfma_f32_16x16x32_f16(wl1_1A, h0b, a1A, 0, 0, 0);
                a1B = __builtin_amdgcn_mfma_f32_16x16x32_f16(wl1_1B, h0b, a1B, 0, 0, 0);
                f32x4 anA = {bias0A.x, bias0A.y, bias0A.z, bias0A.w};
                f32x4 anB = {bias0B.x, bias0B.y, bias0B.z, bias0B.w};
                anA = __builtin_amdgcn_mfma_f32_16x16x32_f16(wl0_1A, h0a, anA, 0, 0, 0);
                anB = __builtin_amdgcn_mfma_f32_16x16x32_f16(wl0_1B, h0a, anB, 0, 0, 0);
                anA = __builtin_amdgcn_mfma_f32_16x16x32_f16(wl0_2A, h0b, anA, 0, 0, 0);
                anB = __builtin_amdgcn_mfma_f32_16x16x32_f16(wl0_2B, h0b, anB, 0, 0, 0);
                a0A = anA; a0B = anB;
                float hA = lstm_out2(a1A, c1A);
                float hB = lstm_out2(a1B, c1B);
                *(uint*)(smem + O_H1 + w * 256 + cb * 16 + q * 4) = pkrtz(hA, hB);
            }
            if (w < 4 && t + 1 < NT) {   // prehid(t+1) packed f16
                union { uint4 u4; f16x8 h; } xb;
                xb.u4 = (uint4){0u, 0u, 0u, 0u};
                if (q == 0)      xb.u4 = *(const uint4*)(smem + O_XB + ((t + 1) & 7) * 256 + cb * 16);
                else if (q == 1) xb.u4.x = 0x3C000000u;   // k8=0, k9=1
                f32x4 acc = {0.f, 0.f, 0.f, 0.f};
                acc = __builtin_amdgcn_mfma_f32_16x16x32_f16(wv1, xb.h, acc, 0, 0, 0);
                uint2 ph; ph.x = pkrtz(acc[0], acc[1]); ph.y = pkrtz(acc[2], acc[3]);
                *(uint2*)(smem + O_PXH + ((t + 1) & 1) * 2048
                          + (2 * w + (q >> 1)) * 256 + cb * 16 + (q & 1) * 8) = ph;
            }
            if (u == 3 && tid >= 256 && tid < 384) {   // restock slots (tb+8..11)&7
                int L = tid - 256, pb = L >> 3, ti = (L >> 1) & 3, ph = L & 1;
                uint2 p2; p2.x = pkrtz(px.x, px.y); p2.y = pkrtz(px.z, px.w);
                *(uint2*)(smem + O_XB + ((tb + 8 + ti) & 7) * 256 + pb * 16 + ph * 8) = p2;
                int tt = tb + 12 + ti;
                if (tt < NT)
                    px = *(const float4*)(feat + ((size_t)(b0 + pb) * NT + tt) * 8 + 4 * ph);
            }
            __syncthreads();   // h1/prehid/x ready for next step
        }
    }

    // ---- epilogue: delta(255) via the same MFMA path ----
    {
        f16x8 h1a = *(const f16x8*)(smem + O_H1 + lane * 16);
        f16x8 h1b = *(const f16x8*)(smem + O_H1 + 1024 + lane * 16);
        f32x4 ad = {0.f, 0.f, 0.f, 0.f};
        ad = __builtin_amdgcn_mfma_f32_16x16x32_f16(wdlt0, h1a, ad, 0, 0, 0);
        ad = __builtin_amdgcn_mfma_f32_16x16x32_f16(wdlt1, h1b, ad, 0, 0, 0);
        float d = __shfl(ad[0], cb, 64) + bov;
        if (w == 0 && q == 1) {
            dout.w = d;
            *(float4*)(out + (size_t)(b0 + cb) * NT + (NT - 4)) = dout;
        }
    }
}

extern "C" void kernel_launch(void* const* d_in, const int* in_sizes, int n_in,
                              void* d_out, int out_size, void* d_ws, size_t ws_size,
                              hipStream_t stream) {
    const float* feat = (const float*)d_in[0];
    const float* W1   = (const float*)d_in[1];
    const float* b1   = (const float*)d_in[2];
    const float* W2   = (const float*)d_in[3];
    const float* b2   = (const float*)d_in[4];
    const float* Wih0 = (const float*)d_in[5];
    const float* Whh0 = (const float*)d_in[6];
    const float* bih0 = (const float*)d_in[7];
    const float* bhh0 = (const float*)d_in[8];
    const float* Wih1 = (const float*)d_in[9];
    const float* Whh1 = (const float*)d_in[10];
    const float* bih1 = (const float*)d_in[11];
    const float* bhh1 = (const float*)d_in[12];
    const float* Wo   = (const float*)d_in[13];
    const float* bo   = (const float*)d_in[14];
    uint* ws   = (uint*)d_ws;
    float* out = (float*)d_out;

    hipLaunchKernelGGL(prep_kernel, dim3(40), dim3(1024), 0, stream,
                       W1, b1, W2, b2, Wih0, Whh0, bih0, bhh0,
                       Wih1, Whh1, bih1, bhh1, ws);
    // 256 blocks x 512 threads (8 waves): 16 batches/block, 1 block/CU
    hipLaunchKernelGGL(tft_main, dim3(256), dim3(512), 0, stream,
                       feat, W1, Wo, bo, ws, out);
}